// Round 7
// baseline (405.163 us; speedup 1.0000x reference)
//
#include <hip/hip_runtime.h>
#include <hip/hip_bf16.h>
#include <math.h>

// ---------------- problem constants ----------------
#define L_SEQ   4096
#define DMODEL  1024
#define DINNER  2048
#define NHEADS  32
#define HEADDIM 64
#define DSTATE  128
#define NCHUNK  32
#define CHUNKL  128
#define CONVDIM 2560
#define DPROJ   4672   // 2*DINNER + 2*(2*DSTATE) + 2*NHEADS
#define NPAD1   4736   // DPROJ padded to multiple of 128 (for remainder gemm)
#define NSPLIT  4096   // cols [0,NSPLIT) via 8-phase 256^2 (256 blocks = 1 round);
                       // cols [NSPLIT,DPROJ) via 128^2 gemm (160 blocks)

typedef __hip_bfloat16 bf16;
__device__ __forceinline__ float b2f(bf16 x) { return __bfloat162float(x); }
__device__ __forceinline__ bf16 f2b(float x) { return __float2bfloat16(x); }
__device__ __forceinline__ float sh2f(short s) {
  return __uint_as_float(((unsigned int)(unsigned short)s) << 16);
}
__device__ __forceinline__ short f2bs(float x) {
  bf16 t = __float2bfloat16(x);
  return *reinterpret_cast<short*>(&t);
}

typedef __attribute__((ext_vector_type(8))) short bf16x8v;
typedef __attribute__((ext_vector_type(4))) float f32x4v;

__device__ __forceinline__ float dot8(bf16x8v x, float4 w0, float4 w1) {
  return sh2f(x[0]) * w0.x + sh2f(x[1]) * w0.y + sh2f(x[2]) * w0.z + sh2f(x[3]) * w0.w +
         sh2f(x[4]) * w1.x + sh2f(x[5]) * w1.y + sh2f(x[6]) * w1.z + sh2f(x[7]) * w1.w;
}

// zxbcdt column layout: [0,2048) = z ; [2048,4608) = xBC ; [4608,4672) = dt raw
// xBC_conv channel layout: [0,2048) = x ; fw B = [2048,2176) C = [2176,2304)
//                          bw B = [2304,2432) C = [2432,2560)  (bw streams time-flipped)

// ---------------- fused casts: u -> bf16 and in_proj_w -> bf16 (zero-padded) ----------------
__global__ __launch_bounds__(256) void cast2_kernel(
    const float* __restrict__ u, const float* __restrict__ w1,
    bf16* __restrict__ u_bf, bf16* __restrict__ w1_bf) {
  const int NU = (L_SEQ * DMODEL) / 256;   // 16384 blocks
  int bid = blockIdx.x;
  if (bid < NU) {
    int i = bid * 256 + threadIdx.x;
    u_bf[i] = f2b(u[i]);
  } else {
    int i = (bid - NU) * 256 + threadIdx.x;
    w1_bf[i] = (i < DPROJ * DMODEL) ? f2b(w1[i]) : f2b(0.f);
  }
}

// ---------------- f32 -> bf16 cast ----------------
__global__ __launch_bounds__(256) void cast_kernel(
    const float* __restrict__ src, bf16* __restrict__ dst, int n_src, int n_tot) {
  int i = blockIdx.x * 256 + threadIdx.x;
  if (i < n_tot) dst[i] = (i < n_src) ? f2b(src[i]) : f2b(0.f);
}

// ================= in_proj main: 8-phase 256x256 GEMM (R1-verified body) =================
// C[m,n] = sum_k A[m,k]*B[n,k]; A = u_bf [4096][1024], B = w1p_bf rows [0,4096),
// C = zx cols [0,4096). BK=64, 512 threads = 8 waves (2Mx4N), per-wave C = 128x64.
// Grid = 16 x 16 = 256 blocks = exactly one residency round (128 KiB LDS -> 1/CU).
// Register budget (the R2/R3 lesson): acc[8][4] = 128 regs + a/b frags 64 + addr
// ~= 244 <= 256-reg cap at 2 waves/SIMD. BN=320 (acc 160) does NOT fit -- spills.
// LDS: 2 dbuf slots x (A 256x64 + B 256x64), 16 subtiles of [16r][32c] per 128x64
// half, st_16x32 XOR swizzle via pre-swizzled global source (linear gload_lds dest)
// + swizzled ds_read addr. vmcnt(6) once per K-tile; vmcnt(0) only at t=NT-2.
#define G1_K  1024
#define G1_GN 16            // N tiles of 256 covering [0,4096)
#define G1_NT (G1_K / 64)   // 16 K-tiles

__global__ __launch_bounds__(512, 2) void gemm1_8ph(
    const bf16* __restrict__ A, const bf16* __restrict__ B, bf16* __restrict__ C) {
  __shared__ bf16 Al[2][2][8192];   // [slot][half][subtiled 128x64]  64 KB
  __shared__ bf16 Bl[2][2][8192];   // 64 KB
  const int tid = threadIdx.x;
  const int lane = tid & 63;
  const int w = tid >> 6;        // 0..7
  const int wm = w >> 2;         // 0..1 -> C rows [wm*128, +128)
  const int wn = w & 3;          // 0..3 -> C cols [wn*64, +64)
  const int bm = (blockIdx.x / G1_GN) * 256;
  const int bn = (blockIdx.x % G1_GN) * 256;
  // staging source pre-swizzle (bf16 units): dest r_in = lane>>2, swz bit = r_in bit3
  const int scol = ((lane & 3) ^ (((lane >> 5) & 1) << 1)) * 8;
  // read-side swizzled col within subtile: flip bit4 when row bit3 set
  const int cin = ((lane >> 4) * 8) ^ (((lane >> 3) & 1) << 4);
  const int r16 = lane & 15;
  const bf16* Ag = A + (size_t)bm * G1_K;
  const bf16* Bg = B + (size_t)bn * G1_K;

  // stage one 128x64 half-tile (A: mat=0, B: mat=1) of K-tile tt.
  // wave w fills subtiles w and 8+w (1024B each, linear dest; swizzle via source).
  auto stage = [&](int mat, int tt, int hf) {
    const bf16* g = (mat ? Bg : Ag)
        + (size_t)(hf * 128 + (w >> 1) * 16 + (lane >> 2)) * G1_K
        + tt * 64 + (w & 1) * 32 + scol;
    bf16* d0 = mat ? &Bl[tt & 1][hf][0] : &Al[tt & 1][hf][0];
    __builtin_amdgcn_global_load_lds(
        (const __attribute__((address_space(1))) void*)g,
        (__attribute__((address_space(3))) void*)(d0 + w * 512), 16, 0, 0);
    __builtin_amdgcn_global_load_lds(
        (const __attribute__((address_space(1))) void*)(g + (size_t)64 * G1_K),
        (__attribute__((address_space(3))) void*)(d0 + (8 + w) * 512), 16, 0, 0);
  };

  f32x4v acc[8][4];
#pragma unroll
  for (int i = 0; i < 8; i++)
#pragma unroll
    for (int j = 0; j < 4; j++) acc[i][j] = (f32x4v){0.f, 0.f, 0.f, 0.f};

  // prologue: tile0 {A0,A1,B0,B1}, tile1 {A0,A1,B0} = 7 half-tiles (14 loads)
  stage(0, 0, 0); stage(0, 0, 1); stage(1, 0, 0); stage(1, 0, 1);
  stage(0, 1, 0); stage(0, 1, 1); stage(1, 1, 0);
  asm volatile("s_waitcnt vmcnt(6)" ::: "memory");   // tile0 fully resident
  __builtin_amdgcn_s_barrier();
  __builtin_amdgcn_sched_barrier(0);

#pragma unroll 2
  for (int t = 0; t < G1_NT; ++t) {
    const int slot = t & 1;
    const bf16* Ah = &Al[slot][wm][0];
    const bf16* Bh = &Bl[slot][wn >> 1][0];
    const int brb = (wn & 1) * 4;   // B subtile-row base within half
    bf16x8v a[4][2], b[4][2];
    // ---- phase 0: ds A m0-3 + B n0-1 (12 reads); stage B1(t+1); mfma m0-3 x n0-1
#pragma unroll
    for (int i = 0; i < 4; i++) {
      a[i][0] = *(const bf16x8v*)&Ah[(i * 2 + 0) * 512 + r16 * 32 + cin];
      a[i][1] = *(const bf16x8v*)&Ah[(i * 2 + 1) * 512 + r16 * 32 + cin];
    }
#pragma unroll
    for (int j = 0; j < 2; j++) {
      b[j][0] = *(const bf16x8v*)&Bh[((brb + j) * 2 + 0) * 512 + r16 * 32 + cin];
      b[j][1] = *(const bf16x8v*)&Bh[((brb + j) * 2 + 1) * 512 + r16 * 32 + cin];
    }
    if (t + 1 < G1_NT) stage(1, t + 1, 1);
    __builtin_amdgcn_s_barrier();
    asm volatile("s_waitcnt lgkmcnt(0)" ::: "memory");
    __builtin_amdgcn_s_setprio(1);
#pragma unroll
    for (int i = 0; i < 4; i++)
#pragma unroll
      for (int j = 0; j < 2; j++) {
        acc[i][j] = __builtin_amdgcn_mfma_f32_16x16x32_bf16(a[i][0], b[j][0], acc[i][j], 0, 0, 0);
        acc[i][j] = __builtin_amdgcn_mfma_f32_16x16x32_bf16(a[i][1], b[j][1], acc[i][j], 0, 0, 0);
      }
    __builtin_amdgcn_s_setprio(0);
    __builtin_amdgcn_s_barrier();
    // ---- phase 1: ds B n2-3 (4 reads); mfma m0-3 x n2-3
#pragma unroll
    for (int j = 2; j < 4; j++) {
      b[j][0] = *(const bf16x8v*)&Bh[((brb + j) * 2 + 0) * 512 + r16 * 32 + cin];
      b[j][1] = *(const bf16x8v*)&Bh[((brb + j) * 2 + 1) * 512 + r16 * 32 + cin];
    }
    __builtin_amdgcn_s_barrier();
    asm volatile("s_waitcnt lgkmcnt(0)" ::: "memory");
    __builtin_amdgcn_s_setprio(1);
#pragma unroll
    for (int i = 0; i < 4; i++)
#pragma unroll
      for (int j = 2; j < 4; j++) {
        acc[i][j] = __builtin_amdgcn_mfma_f32_16x16x32_bf16(a[i][0], b[j][0], acc[i][j], 0, 0, 0);
        acc[i][j] = __builtin_amdgcn_mfma_f32_16x16x32_bf16(a[i][1], b[j][1], acc[i][j], 0, 0, 0);
      }
    __builtin_amdgcn_s_setprio(0);
    __builtin_amdgcn_s_barrier();
    // ---- phase 2: ds A m4-7 (8 reads); stage B0(t+2); mfma m4-7 x n2-3
#pragma unroll
    for (int i = 0; i < 4; i++) {
      a[i][0] = *(const bf16x8v*)&Ah[((4 + i) * 2 + 0) * 512 + r16 * 32 + cin];
      a[i][1] = *(const bf16x8v*)&Ah[((4 + i) * 2 + 1) * 512 + r16 * 32 + cin];
    }
    if (t + 2 < G1_NT) stage(1, t + 2, 0);
    __builtin_amdgcn_s_barrier();
    asm volatile("s_waitcnt lgkmcnt(0)" ::: "memory");
    __builtin_amdgcn_s_setprio(1);
#pragma unroll
    for (int i = 0; i < 4; i++)
#pragma unroll
      for (int j = 2; j < 4; j++) {
        acc[4 + i][j] = __builtin_amdgcn_mfma_f32_16x16x32_bf16(a[i][0], b[j][0], acc[4 + i][j], 0, 0, 0);
        acc[4 + i][j] = __builtin_amdgcn_mfma_f32_16x16x32_bf16(a[i][1], b[j][1], acc[4 + i][j], 0, 0, 0);
      }
    __builtin_amdgcn_s_setprio(0);
    __builtin_amdgcn_s_barrier();
    // ---- phase 3: stage A0,A1(t+2); mfma m4-7 x n0-1; counted vmcnt; barrier
    if (t + 2 < G1_NT) { stage(0, t + 2, 0); stage(0, t + 2, 1); }
    __builtin_amdgcn_s_barrier();
    __builtin_amdgcn_s_setprio(1);
#pragma unroll
    for (int i = 0; i < 4; i++)
#pragma unroll
      for (int j = 0; j < 2; j++) {
        acc[4 + i][j] = __builtin_amdgcn_mfma_f32_16x16x32_bf16(a[i][0], b[j][0], acc[4 + i][j], 0, 0, 0);
        acc[4 + i][j] = __builtin_amdgcn_mfma_f32_16x16x32_bf16(a[i][1], b[j][1], acc[4 + i][j], 0, 0, 0);
      }
    __builtin_amdgcn_s_setprio(0);
    if (t < G1_NT - 2)       asm volatile("s_waitcnt vmcnt(6)" ::: "memory");
    else if (t == G1_NT - 2) asm volatile("s_waitcnt vmcnt(0)" ::: "memory");
    __builtin_amdgcn_s_barrier();
    __builtin_amdgcn_sched_barrier(0);
  }

  const int quad = lane >> 4;
  const int cn = lane & 15;
#pragma unroll
  for (int i = 0; i < 8; i++)
#pragma unroll
    for (int j = 0; j < 4; j++) {
      int col = bn + wn * 64 + j * 16 + cn;
      if (col < DPROJ) {
#pragma unroll
        for (int r = 0; r < 4; r++) {
          int row = bm + wm * 128 + i * 16 + quad * 4 + r;
          C[(size_t)row * DPROJ + col] = f2b(acc[i][j][r]);
        }
      }
    }
}

// ---------------- MFMA GEMM: C[m,n] = sum_k A[m,k]*B[n,k], bf16 in, f32 acc ----------------
// (used for the in_proj N-remainder and for out_proj)
template <typename TC>
__global__ __launch_bounds__(256) void gemm_mfma(
    const bf16* __restrict__ A, int lda,
    const bf16* __restrict__ B, int ldb,
    TC* __restrict__ C, int ldc,
    int N, int K, int gridM, int gridN, int swz) {
  __shared__ short As[128][32];
  __shared__ short Bs[128][32];
  int tid = threadIdx.x;
  int lane = tid & 63;
  int w = tid >> 6;            // wave 0..3
  int wr = w >> 1, wc = w & 1; // 2x2 wave grid
  int bid = blockIdx.x;
  int bm, bn;
  if (swz) {
    int mst = gridM >> 3;
    int xk = bid & 7, q = bid >> 3;
    bm = (xk + 8 * (q % mst)) * 128;
    bn = (q / mst) * 128;
  } else {
    bm = (bid / gridN) * 128;
    bn = (bid % gridN) * 128;
  }
  f32x4v acc[4][4];
#pragma unroll
  for (int i = 0; i < 4; i++)
#pragma unroll
    for (int j = 0; j < 4; j++) acc[i][j] = (f32x4v){0.f, 0.f, 0.f, 0.f};

  const bf16* Ab = A + (size_t)(bm + w * 32 + (lane >> 2)) * lda + (lane & 3) * 8;
  const bf16* Bb = B + (size_t)(bn + w * 32 + (lane >> 2)) * ldb + (lane & 3) * 8;

  for (int k0 = 0; k0 < K; k0 += 32) {
    __builtin_amdgcn_global_load_lds(
        (const __attribute__((address_space(1))) void*)(Ab + k0),
        (__attribute__((address_space(3))) void*)&As[w * 32][0], 16, 0, 0);
    __builtin_amdgcn_global_load_lds(
        (const __attribute__((address_space(1))) void*)(Ab + (size_t)16 * lda + k0),
        (__attribute__((address_space(3))) void*)&As[w * 32 + 16][0], 16, 0, 0);
    __builtin_amdgcn_global_load_lds(
        (const __attribute__((address_space(1))) void*)(Bb + k0),
        (__attribute__((address_space(3))) void*)&Bs[w * 32][0], 16, 0, 0);
    __builtin_amdgcn_global_load_lds(
        (const __attribute__((address_space(1))) void*)(Bb + (size_t)16 * ldb + k0),
        (__attribute__((address_space(3))) void*)&Bs[w * 32 + 16][0], 16, 0, 0);
    __syncthreads();
    bf16x8v af[4], bv[4];
#pragma unroll
    for (int i = 0; i < 4; i++)
      af[i] = *(const bf16x8v*)&As[wr * 64 + i * 16 + (lane & 15)][(lane >> 4) * 8];
#pragma unroll
    for (int j = 0; j < 4; j++)
      bv[j] = *(const bf16x8v*)&Bs[wc * 64 + j * 16 + (lane & 15)][(lane >> 4) * 8];
#pragma unroll
    for (int i = 0; i < 4; i++)
#pragma unroll
      for (int j = 0; j < 4; j++)
        acc[i][j] = __builtin_amdgcn_mfma_f32_16x16x32_bf16(af[i], bv[j], acc[i][j], 0, 0, 0);
    __syncthreads();
  }
  int quad = lane >> 4;
  int cn = lane & 15;
#pragma unroll
  for (int i = 0; i < 4; i++) {
#pragma unroll
    for (int j = 0; j < 4; j++) {
      int col = bn + wc * 64 + j * 16 + cn;
      if (col < N) {
#pragma unroll
        for (int r = 0; r < 4; r++) {
          int row = bm + wr * 64 + i * 16 + quad * 4 + r;
          float v = acc[i][j][r];
          if constexpr (sizeof(TC) == 2) C[(size_t)row * ldc + col] = f2b(v);
          else                           C[(size_t)row * ldc + col] = v;
        }
      }
    }
  }
}

// ---------------- fc_D: fd[t][h] = sum_k x[t,k]*W[h,k] + D[h] ----------------
// R6: k split across the 4 waves (512 each; lane g-split -> 256 k/lane, 32-iter
// chain) + 4x grid (1024 blocks = 4/CU, 4 waves/SIMD). R5 measured 57.9 us at
// 1 wave/SIMD (zero TLP, 128-iter dependent chain) -- pure latency-bound.
// Same 4-t-per-block W amortization (256 KB L2 per 4 t); LDS cross-wave reduce.
__global__ __launch_bounds__(256) void fc_kernel(
    const bf16* __restrict__ xbc, const float* __restrict__ Wf,
    const float* __restrict__ Dp, float* __restrict__ fd) {
  int lane = threadIdx.x & 63;
  int w = threadIdx.x >> 6;          // wave = k-quarter
  int t0 = blockIdx.x * 4;
  int h = lane & 31;
  int g = lane >> 5;                 // k-eighth within quarter
  int k0 = w * 512 + g * 256;
  const float* wr = Wf + (size_t)h * DINNER + k0;
  const bf16* xr = xbc + (size_t)t0 * CONVDIM + k0;
  float a0 = 0.f, a1 = 0.f, a2 = 0.f, a3 = 0.f;
#pragma unroll 4
  for (int k = 0; k < 256; k += 8) {
    float4 w0 = *(const float4*)(wr + k);
    float4 w1 = *(const float4*)(wr + k + 4);
    bf16x8v x0 = *(const bf16x8v*)(xr + k);
    bf16x8v x1 = *(const bf16x8v*)(xr + CONVDIM + k);
    bf16x8v x2 = *(const bf16x8v*)(xr + 2 * CONVDIM + k);
    bf16x8v x3 = *(const bf16x8v*)(xr + 3 * CONVDIM + k);
    a0 += dot8(x0, w0, w1);
    a1 += dot8(x1, w0, w1);
    a2 += dot8(x2, w0, w1);
    a3 += dot8(x3, w0, w1);
  }
  a0 += __shfl_down(a0, 32);
  a1 += __shfl_down(a1, 32);
  a2 += __shfl_down(a2, 32);
  a3 += __shfl_down(a3, 32);
  __shared__ float red[4][4][32];    // [wave][t][h]
  if (lane < 32) {
    red[w][0][h] = a0; red[w][1][h] = a1; red[w][2][h] = a2; red[w][3][h] = a3;
  }
  __syncthreads();
  int tid = threadIdx.x;
  if (tid < 128) {
    int tt = tid >> 5;
    int hh = tid & 31;
    float s = red[0][tt][hh] + red[1][tt][hh] + red[2][tt][hh] + red[3][tt][hh];
    fd[(t0 + tt) * NHEADS + hh] = s + Dp[hh];
  }
}

// ---------------- conv (4 t/thread) + SiLU, with dt softplus folded in ----------------
#define CONV_BLOCKS ((L_SEQ / 4) * CONVDIM / 256)   // 10240
__global__ __launch_bounds__(256) void conv_dt_kernel(
    const bf16* __restrict__ zx, const float* __restrict__ conv_w,
    const float* __restrict__ conv_b, bf16* __restrict__ xbc,
    const float* __restrict__ dt_bias, float* __restrict__ dt2) {
  int bid = blockIdx.x;
  if (bid < CONV_BLOCKS) {
    int idx = bid * 256 + threadIdx.x;
    int ch = idx % CONVDIM;
    int t0 = (idx / CONVDIM) * 4;
    const bf16* col = zx + DINNER + ch;
    float w0 = conv_w[ch * 4 + 0], w1 = conv_w[ch * 4 + 1];
    float w2 = conv_w[ch * 4 + 2], w3 = conv_w[ch * 4 + 3];
    float bsv = conv_b[ch];
    float x[7];
#pragma unroll
    for (int i = 0; i < 7; i++) {
      int t = t0 - 3 + i;
      x[i] = (t >= 0) ? b2f(col[(size_t)t * DPROJ]) : 0.f;
    }
#pragma unroll
    for (int j = 0; j < 4; j++) {
      float acc = bsv + w0 * x[j] + w1 * x[j + 1] + w2 * x[j + 2] + w3 * x[j + 3];
      xbc[(size_t)(t0 + j) * CONVDIM + ch] = f2b(acc / (1.f + __expf(-acc)));
    }
  } else {
    int idx = (bid - CONV_BLOCKS) * 256 + threadIdx.x;   // 2*L_SEQ*NHEADS
    int h = idx % NHEADS;
    int t = (idx / NHEADS) % L_SEQ;
    int b = idx / (NHEADS * L_SEQ);
    float v;
    if (b == 0) v = b2f(zx[(size_t)t * DPROJ + 4608 + h]);
    else        v = b2f(zx[(size_t)(L_SEQ - 1 - t) * DPROJ + 4608 + NHEADS + h]);
    v += dt_bias[h];
    dt2[idx] = (v > 20.f) ? v : log1pf(expf(v));
  }
}

// ---------------- G[b,c,l,s] = sum_n C[l,n]*B[s,n]  (MFMA, quarter-split) ----------------
// 4 blocks per (b,c); block handles 32 l-rows. Waves above the diagonal skip compute
// (upper triangle of G is never consumed).
__global__ __launch_bounds__(256) void gmat_kernel(
    const bf16* __restrict__ xbc, bf16* __restrict__ G) {
  __shared__ bf16 Cs[32][136];   // C[l0+l][n]  8.5 KB
  __shared__ bf16 Bs[128][136];  // B[s][n]     34 KB
  int blk = blockIdx.x;          // (b*32+c)*4 + quarter
  int quarter = blk & 3;
  int bc = blk >> 2;
  int b = bc / NCHUNK, c = bc % NCHUNK;
  int l0 = quarter * 32;
  int tid = threadIdx.x;
  int lane = tid & 63;
  int w = tid >> 6;
  int bofs = b ? 2304 : 2048;
  int cofs = b ? 2432 : 2176;
  for (int o = tid; o < CHUNKL * DSTATE / 8; o += 256) {   // 2048 vecs
    int s = o >> 4;
    int n8 = (o & 15) * 8;
    int t = b ? (L_SEQ - 1 - (c * CHUNKL + s)) : (c * CHUNKL + s);
    *(bf16x8v*)&Bs[s][n8] = *(const bf16x8v*)&xbc[(size_t)t * CONVDIM + bofs + n8];
  }
  for (int o = tid; o < 32 * DSTATE / 8; o += 256) {       // 512 vecs
    int l = o >> 4;
    int n8 = (o & 15) * 8;
    int t = b ? (L_SEQ - 1 - (c * CHUNKL + l0 + l)) : (c * CHUNKL + l0 + l);
    *(bf16x8v*)&Cs[l][n8] = *(const bf16x8v*)&xbc[(size_t)t * CONVDIM + cofs + n8];
  }
  __syncthreads();
  if (w > quarter) return;   // s-tiles 2w,2w+1 start at s=32w > l0+31: masked at use
  f32x4v acc[2][2];
#pragma unroll
  for (int i = 0; i < 2; i++)
#pragma unroll
    for (int j = 0; j < 2; j++) acc[i][j] = (f32x4v){0.f, 0.f, 0.f, 0.f};
#pragma unroll
  for (int k0 = 0; k0 < 128; k0 += 32) {
    bf16x8v a0 = *(const bf16x8v*)&Cs[(lane & 15)][(lane >> 4) * 8 + k0];
    bf16x8v a1 = *(const bf16x8v*)&Cs[16 + (lane & 15)][(lane >> 4) * 8 + k0];
#pragma unroll
    for (int j = 0; j < 2; j++) {
      bf16x8v bv = *(const bf16x8v*)&Bs[(2 * w + j) * 16 + (lane & 15)][(lane >> 4) * 8 + k0];
      acc[0][j] = __builtin_amdgcn_mfma_f32_16x16x32_bf16(a0, bv, acc[0][j], 0, 0, 0);
      acc[1][j] = __builtin_amdgcn_mfma_f32_16x16x32_bf16(a1, bv, acc[1][j], 0, 0, 0);
    }
  }
  int quad = lane >> 4, cn = lane & 15;
  bf16* Gb = G + (size_t)bc * CHUNKL * CHUNKL;
#pragma unroll
  for (int i = 0; i < 2; i++)
#pragma unroll
    for (int j = 0; j < 2; j++)
#pragma unroll
      for (int r = 0; r < 4; r++) {
        int l = l0 + i * 16 + quad * 4 + r;
        int s = (2 * w + j) * 16 + cn;
        Gb[l * CHUNKL + s] = f2b(acc[i][j][r]);
      }
}

// ---------------- per-(b,c,h): chunk states only (MFMA, bf16 out) ----------------
__global__ __launch_bounds__(256) void chunk_kernel(
    const bf16* __restrict__ xbc, const float* __restrict__ dt2,
    const float* __restrict__ A_log,
    bf16* __restrict__ states, float* __restrict__ csum) {
  int gid = blockIdx.x;           // (b*32+c)*32 + h
  int h = gid % NHEADS;
  int bc = gid / NHEADS;
  int c = bc % NCHUNK, b = bc / NCHUNK;
  int tid = threadIdx.x;
  int lane = tid & 63;
  int w = tid >> 6;
  __shared__ bf16 BdT[128][136];  // [n][l] = B[l][n]*decay[l]  34 KB
  __shared__ bf16 xdtT[64][136];  // [p][s] = x[s,p]*dt[s]      17 KB
  __shared__ float acs[CHUNKL];
  __shared__ float dtl[CHUNKL];
  __shared__ float decays[CHUNKL];
  if (tid < CHUNKL)
    dtl[tid] = dt2[((size_t)b * L_SEQ + c * CHUNKL + tid) * NHEADS + h];
  __syncthreads();
  if (tid == 0) {
    float Ah = -__expf(A_log[h]);
    float s = 0.f;
    for (int l = 0; l < CHUNKL; l++) { s += Ah * dtl[l]; acs[l] = s; }
    csum[gid] = __expf(s);        // stored pre-exponentiated for scan
  }
  __syncthreads();
  if (tid < CHUNKL) decays[tid] = __expf(acs[CHUNKL - 1] - acs[tid]);
  // xdtT[p][s] staging: lane->s (t-strided 16B loads), conflict-free scatter
  for (int o = tid; o < CHUNKL * HEADDIM / 8; o += 256) {   // 1024 vecs
    int s = o & 127;
    int p8 = (o >> 7) * 8;
    int t = b ? (L_SEQ - 1 - (c * CHUNKL + s)) : (c * CHUNKL + s);
    bf16x8v xv = *(const bf16x8v*)&xbc[(size_t)t * CONVDIM + h * HEADDIM + p8];
    float d = dtl[s];
#pragma unroll
    for (int j = 0; j < 8; j++) xdtT[p8 + j][s] = f2b(sh2f(xv[j]) * d);
  }
  __syncthreads();   // decays ready
  // BdT[n][l] staging: lane->l, conflict-free scatter
  for (int o = tid; o < CHUNKL * CHUNKL / 8; o += 256) {    // 2048 vecs
    int l = o & 127;
    int n8 = (o >> 7) * 8;
    int t = b ? (L_SEQ - 1 - (c * CHUNKL + l)) : (c * CHUNKL + l);
    bf16x8v bv = *(const bf16x8v*)&xbc[(size_t)t * CONVDIM + (b ? 2304 : 2048) + n8];
    float d = decays[l];
#pragma unroll
    for (int j = 0; j < 8; j++) BdT[n8 + j][l] = f2b(sh2f(bv[j]) * d);
  }
  __syncthreads();
  // states[p][n] = sum_l xdtT[p][l]*BdT[n][l]; wave w -> p rows [16w,16w+16)
  f32x4v accS[8];
#pragma unroll
  for (int j = 0; j < 8; j++) accS[j] = (f32x4v){0.f, 0.f, 0.f, 0.f};
#pragma unroll
  for (int k0 = 0; k0 < 128; k0 += 32) {
    bf16x8v av = *(const bf16x8v*)&xdtT[w * 16 + (lane & 15)][(lane >> 4) * 8 + k0];
#pragma unroll
    for (int j = 0; j < 8; j++) {
      bf16x8v bv = *(const bf16x8v*)&BdT[j * 16 + (lane & 15)][(lane >> 4) * 8 + k0];
      accS[j] = __builtin_amdgcn_mfma_f32_16x16x32_bf16(av, bv, accS[j], 0, 0, 0);
    }
  }
  int quad = lane >> 4, cn = lane & 15;
  bf16* st = states + (size_t)gid * (HEADDIM * DSTATE);
#pragma unroll
  for (int j = 0; j < 8; j++)
#pragma unroll
    for (int r = 0; r < 4; r++) {
      int p = w * 16 + quad * 4 + r;
      int n = j * 16 + cn;
      st[p * DSTATE + n] = f2b(accS[j][r]);
    }
}

// ---------------- inter-chunk scan: register-batched (independent loads first) --------
__global__ __launch_bounds__(256) void scan_kernel(
    bf16* __restrict__ states, const float* __restrict__ csum) {
  int idx = blockIdx.x * 256 + threadIdx.x;  // 2*NHEADS*HEADDIM*DSTATE
  int n = idx % DSTATE;
  int p = (idx / DSTATE) % HEADDIM;
  int h = (idx / (DSTATE * HEADDIM)) % NHEADS;
  int b = idx / (DSTATE * HEADDIM * NHEADS);
  size_t base = ((size_t)(b * NCHUNK) * NHEADS + h) * (HEADDIM * DSTATE) + p * DSTATE + n;
  const size_t cstride = (size_t)NHEADS * HEADDIM * DSTATE;
  float tmp[NCHUNK], cv[NCHUNK];
#pragma unroll
  for (int c = 0; c < NCHUNK; c++) tmp[c] = b2f(states[base + c * cstride]);
#pragma unroll
  for (int c = 0; c < NCHUNK; c++) cv[c] = csum[(b * NCHUNK + c) * NHEADS + h];
  float S = 0.f;
#pragma unroll
  for (int c = 0; c < NCHUNK; c++) {
    states[base + c * cstride] = f2b(S);
    S = cv[c] * S + tmp[c];
  }
}

// ---------------- fused Y = Y_diag + Y_off + D*x (MFMA, single bf16 write) ----------------
// R7: l-split -- each (b,c,h) tile handled by TWO blocks of 64 l-rows (half = blk&1).
// LDS 53.8 -> 36.4 KB => 4 blocks/CU (16 waves/CU, was 12); grid 2048 -> 4096.
// Serial tid-0 cumsum replaced by wave-parallel shfl_up scan (2 elems/lane).
// Upper-triangle skips: whole-vec zero in W staging (no expf) and wave-uniform
// k0 > l_max break in Y_diag (half-0 blocks do half the MFMA).
__global__ __launch_bounds__(256) void yoff_kernel(
    const bf16* __restrict__ xbc, const float* __restrict__ dt2,
    const float* __restrict__ A_log, const bf16* __restrict__ G,
    const bf16* __restrict__ states, const float* __restrict__ Dp,
    bf16* __restrict__ Y) {
  int blk = blockIdx.x;            // ((b*32+c)*32 + h)*2 + half
  int half = blk & 1;
  int gid = blk >> 1;
  int h = gid % NHEADS;
  int bc = gid / NHEADS;
  int c = bc % NCHUNK, b = bc / NCHUNK;
  int l0 = half * 64;
  int tid = threadIdx.x;
  int lane = tid & 63;
  int w = tid >> 6;
  __shared__ bf16 WB[64][136];    // 17.4 KB (W l-half, then Ce l-half)
  __shared__ bf16 SX[64][136];    // 17.4 KB (xdtT, then St)
  __shared__ float acs[CHUNKL];
  __shared__ float dtl[CHUNKL];
  __shared__ float eAl[CHUNKL];
  if (tid < CHUNKL)
    dtl[tid] = dt2[((size_t)b * L_SEQ + c * CHUNKL + tid) * NHEADS + h];
  __syncthreads();
  // wave-parallel inclusive scan of Ah*dtl (128 elems, 2/lane, wave 0 only)
  if (tid < 64) {
    float Ah = -__expf(A_log[h]);
    float v0 = Ah * dtl[2 * tid];
    float v1 = Ah * dtl[2 * tid + 1];
    float s = v0 + v1;
#pragma unroll
    for (int off = 1; off < 64; off <<= 1) {
      float t = __shfl_up(s, off);
      if (tid >= off) s += t;
    }
    acs[2 * tid]     = s - v1;
    acs[2 * tid + 1] = s;
  }
  __syncthreads();
  if (tid < CHUNKL) eAl[tid] = __expf(acs[tid]);   // <= 1
  // SX <- xdtT[p][s]: lane->s, conflict-free scatter (full s range)
  for (int o = tid; o < CHUNKL * HEADDIM / 8; o += 256) {   // 1024 vecs
    int s = o & 127;
    int p8 = (o >> 7) * 8;
    int t = b ? (L_SEQ - 1 - (c * CHUNKL + s)) : (c * CHUNKL + s);
    bf16x8v xv = *(const bf16x8v*)&xbc[(size_t)t * CONVDIM + h * HEADDIM + p8];
    float d = dtl[s];
#pragma unroll
    for (int j = 0; j < 8; j++) SX[p8 + j][s] = f2b(sh2f(xv[j]) * d);
  }
  // WB <- W[l][s] = G*exp(acs[l]-acs[s]) (s<=l), rows [l0,l0+64): b128 writes.
  // Whole-vec upper-tri (s8 > l) skips the G load and the 8 expf.
  {
    const bf16* Gb = G + (size_t)bc * CHUNKL * CHUNKL;
    for (int o = tid; o < 64 * CHUNKL / 8; o += 256) {  // 1024 vecs
      int ll = o >> 4;
      int l = l0 + ll;
      int s8 = (o & 15) * 8;
      bf16x8v wv;
      if (s8 > l) {
#pragma unroll
        for (int j = 0; j < 8; j++) wv[j] = 0;
      } else {
        bf16x8v g = *(const bf16x8v*)&Gb[l * CHUNKL + s8];
        float al = acs[l];
#pragma unroll
        for (int j = 0; j < 8; j++) {
          int s = s8 + j;
          float e = (s <= l) ? sh2f(g[j]) * __expf(al - acs[s]) : 0.f;
          wv[j] = f2bs(e);
        }
      }
      *(bf16x8v*)&WB[ll][s8] = wv;
    }
  }
  __syncthreads();
  f32x4v accY[4];
#pragma unroll
  for (int j = 0; j < 4; j++) accY[j] = (f32x4v){0.f, 0.f, 0.f, 0.f};
  // Y_diag: A=W rows [16w,16w+16) local, B=xdtT p-tiles, k=s.
  // Wave-uniform skip: k0 > max row index => W block all-zero.
  const int kcap = l0 + w * 16 + 15;
#pragma unroll
  for (int k0 = 0; k0 < 128; k0 += 32) {
    if (k0 > kcap) break;
    bf16x8v a0 = *(const bf16x8v*)&WB[w * 16 + (lane & 15)][(lane >> 4) * 8 + k0];
#pragma unroll
    for (int j = 0; j < 4; j++) {
      bf16x8v bv = *(const bf16x8v*)&SX[j * 16 + (lane & 15)][(lane >> 4) * 8 + k0];
      accY[j] = __builtin_amdgcn_mfma_f32_16x16x32_bf16(a0, bv, accY[j], 0, 0, 0);
    }
  }
  __syncthreads();   // all phase-1 LDS reads done
  // restage: WB <- Ce[l][n] rows [l0,l0+64), SX <- St (16B copies)
  {
    int cofs = b ? 2432 : 2176;
    for (int o = tid; o < 64 * DSTATE / 8; o += 256) {      // 1024 vecs
      int ll = o >> 4;
      int l = l0 + ll;
      int n8 = (o & 15) * 8;
      int t = b ? (L_SEQ - 1 - (c * CHUNKL + l)) : (c * CHUNKL + l);
      bf16x8v cv = *(const bf16x8v*)&xbc[(size_t)t * CONVDIM + cofs + n8];
      float e = eAl[l];
      bf16x8v ov;
#pragma unroll
      for (int j = 0; j < 8; j++) ov[j] = f2bs(sh2f(cv[j]) * e);
      *(bf16x8v*)&WB[ll][n8] = ov;
    }
    const bf16* stp = states + (size_t)gid * (HEADDIM * DSTATE);
    for (int o = tid; o < HEADDIM * DSTATE / 8; o += 256) { // 1024 vecs
      int p = o >> 4;
      int n8 = (o & 15) * 8;
      *(bf16x8v*)&SX[p][n8] = *(const bf16x8v*)&stp[o * 8];
    }
  }
  __syncthreads();
  // Y_off: A=Ce rows, B=St p-tiles, k=n; accumulate into same accY
#pragma unroll
  for (int k0 = 0; k0 < 128; k0 += 32) {
    bf16x8v a0 = *(const bf16x8v*)&WB[w * 16 + (lane & 15)][(lane >> 4) * 8 + k0];
#pragma unroll
    for (int j = 0; j < 4; j++) {
      bf16x8v bv = *(const bf16x8v*)&SX[j * 16 + (lane & 15)][(lane >> 4) * 8 + k0];
      accY[j] = __builtin_amdgcn_mfma_f32_16x16x32_bf16(a0, bv, accY[j], 0, 0, 0);
    }
  }
  int quad = lane >> 4, cn = lane & 15;
  float Dh = Dp[h];
#pragma unroll
  for (int j = 0; j < 4; j++)
#pragma unroll
    for (int r = 0; r < 4; r++) {
      int l = l0 + w * 16 + quad * 4 + r;
      int p = j * 16 + cn;
      int t = b ? (L_SEQ - 1 - (c * CHUNKL + l)) : (c * CHUNKL + l);
      float xv = b2f(xbc[(size_t)t * CONVDIM + h * HEADDIM + p]);
      size_t yi = ((size_t)b * L_SEQ + c * CHUNKL + l) * DINNER + h * HEADDIM + p;
      Y[yi] = f2b(accY[j][r] + xv * Dh);
    }
}

// ---------------- combine: shift, flip, +x*fd, gate, RMSNorm (vectorized) ----------------
__global__ __launch_bounds__(256) void combine_kernel(
    const bf16* __restrict__ Y, const bf16* __restrict__ xbc,
    const bf16* __restrict__ zx, const float* __restrict__ fd,
    const float* __restrict__ norm_w, bf16* __restrict__ yn) {
  int t = blockIdx.x;
  int tid = threadIdx.x;
  int j8 = tid * 8;
  float yf[8], yb[8];
#pragma unroll
  for (int j = 0; j < 8; j++) { yf[j] = 0.f; yb[j] = 0.f; }
  if (t >= 1) {
    bf16x8v v = *(const bf16x8v*)&Y[(size_t)(t - 1) * DINNER + j8];
#pragma unroll
    for (int j = 0; j < 8; j++) yf[j] = sh2f(v[j]);
  }
  if (t <= L_SEQ - 2) {
    bf16x8v v = *(const bf16x8v*)&Y[((size_t)L_SEQ + (L_SEQ - 2 - t)) * DINNER + j8];
#pragma unroll
    for (int j = 0; j < 8; j++) yb[j] = sh2f(v[j]);
  }
  bf16x8v xogv = *(const bf16x8v*)&xbc[(size_t)t * CONVDIM + j8];
  bf16x8v zv = *(const bf16x8v*)&zx[(size_t)t * DPROJ + j8];
  float fdv = fd[t * NHEADS + (j8 >> 6)];
  float yg[8];
  float ss = 0.f;
#pragma unroll
  for (int j = 0; j < 8; j++) {
    float y = yf[j] + yb[j] + sh2f(xogv[j]) * fdv;
    float z = sh2f(zv[j]);
    float g = y * (z / (1.f + __expf(-z)));
    yg[j] = g;
    ss += g * g;
  }
#pragma unroll
  for (int off = 32; off > 0; off >>= 1) ss += __shfl_down(ss, off);
  __shared__ float red[4];
  if ((tid & 63) == 0) red[tid >> 6] = ss;
  __syncthreads();
  float tot = red[0] + red[1] + red[2] + red[3];
  float scale = rsqrtf(tot / (float)DINNER + 1e-5f);
  float4 nw0 = *(const float4*)&norm_w[j8];
  float4 nw1 = *(const float4*)&norm_w[j8 + 4];
  bf16x8v ov;
  ov[0] = f2bs(yg[0] * scale * nw0.x);
  ov[1] = f2bs(yg[1] * scale * nw0.y);
  ov[2] = f2bs(yg[2] * scale * nw0.z);
  ov[3] = f2bs(yg[3] * scale * nw0.w);
  ov[4] = f2bs(yg[4] * scale * nw1.x);
  ov[5] = f2bs(yg[5] * scale * nw1.y);
  ov[6] = f2bs(yg[6] * scale * nw1.z);
  ov[7] = f2bs(yg[7] * scale * nw1.w);
  *(bf16x8v*)&yn[(size_t)t * DINNER + j8] = ov;
}

// ---------------- launch ----------------
extern "C" void kernel_launch(void* const* d_in, const int* in_sizes, int n_in,
                              void* d_out, int out_size, void* d_ws, size_t ws_size,
                              hipStream_t stream) {
  const float* u         = (const float*)d_in[0];
  const float* in_proj_w = (const float*)d_in[1];
  const float* conv_w    = (const float*)d_in[2];
  const float* conv_b    = (const float*)d_in[3];
  const float* dt_bias   = (const float*)d_in[4];
  const float* A_log     = (const float*)d_in[5];
  const float* Dp        = (const float*)d_in[6];
  const float* fc_D_w    = (const float*)d_in[7];
  const float* norm_w    = (const float*)d_in[8];
  const float* out_proj_w= (const float*)d_in[9];
  float* out = (float*)d_out;

  char* base = (char*)d_ws;
  bf16*  zx  = (bf16*)base;  base += (size_t)L_SEQ * DPROJ * 2;                    // 38.3 MB
  bf16*  xbc = (bf16*)base;  base += (size_t)L_SEQ * CONVDIM * 2;                  // 21.0 MB
  float* dt2 = (float*)base; base += (size_t)2 * L_SEQ * NHEADS * 4;               //  1.0 MB
  bf16*  G   = (bf16*)base;  base += (size_t)2 * NCHUNK * CHUNKL * CHUNKL * 4;     //  4.2 MB region
  bf16*  Yb  = (bf16*)base;  base += (size_t)2 * L_SEQ * DINNER * 4;               // 67.1 MB region
  bf16*  stb = (bf16*)base;  base += (size_t)2 * NCHUNK * NHEADS * HEADDIM * DSTATE * 4; // 67.1 MB region
  float* cs  = (float*)base; base += (size_t)2 * NCHUNK * NHEADS * 4;              //  8 KB
  // aliases into dead regions:
  bf16*  u_bf   = (bf16*)Yb;                          // 8.4 MB   (Yb live only after yoff)
  bf16*  w1p_bf = (bf16*)((char*)Yb + 9437184);       // 9.7 MB   (in_proj_w padded to 4736 rows)
  bf16*  w2_bf  = (bf16*)G;                           // 4.2 MB   (G dead after yoff)
  bf16*  yn     = (bf16*)stb;                         // 16.8 MB  (stb dead after yoff)
  float* fd     = (float*)((char*)stb + 33554432);    //  0.5 MB

  // 0. fused casts for MFMA gemm1 (w1 zero-padded to NPAD1 rows)
  cast2_kernel<<<(L_SEQ * DMODEL + NPAD1 * DMODEL) / 256, 256, 0, stream>>>(
      u, in_proj_w, u_bf, w1p_bf);
  // 1a. in_proj main: cols [0,4096) (8-phase 256^2, 256 blocks = exactly 1 round)
  gemm1_8ph<<<(L_SEQ / 256) * G1_GN, 512, 0, stream>>>(u_bf, w1p_bf, zx);
  // 1b. in_proj remainder: cols [4096,4672) (128^2 gemm, 160 blocks)
  gemm_mfma<bf16><<<(L_SEQ / 128) * ((NPAD1 - NSPLIT) / 128), 256, 0, stream>>>(
      u_bf, DMODEL, w1p_bf + (size_t)NSPLIT * DMODEL, DMODEL,
      zx + NSPLIT, DPROJ, DPROJ - NSPLIT, DMODEL,
      L_SEQ / 128, (NPAD1 - NSPLIT) / 128, 0);
  // 2. conv + silu + dt (fused)
  conv_dt_kernel<<<CONV_BLOCKS + (2 * L_SEQ * NHEADS) / 256, 256, 0, stream>>>(
      zx, conv_w, conv_b, xbc, dt_bias, dt2);
  // 3a. G = C B^T per (b,c), quarter-split (MFMA, bf16)
  gmat_kernel<<<2 * NCHUNK * 4, 256, 0, stream>>>(xbc, G);
  // 3b. chunk states (MFMA, bf16)
  chunk_kernel<<<2 * NCHUNK * NHEADS, 256, 0, stream>>>(
      xbc, dt2, A_log, stb, cs);
  // 3c. inter-chunk scan (register-batched)
  scan_kernel<<<(2 * NHEADS * HEADDIM * DSTATE) / 256, 256, 0, stream>>>(stb, cs);
  // 3d. fused Y = Y_diag + Y_off + D*x (MFMA, l-split: 2 blocks per (b,c,h))
  yoff_kernel<<<2 * NCHUNK * NHEADS * 2, 256, 0, stream>>>(
      xbc, dt2, A_log, G, stb, Dp, Yb);
  // 4a. cast out_proj_w (into dead G region)
  cast_kernel<<<(DMODEL * DINNER + 255) / 256, 256, 0, stream>>>(
      out_proj_w, w2_bf, DMODEL * DINNER, DMODEL * DINNER);
  // 4b. fd = x_og @ fc_D_w^T + D  (k-split across waves, 1024 blocks)
  fc_kernel<<<L_SEQ / 4, 256, 0, stream>>>(xbc, fc_D_w, Dp, fd);
  // 5. combine + gate + RMSNorm
  combine_kernel<<<L_SEQ, 256, 0, stream>>>(Yb, xbc, zx, fd, norm_w, yn);
  // 6. out_proj (MFMA, XCD-swizzled: 256 blocks = 1/CU, swizzle's home case)
  gemm_mfma<float><<<(L_SEQ / 128) * (DMODEL / 128), 256, 0, stream>>>(
      yn, DINNER, w2_bf, DINNER, out, DMODEL, DMODEL, DINNER,
      L_SEQ / 128, DMODEL / 128, 1);
}

// Round 8
// 398.085 us; speedup vs baseline: 1.0178x; 1.0178x over previous
//
#include <hip/hip_runtime.h>
#include <hip/hip_bf16.h>
#include <math.h>

// ---------------- problem constants ----------------
#define L_SEQ   4096
#define DMODEL  1024
#define DINNER  2048
#define NHEADS  32
#define HEADDIM 64
#define DSTATE  128
#define NCHUNK  32
#define CHUNKL  128
#define CONVDIM 2560
#define DPROJ   4672   // 2*DINNER + 2*(2*DSTATE) + 2*NHEADS
#define NPAD1   4736   // DPROJ padded to multiple of 128 (for remainder gemm)
#define NSPLIT  4096   // cols [0,NSPLIT) via 8-phase 256^2 (256 blocks = 1 round);
                       // cols [NSPLIT,DPROJ) via 128^2 gemm (160 blocks)

typedef __hip_bfloat16 bf16;
__device__ __forceinline__ float b2f(bf16 x) { return __bfloat162float(x); }
__device__ __forceinline__ bf16 f2b(float x) { return __float2bfloat16(x); }
__device__ __forceinline__ float sh2f(short s) {
  return __uint_as_float(((unsigned int)(unsigned short)s) << 16);
}
__device__ __forceinline__ short f2bs(float x) {
  bf16 t = __float2bfloat16(x);
  return *reinterpret_cast<short*>(&t);
}

typedef __attribute__((ext_vector_type(8))) short bf16x8v;
typedef __attribute__((ext_vector_type(4))) float f32x4v;

__device__ __forceinline__ float dot8(bf16x8v x, float4 w0, float4 w1) {
  return sh2f(x[0]) * w0.x + sh2f(x[1]) * w0.y + sh2f(x[2]) * w0.z + sh2f(x[3]) * w0.w +
         sh2f(x[4]) * w1.x + sh2f(x[5]) * w1.y + sh2f(x[6]) * w1.z + sh2f(x[7]) * w1.w;
}

// zxbcdt column layout: [0,2048) = z ; [2048,4608) = xBC ; [4608,4672) = dt raw
// xBC_conv channel layout: [0,2048) = x ; fw B = [2048,2176) C = [2176,2304)
//                          bw B = [2304,2432) C = [2432,2560)  (bw streams time-flipped)

// ---------------- fused casts: u -> bf16 and in_proj_w -> bf16 (zero-padded) ----------------
__global__ __launch_bounds__(256) void cast2_kernel(
    const float* __restrict__ u, const float* __restrict__ w1,
    bf16* __restrict__ u_bf, bf16* __restrict__ w1_bf) {
  const int NU = (L_SEQ * DMODEL) / 256;   // 16384 blocks
  int bid = blockIdx.x;
  if (bid < NU) {
    int i = bid * 256 + threadIdx.x;
    u_bf[i] = f2b(u[i]);
  } else {
    int i = (bid - NU) * 256 + threadIdx.x;
    w1_bf[i] = (i < DPROJ * DMODEL) ? f2b(w1[i]) : f2b(0.f);
  }
}

// ---------------- f32 -> bf16 cast ----------------
__global__ __launch_bounds__(256) void cast_kernel(
    const float* __restrict__ src, bf16* __restrict__ dst, int n_src, int n_tot) {
  int i = blockIdx.x * 256 + threadIdx.x;
  if (i < n_tot) dst[i] = (i < n_src) ? f2b(src[i]) : f2b(0.f);
}

// ================= in_proj main: 8-phase 256x256 GEMM (R1-verified body) =================
// C[m,n] = sum_k A[m,k]*B[n,k]; A = u_bf [4096][1024], B = w1p_bf rows [0,4096),
// C = zx cols [0,4096). BK=64, 512 threads = 8 waves (2Mx4N), per-wave C = 128x64.
// Grid = 16 x 16 = 256 blocks = exactly one residency round (128 KiB LDS -> 1/CU).
// Register budget (the R2/R3 lesson): acc[8][4] = 128 regs + a/b frags 64 + addr
// ~= 244 <= 256-reg cap at 2 waves/SIMD. BN=320 (acc 160) does NOT fit -- spills.
// LDS: 2 dbuf slots x (A 256x64 + B 256x64), 16 subtiles of [16r][32c] per 128x64
// half, st_16x32 XOR swizzle via pre-swizzled global source (linear gload_lds dest)
// + swizzled ds_read addr. vmcnt(6) once per K-tile; vmcnt(0) only at t=NT-2.
#define G1_K  1024
#define G1_GN 16            // N tiles of 256 covering [0,4096)
#define G1_NT (G1_K / 64)   // 16 K-tiles

__global__ __launch_bounds__(512, 2) void gemm1_8ph(
    const bf16* __restrict__ A, const bf16* __restrict__ B, bf16* __restrict__ C) {
  __shared__ bf16 Al[2][2][8192];   // [slot][half][subtiled 128x64]  64 KB
  __shared__ bf16 Bl[2][2][8192];   // 64 KB
  const int tid = threadIdx.x;
  const int lane = tid & 63;
  const int w = tid >> 6;        // 0..7
  const int wm = w >> 2;         // 0..1 -> C rows [wm*128, +128)
  const int wn = w & 3;          // 0..3 -> C cols [wn*64, +64)
  const int bm = (blockIdx.x / G1_GN) * 256;
  const int bn = (blockIdx.x % G1_GN) * 256;
  // staging source pre-swizzle (bf16 units): dest r_in = lane>>2, swz bit = r_in bit3
  const int scol = ((lane & 3) ^ (((lane >> 5) & 1) << 1)) * 8;
  // read-side swizzled col within subtile: flip bit4 when row bit3 set
  const int cin = ((lane >> 4) * 8) ^ (((lane >> 3) & 1) << 4);
  const int r16 = lane & 15;
  const bf16* Ag = A + (size_t)bm * G1_K;
  const bf16* Bg = B + (size_t)bn * G1_K;

  // stage one 128x64 half-tile (A: mat=0, B: mat=1) of K-tile tt.
  // wave w fills subtiles w and 8+w (1024B each, linear dest; swizzle via source).
  auto stage = [&](int mat, int tt, int hf) {
    const bf16* g = (mat ? Bg : Ag)
        + (size_t)(hf * 128 + (w >> 1) * 16 + (lane >> 2)) * G1_K
        + tt * 64 + (w & 1) * 32 + scol;
    bf16* d0 = mat ? &Bl[tt & 1][hf][0] : &Al[tt & 1][hf][0];
    __builtin_amdgcn_global_load_lds(
        (const __attribute__((address_space(1))) void*)g,
        (__attribute__((address_space(3))) void*)(d0 + w * 512), 16, 0, 0);
    __builtin_amdgcn_global_load_lds(
        (const __attribute__((address_space(1))) void*)(g + (size_t)64 * G1_K),
        (__attribute__((address_space(3))) void*)(d0 + (8 + w) * 512), 16, 0, 0);
  };

  f32x4v acc[8][4];
#pragma unroll
  for (int i = 0; i < 8; i++)
#pragma unroll
    for (int j = 0; j < 4; j++) acc[i][j] = (f32x4v){0.f, 0.f, 0.f, 0.f};

  // prologue: tile0 {A0,A1,B0,B1}, tile1 {A0,A1,B0} = 7 half-tiles (14 loads)
  stage(0, 0, 0); stage(0, 0, 1); stage(1, 0, 0); stage(1, 0, 1);
  stage(0, 1, 0); stage(0, 1, 1); stage(1, 1, 0);
  asm volatile("s_waitcnt vmcnt(6)" ::: "memory");   // tile0 fully resident
  __builtin_amdgcn_s_barrier();
  __builtin_amdgcn_sched_barrier(0);

#pragma unroll 2
  for (int t = 0; t < G1_NT; ++t) {
    const int slot = t & 1;
    const bf16* Ah = &Al[slot][wm][0];
    const bf16* Bh = &Bl[slot][wn >> 1][0];
    const int brb = (wn & 1) * 4;   // B subtile-row base within half
    bf16x8v a[4][2], b[4][2];
    // ---- phase 0: ds A m0-3 + B n0-1 (12 reads); stage B1(t+1); mfma m0-3 x n0-1
#pragma unroll
    for (int i = 0; i < 4; i++) {
      a[i][0] = *(const bf16x8v*)&Ah[(i * 2 + 0) * 512 + r16 * 32 + cin];
      a[i][1] = *(const bf16x8v*)&Ah[(i * 2 + 1) * 512 + r16 * 32 + cin];
    }
#pragma unroll
    for (int j = 0; j < 2; j++) {
      b[j][0] = *(const bf16x8v*)&Bh[((brb + j) * 2 + 0) * 512 + r16 * 32 + cin];
      b[j][1] = *(const bf16x8v*)&Bh[((brb + j) * 2 + 1) * 512 + r16 * 32 + cin];
    }
    if (t + 1 < G1_NT) stage(1, t + 1, 1);
    __builtin_amdgcn_s_barrier();
    asm volatile("s_waitcnt lgkmcnt(0)" ::: "memory");
    __builtin_amdgcn_s_setprio(1);
#pragma unroll
    for (int i = 0; i < 4; i++)
#pragma unroll
      for (int j = 0; j < 2; j++) {
        acc[i][j] = __builtin_amdgcn_mfma_f32_16x16x32_bf16(a[i][0], b[j][0], acc[i][j], 0, 0, 0);
        acc[i][j] = __builtin_amdgcn_mfma_f32_16x16x32_bf16(a[i][1], b[j][1], acc[i][j], 0, 0, 0);
      }
    __builtin_amdgcn_s_setprio(0);
    __builtin_amdgcn_s_barrier();
    // ---- phase 1: ds B n2-3 (4 reads); mfma m0-3 x n2-3
#pragma unroll
    for (int j = 2; j < 4; j++) {
      b[j][0] = *(const bf16x8v*)&Bh[((brb + j) * 2 + 0) * 512 + r16 * 32 + cin];
      b[j][1] = *(const bf16x8v*)&Bh[((brb + j) * 2 + 1) * 512 + r16 * 32 + cin];
    }
    __builtin_amdgcn_s_barrier();
    asm volatile("s_waitcnt lgkmcnt(0)" ::: "memory");
    __builtin_amdgcn_s_setprio(1);
#pragma unroll
    for (int i = 0; i < 4; i++)
#pragma unroll
      for (int j = 2; j < 4; j++) {
        acc[i][j] = __builtin_amdgcn_mfma_f32_16x16x32_bf16(a[i][0], b[j][0], acc[i][j], 0, 0, 0);
        acc[i][j] = __builtin_amdgcn_mfma_f32_16x16x32_bf16(a[i][1], b[j][1], acc[i][j], 0, 0, 0);
      }
    __builtin_amdgcn_s_setprio(0);
    __builtin_amdgcn_s_barrier();
    // ---- phase 2: ds A m4-7 (8 reads); stage B0(t+2); mfma m4-7 x n2-3
#pragma unroll
    for (int i = 0; i < 4; i++) {
      a[i][0] = *(const bf16x8v*)&Ah[((4 + i) * 2 + 0) * 512 + r16 * 32 + cin];
      a[i][1] = *(const bf16x8v*)&Ah[((4 + i) * 2 + 1) * 512 + r16 * 32 + cin];
    }
    if (t + 2 < G1_NT) stage(1, t + 2, 0);
    __builtin_amdgcn_s_barrier();
    asm volatile("s_waitcnt lgkmcnt(0)" ::: "memory");
    __builtin_amdgcn_s_setprio(1);
#pragma unroll
    for (int i = 0; i < 4; i++)
#pragma unroll
      for (int j = 2; j < 4; j++) {
        acc[4 + i][j] = __builtin_amdgcn_mfma_f32_16x16x32_bf16(a[i][0], b[j][0], acc[4 + i][j], 0, 0, 0);
        acc[4 + i][j] = __builtin_amdgcn_mfma_f32_16x16x32_bf16(a[i][1], b[j][1], acc[4 + i][j], 0, 0, 0);
      }
    __builtin_amdgcn_s_setprio(0);
    __builtin_amdgcn_s_barrier();
    // ---- phase 3: stage A0,A1(t+2); mfma m4-7 x n0-1; counted vmcnt; barrier
    if (t + 2 < G1_NT) { stage(0, t + 2, 0); stage(0, t + 2, 1); }
    __builtin_amdgcn_s_barrier();
    __builtin_amdgcn_s_setprio(1);
#pragma unroll
    for (int i = 0; i < 4; i++)
#pragma unroll
      for (int j = 0; j < 2; j++) {
        acc[4 + i][j] = __builtin_amdgcn_mfma_f32_16x16x32_bf16(a[i][0], b[j][0], acc[4 + i][j], 0, 0, 0);
        acc[4 + i][j] = __builtin_amdgcn_mfma_f32_16x16x32_bf16(a[i][1], b[j][1], acc[4 + i][j], 0, 0, 0);
      }
    __builtin_amdgcn_s_setprio(0);
    if (t < G1_NT - 2)       asm volatile("s_waitcnt vmcnt(6)" ::: "memory");
    else if (t == G1_NT - 2) asm volatile("s_waitcnt vmcnt(0)" ::: "memory");
    __builtin_amdgcn_s_barrier();
    __builtin_amdgcn_sched_barrier(0);
  }

  const int quad = lane >> 4;
  const int cn = lane & 15;
#pragma unroll
  for (int i = 0; i < 8; i++)
#pragma unroll
    for (int j = 0; j < 4; j++) {
      int col = bn + wn * 64 + j * 16 + cn;
      if (col < DPROJ) {
#pragma unroll
        for (int r = 0; r < 4; r++) {
          int row = bm + wm * 128 + i * 16 + quad * 4 + r;
          C[(size_t)row * DPROJ + col] = f2b(acc[i][j][r]);
        }
      }
    }
}

// ---------------- MFMA GEMM: C[m,n] = sum_k A[m,k]*B[n,k], bf16 in, f32 acc ----------------
// (used for the in_proj N-remainder and for out_proj)
template <typename TC>
__global__ __launch_bounds__(256) void gemm_mfma(
    const bf16* __restrict__ A, int lda,
    const bf16* __restrict__ B, int ldb,
    TC* __restrict__ C, int ldc,
    int N, int K, int gridM, int gridN, int swz) {
  __shared__ short As[128][32];
  __shared__ short Bs[128][32];
  int tid = threadIdx.x;
  int lane = tid & 63;
  int w = tid >> 6;            // wave 0..3
  int wr = w >> 1, wc = w & 1; // 2x2 wave grid
  int bid = blockIdx.x;
  int bm, bn;
  if (swz) {
    int mst = gridM >> 3;
    int xk = bid & 7, q = bid >> 3;
    bm = (xk + 8 * (q % mst)) * 128;
    bn = (q / mst) * 128;
  } else {
    bm = (bid / gridN) * 128;
    bn = (bid % gridN) * 128;
  }
  f32x4v acc[4][4];
#pragma unroll
  for (int i = 0; i < 4; i++)
#pragma unroll
    for (int j = 0; j < 4; j++) acc[i][j] = (f32x4v){0.f, 0.f, 0.f, 0.f};

  const bf16* Ab = A + (size_t)(bm + w * 32 + (lane >> 2)) * lda + (lane & 3) * 8;
  const bf16* Bb = B + (size_t)(bn + w * 32 + (lane >> 2)) * ldb + (lane & 3) * 8;

  for (int k0 = 0; k0 < K; k0 += 32) {
    __builtin_amdgcn_global_load_lds(
        (const __attribute__((address_space(1))) void*)(Ab + k0),
        (__attribute__((address_space(3))) void*)&As[w * 32][0], 16, 0, 0);
    __builtin_amdgcn_global_load_lds(
        (const __attribute__((address_space(1))) void*)(Ab + (size_t)16 * lda + k0),
        (__attribute__((address_space(3))) void*)&As[w * 32 + 16][0], 16, 0, 0);
    __builtin_amdgcn_global_load_lds(
        (const __attribute__((address_space(1))) void*)(Bb + k0),
        (__attribute__((address_space(3))) void*)&Bs[w * 32][0], 16, 0, 0);
    __builtin_amdgcn_global_load_lds(
        (const __attribute__((address_space(1))) void*)(Bb + (size_t)16 * ldb + k0),
        (__attribute__((address_space(3))) void*)&Bs[w * 32 + 16][0], 16, 0, 0);
    __syncthreads();
    bf16x8v af[4], bv[4];
#pragma unroll
    for (int i = 0; i < 4; i++)
      af[i] = *(const bf16x8v*)&As[wr * 64 + i * 16 + (lane & 15)][(lane >> 4) * 8];
#pragma unroll
    for (int j = 0; j < 4; j++)
      bv[j] = *(const bf16x8v*)&Bs[wc * 64 + j * 16 + (lane & 15)][(lane >> 4) * 8];
#pragma unroll
    for (int i = 0; i < 4; i++)
#pragma unroll
      for (int j = 0; j < 4; j++)
        acc[i][j] = __builtin_amdgcn_mfma_f32_16x16x32_bf16(af[i], bv[j], acc[i][j], 0, 0, 0);
    __syncthreads();
  }
  int quad = lane >> 4;
  int cn = lane & 15;
#pragma unroll
  for (int i = 0; i < 4; i++) {
#pragma unroll
    for (int j = 0; j < 4; j++) {
      int col = bn + wc * 64 + j * 16 + cn;
      if (col < N) {
#pragma unroll
        for (int r = 0; r < 4; r++) {
          int row = bm + wr * 64 + i * 16 + quad * 4 + r;
          float v = acc[i][j][r];
          if constexpr (sizeof(TC) == 2) C[(size_t)row * ldc + col] = f2b(v);
          else                           C[(size_t)row * ldc + col] = v;
        }
      }
    }
  }
}

// ---------------- fc_D: fd[t][h] = sum_k x[t,k]*W[h,k] + D[h] ----------------
// R6: k split across the 4 waves (512 each; lane g-split -> 256 k/lane, 32-iter
// chain) + 4x grid (1024 blocks = 4/CU, 4 waves/SIMD).
__global__ __launch_bounds__(256) void fc_kernel(
    const bf16* __restrict__ xbc, const float* __restrict__ Wf,
    const float* __restrict__ Dp, float* __restrict__ fd) {
  int lane = threadIdx.x & 63;
  int w = threadIdx.x >> 6;          // wave = k-quarter
  int t0 = blockIdx.x * 4;
  int h = lane & 31;
  int g = lane >> 5;                 // k-eighth within quarter
  int k0 = w * 512 + g * 256;
  const float* wr = Wf + (size_t)h * DINNER + k0;
  const bf16* xr = xbc + (size_t)t0 * CONVDIM + k0;
  float a0 = 0.f, a1 = 0.f, a2 = 0.f, a3 = 0.f;
#pragma unroll 4
  for (int k = 0; k < 256; k += 8) {
    float4 w0 = *(const float4*)(wr + k);
    float4 w1 = *(const float4*)(wr + k + 4);
    bf16x8v x0 = *(const bf16x8v*)(xr + k);
    bf16x8v x1 = *(const bf16x8v*)(xr + CONVDIM + k);
    bf16x8v x2 = *(const bf16x8v*)(xr + 2 * CONVDIM + k);
    bf16x8v x3 = *(const bf16x8v*)(xr + 3 * CONVDIM + k);
    a0 += dot8(x0, w0, w1);
    a1 += dot8(x1, w0, w1);
    a2 += dot8(x2, w0, w1);
    a3 += dot8(x3, w0, w1);
  }
  a0 += __shfl_down(a0, 32);
  a1 += __shfl_down(a1, 32);
  a2 += __shfl_down(a2, 32);
  a3 += __shfl_down(a3, 32);
  __shared__ float red[4][4][32];    // [wave][t][h]
  if (lane < 32) {
    red[w][0][h] = a0; red[w][1][h] = a1; red[w][2][h] = a2; red[w][3][h] = a3;
  }
  __syncthreads();
  int tid = threadIdx.x;
  if (tid < 128) {
    int tt = tid >> 5;
    int hh = tid & 31;
    float s = red[0][tt][hh] + red[1][tt][hh] + red[2][tt][hh] + red[3][tt][hh];
    fd[(t0 + tt) * NHEADS + hh] = s + Dp[hh];
  }
}

// ---------------- conv (4 t/thread) + SiLU, with dt softplus folded in ----------------
#define CONV_BLOCKS ((L_SEQ / 4) * CONVDIM / 256)   // 10240
__global__ __launch_bounds__(256) void conv_dt_kernel(
    const bf16* __restrict__ zx, const float* __restrict__ conv_w,
    const float* __restrict__ conv_b, bf16* __restrict__ xbc,
    const float* __restrict__ dt_bias, float* __restrict__ dt2) {
  int bid = blockIdx.x;
  if (bid < CONV_BLOCKS) {
    int idx = bid * 256 + threadIdx.x;
    int ch = idx % CONVDIM;
    int t0 = (idx / CONVDIM) * 4;
    const bf16* col = zx + DINNER + ch;
    float w0 = conv_w[ch * 4 + 0], w1 = conv_w[ch * 4 + 1];
    float w2 = conv_w[ch * 4 + 2], w3 = conv_w[ch * 4 + 3];
    float bsv = conv_b[ch];
    float x[7];
#pragma unroll
    for (int i = 0; i < 7; i++) {
      int t = t0 - 3 + i;
      x[i] = (t >= 0) ? b2f(col[(size_t)t * DPROJ]) : 0.f;
    }
#pragma unroll
    for (int j = 0; j < 4; j++) {
      float acc = bsv + w0 * x[j] + w1 * x[j + 1] + w2 * x[j + 2] + w3 * x[j + 3];
      xbc[(size_t)(t0 + j) * CONVDIM + ch] = f2b(acc / (1.f + __expf(-acc)));
    }
  } else {
    int idx = (bid - CONV_BLOCKS) * 256 + threadIdx.x;   // 2*L_SEQ*NHEADS
    int h = idx % NHEADS;
    int t = (idx / NHEADS) % L_SEQ;
    int b = idx / (NHEADS * L_SEQ);
    float v;
    if (b == 0) v = b2f(zx[(size_t)t * DPROJ + 4608 + h]);
    else        v = b2f(zx[(size_t)(L_SEQ - 1 - t) * DPROJ + 4608 + NHEADS + h]);
    v += dt_bias[h];
    dt2[idx] = (v > 20.f) ? v : log1pf(expf(v));
  }
}

// ---------------- G[b,c,l,s] = sum_n C[l,n]*B[s,n]  (MFMA, quarter-split) ----------------
__global__ __launch_bounds__(256) void gmat_kernel(
    const bf16* __restrict__ xbc, bf16* __restrict__ G) {
  __shared__ bf16 Cs[32][136];   // C[l0+l][n]  8.5 KB
  __shared__ bf16 Bs[128][136];  // B[s][n]     34 KB
  int blk = blockIdx.x;          // (b*32+c)*4 + quarter
  int quarter = blk & 3;
  int bc = blk >> 2;
  int b = bc / NCHUNK, c = bc % NCHUNK;
  int l0 = quarter * 32;
  int tid = threadIdx.x;
  int lane = tid & 63;
  int w = tid >> 6;
  int bofs = b ? 2304 : 2048;
  int cofs = b ? 2432 : 2176;
  for (int o = tid; o < CHUNKL * DSTATE / 8; o += 256) {   // 2048 vecs
    int s = o >> 4;
    int n8 = (o & 15) * 8;
    int t = b ? (L_SEQ - 1 - (c * CHUNKL + s)) : (c * CHUNKL + s);
    *(bf16x8v*)&Bs[s][n8] = *(const bf16x8v*)&xbc[(size_t)t * CONVDIM + bofs + n8];
  }
  for (int o = tid; o < 32 * DSTATE / 8; o += 256) {       // 512 vecs
    int l = o >> 4;
    int n8 = (o & 15) * 8;
    int t = b ? (L_SEQ - 1 - (c * CHUNKL + l0 + l)) : (c * CHUNKL + l0 + l);
    *(bf16x8v*)&Cs[l][n8] = *(const bf16x8v*)&xbc[(size_t)t * CONVDIM + cofs + n8];
  }
  __syncthreads();
  if (w > quarter) return;   // s-tiles 2w,2w+1 start at s=32w > l0+31: masked at use
  f32x4v acc[2][2];
#pragma unroll
  for (int i = 0; i < 2; i++)
#pragma unroll
    for (int j = 0; j < 2; j++) acc[i][j] = (f32x4v){0.f, 0.f, 0.f, 0.f};
#pragma unroll
  for (int k0 = 0; k0 < 128; k0 += 32) {
    bf16x8v a0 = *(const bf16x8v*)&Cs[(lane & 15)][(lane >> 4) * 8 + k0];
    bf16x8v a1 = *(const bf16x8v*)&Cs[16 + (lane & 15)][(lane >> 4) * 8 + k0];
#pragma unroll
    for (int j = 0; j < 2; j++) {
      bf16x8v bv = *(const bf16x8v*)&Bs[(2 * w + j) * 16 + (lane & 15)][(lane >> 4) * 8 + k0];
      acc[0][j] = __builtin_amdgcn_mfma_f32_16x16x32_bf16(a0, bv, acc[0][j], 0, 0, 0);
      acc[1][j] = __builtin_amdgcn_mfma_f32_16x16x32_bf16(a1, bv, acc[1][j], 0, 0, 0);
    }
  }
  int quad = lane >> 4, cn = lane & 15;
  bf16* Gb = G + (size_t)bc * CHUNKL * CHUNKL;
#pragma unroll
  for (int i = 0; i < 2; i++)
#pragma unroll
    for (int j = 0; j < 2; j++)
#pragma unroll
      for (int r = 0; r < 4; r++) {
        int l = l0 + i * 16 + quad * 4 + r;
        int s = (2 * w + j) * 16 + cn;
        Gb[l * CHUNKL + s] = f2b(acc[i][j][r]);
      }
}

// ---------------- per-(b,c,h): chunk states only (MFMA, bf16 out) ----------------
__global__ __launch_bounds__(256) void chunk_kernel(
    const bf16* __restrict__ xbc, const float* __restrict__ dt2,
    const float* __restrict__ A_log,
    bf16* __restrict__ states, float* __restrict__ csum) {
  int gid = blockIdx.x;           // (b*32+c)*32 + h
  int h = gid % NHEADS;
  int bc = gid / NHEADS;
  int c = bc % NCHUNK, b = bc / NCHUNK;
  int tid = threadIdx.x;
  int lane = tid & 63;
  int w = tid >> 6;
  __shared__ bf16 BdT[128][136];  // [n][l] = B[l][n]*decay[l]  34 KB
  __shared__ bf16 xdtT[64][136];  // [p][s] = x[s,p]*dt[s]      17 KB
  __shared__ float acs[CHUNKL];
  __shared__ float dtl[CHUNKL];
  __shared__ float decays[CHUNKL];
  if (tid < CHUNKL)
    dtl[tid] = dt2[((size_t)b * L_SEQ + c * CHUNKL + tid) * NHEADS + h];
  __syncthreads();
  if (tid == 0) {
    float Ah = -__expf(A_log[h]);
    float s = 0.f;
    for (int l = 0; l < CHUNKL; l++) { s += Ah * dtl[l]; acs[l] = s; }
    csum[gid] = __expf(s);        // stored pre-exponentiated for scan
  }
  __syncthreads();
  if (tid < CHUNKL) decays[tid] = __expf(acs[CHUNKL - 1] - acs[tid]);
  // xdtT[p][s] staging: lane->s (t-strided 16B loads), conflict-free scatter
  for (int o = tid; o < CHUNKL * HEADDIM / 8; o += 256) {   // 1024 vecs
    int s = o & 127;
    int p8 = (o >> 7) * 8;
    int t = b ? (L_SEQ - 1 - (c * CHUNKL + s)) : (c * CHUNKL + s);
    bf16x8v xv = *(const bf16x8v*)&xbc[(size_t)t * CONVDIM + h * HEADDIM + p8];
    float d = dtl[s];
#pragma unroll
    for (int j = 0; j < 8; j++) xdtT[p8 + j][s] = f2b(sh2f(xv[j]) * d);
  }
  __syncthreads();   // decays ready
  // BdT[n][l] staging: lane->l, conflict-free scatter
  for (int o = tid; o < CHUNKL * CHUNKL / 8; o += 256) {    // 2048 vecs
    int l = o & 127;
    int n8 = (o >> 7) * 8;
    int t = b ? (L_SEQ - 1 - (c * CHUNKL + l)) : (c * CHUNKL + l);
    bf16x8v bv = *(const bf16x8v*)&xbc[(size_t)t * CONVDIM + (b ? 2304 : 2048) + n8];
    float d = decays[l];
#pragma unroll
    for (int j = 0; j < 8; j++) BdT[n8 + j][l] = f2b(sh2f(bv[j]) * d);
  }
  __syncthreads();
  // states[p][n] = sum_l xdtT[p][l]*BdT[n][l]; wave w -> p rows [16w,16w+16)
  f32x4v accS[8];
#pragma unroll
  for (int j = 0; j < 8; j++) accS[j] = (f32x4v){0.f, 0.f, 0.f, 0.f};
#pragma unroll
  for (int k0 = 0; k0 < 128; k0 += 32) {
    bf16x8v av = *(const bf16x8v*)&xdtT[w * 16 + (lane & 15)][(lane >> 4) * 8 + k0];
#pragma unroll
    for (int j = 0; j < 8; j++) {
      bf16x8v bv = *(const bf16x8v*)&BdT[j * 16 + (lane & 15)][(lane >> 4) * 8 + k0];
      accS[j] = __builtin_amdgcn_mfma_f32_16x16x32_bf16(av, bv, accS[j], 0, 0, 0);
    }
  }
  int quad = lane >> 4, cn = lane & 15;
  bf16* st = states + (size_t)gid * (HEADDIM * DSTATE);
#pragma unroll
  for (int j = 0; j < 8; j++)
#pragma unroll
    for (int r = 0; r < 4; r++) {
      int p = w * 16 + quad * 4 + r;
      int n = j * 16 + cn;
      st[p * DSTATE + n] = f2b(accS[j][r]);
    }
}

// ---------------- inter-chunk scan: register-batched (independent loads first) --------
__global__ __launch_bounds__(256) void scan_kernel(
    bf16* __restrict__ states, const float* __restrict__ csum) {
  int idx = blockIdx.x * 256 + threadIdx.x;  // 2*NHEADS*HEADDIM*DSTATE
  int n = idx % DSTATE;
  int p = (idx / DSTATE) % HEADDIM;
  int h = (idx / (DSTATE * HEADDIM)) % NHEADS;
  int b = idx / (DSTATE * HEADDIM * NHEADS);
  size_t base = ((size_t)(b * NCHUNK) * NHEADS + h) * (HEADDIM * DSTATE) + p * DSTATE + n;
  const size_t cstride = (size_t)NHEADS * HEADDIM * DSTATE;
  float tmp[NCHUNK], cv[NCHUNK];
#pragma unroll
  for (int c = 0; c < NCHUNK; c++) tmp[c] = b2f(states[base + c * cstride]);
#pragma unroll
  for (int c = 0; c < NCHUNK; c++) cv[c] = csum[(b * NCHUNK + c) * NHEADS + h];
  float S = 0.f;
#pragma unroll
  for (int c = 0; c < NCHUNK; c++) {
    states[base + c * cstride] = f2b(S);
    S = cv[c] * S + tmp[c];
  }
}

// ---------------- fused Y = Y_diag + Y_off + D*x (MFMA, single bf16 write) ----------------
// R8: back to R6 single-block-per-(b,c,h) tiling (2048 blocks -- R7's l-split
// duplicated staging traffic, FETCH +38%, time +10%: kernel is traffic-bound,
// not occupancy-bound). Kept from R7: wave-parallel shfl_up scan; upper-tri
// zero-fill in W staging (no G load / expf); wave-uniform k0 break in Y_diag.
// New (T14): Ce/St preloaded into REGISTERS before GEMM1, ds_written after its
// barrier -- hides the restage L2/HBM latency under GEMM1 (+48 VGPR, ~120 total,
// < 170 cap at 3 blocks/CU).
__global__ __launch_bounds__(256) void yoff_kernel(
    const bf16* __restrict__ xbc, const float* __restrict__ dt2,
    const float* __restrict__ A_log, const bf16* __restrict__ G,
    const bf16* __restrict__ states, const float* __restrict__ Dp,
    bf16* __restrict__ Y) {
  int gid = blockIdx.x;
  int h = gid % NHEADS;
  int bc = gid / NHEADS;
  int c = bc % NCHUNK, b = bc / NCHUNK;
  int tid = threadIdx.x;
  int lane = tid & 63;
  int w = tid >> 6;
  __shared__ bf16 WB[128][136];   // 34 KB (W, then Ce)
  __shared__ bf16 SX[64][136];    // 17 KB (xdtT, then St)
  __shared__ float acs[CHUNKL];
  __shared__ float dtl[CHUNKL];
  __shared__ float eAl[CHUNKL];
  if (tid < CHUNKL)
    dtl[tid] = dt2[((size_t)b * L_SEQ + c * CHUNKL + tid) * NHEADS + h];
  __syncthreads();
  // wave-parallel inclusive scan of Ah*dtl (128 elems, 2/lane, wave 0 only)
  if (tid < 64) {
    float Ah = -__expf(A_log[h]);
    float v0 = Ah * dtl[2 * tid];
    float v1 = Ah * dtl[2 * tid + 1];
    float s = v0 + v1;
#pragma unroll
    for (int off = 1; off < 64; off <<= 1) {
      float t = __shfl_up(s, off);
      if (tid >= off) s += t;
    }
    acs[2 * tid]     = s - v1;
    acs[2 * tid + 1] = s;
  }
  __syncthreads();
  if (tid < CHUNKL) eAl[tid] = __expf(acs[tid]);   // <= 1
  // T14: issue Ce + St global loads NOW; values consumed only after GEMM1.
  bf16x8v ce_r[8], st_r[4];
  {
    int cofs = b ? 2432 : 2176;
#pragma unroll
    for (int it = 0; it < 8; it++) {
      int o = tid + it * 256;
      int l = o >> 4;
      int n8 = (o & 15) * 8;
      int t = b ? (L_SEQ - 1 - (c * CHUNKL + l)) : (c * CHUNKL + l);
      ce_r[it] = *(const bf16x8v*)&xbc[(size_t)t * CONVDIM + cofs + n8];
    }
    const bf16* stp = states + (size_t)gid * (HEADDIM * DSTATE);
#pragma unroll
    for (int it = 0; it < 4; it++) {
      int o = tid + it * 256;
      st_r[it] = *(const bf16x8v*)&stp[o * 8];
    }
  }
  // SX <- xdtT[p][s]: lane->s, conflict-free scatter
  for (int o = tid; o < CHUNKL * HEADDIM / 8; o += 256) {   // 1024 vecs
    int s = o & 127;
    int p8 = (o >> 7) * 8;
    int t = b ? (L_SEQ - 1 - (c * CHUNKL + s)) : (c * CHUNKL + s);
    bf16x8v xv = *(const bf16x8v*)&xbc[(size_t)t * CONVDIM + h * HEADDIM + p8];
    float d = dtl[s];
#pragma unroll
    for (int j = 0; j < 8; j++) SX[p8 + j][s] = f2b(sh2f(xv[j]) * d);
  }
  // WB <- W[l][s] = G*exp(acs[l]-acs[s]) (s<=l): b128 writes; upper-tri vecs
  // (s8 > l) skip the G load and expf entirely.
  {
    const bf16* Gb = G + (size_t)bc * CHUNKL * CHUNKL;
    for (int o = tid; o < CHUNKL * CHUNKL / 8; o += 256) {  // 2048 vecs
      int l = o >> 4;
      int s8 = (o & 15) * 8;
      bf16x8v wv;
      if (s8 > l) {
#pragma unroll
        for (int j = 0; j < 8; j++) wv[j] = 0;
      } else {
        bf16x8v g = *(const bf16x8v*)&Gb[l * CHUNKL + s8];
        float al = acs[l];
#pragma unroll
        for (int j = 0; j < 8; j++) {
          int s = s8 + j;
          float e = (s <= l) ? sh2f(g[j]) * __expf(al - acs[s]) : 0.f;
          wv[j] = f2bs(e);
        }
      }
      *(bf16x8v*)&WB[l][s8] = wv;
    }
  }
  __syncthreads();
  f32x4v accY[2][4];
#pragma unroll
  for (int i = 0; i < 2; i++)
#pragma unroll
    for (int j = 0; j < 4; j++) accY[i][j] = (f32x4v){0.f, 0.f, 0.f, 0.f};
  // Y_diag: A=W rows [32w,32w+32), B=xdtT p-tiles, k=s.
  // Wave-uniform skip: k0 > 32w+31 => A block all-zero (strict upper triangle).
#pragma unroll
  for (int k0 = 0; k0 < 128; k0 += 32) {
    if (k0 > w * 32 + 31) break;
    bf16x8v a0 = *(const bf16x8v*)&WB[w * 32 + (lane & 15)][(lane >> 4) * 8 + k0];
    bf16x8v a1 = *(const bf16x8v*)&WB[w * 32 + 16 + (lane & 15)][(lane >> 4) * 8 + k0];
#pragma unroll
    for (int j = 0; j < 4; j++) {
      bf16x8v bv = *(const bf16x8v*)&SX[j * 16 + (lane & 15)][(lane >> 4) * 8 + k0];
      accY[0][j] = __builtin_amdgcn_mfma_f32_16x16x32_bf16(a0, bv, accY[0][j], 0, 0, 0);
      accY[1][j] = __builtin_amdgcn_mfma_f32_16x16x32_bf16(a1, bv, accY[1][j], 0, 0, 0);
    }
  }
  __syncthreads();   // all phase-1 LDS reads done
  // restage from REGISTERS (global latency already hidden under GEMM1):
  // WB <- Ce*eAl, SX <- St
  {
#pragma unroll
    for (int it = 0; it < 8; it++) {
      int o = tid + it * 256;
      int l = o >> 4;
      int n8 = (o & 15) * 8;
      float e = eAl[l];
      bf16x8v ov;
#pragma unroll
      for (int j = 0; j < 8; j++) ov[j] = f2bs(sh2f(ce_r[it][j]) * e);
      *(bf16x8v*)&WB[l][n8] = ov;
    }
#pragma unroll
    for (int it = 0; it < 4; it++) {
      int o = tid + it * 256;
      int p = o >> 4;
      int n8 = (o & 15) * 8;
      *(bf16x8v*)&SX[p][n8] = st_r[it];
    }
  }
  __syncthreads();
  // Y_off: A=Ce rows, B=St p-tiles, k=n; accumulate into same accY
#pragma unroll
  for (int k0 = 0; k0 < 128; k0 += 32) {
    bf16x8v a0 = *(const bf16x8v*)&WB[w * 32 + (lane & 15)][(lane >> 4) * 8 + k0];
    bf16x8v a1 = *(const bf16x8v*)&WB[w * 32 + 16 + (lane & 15)][(lane >> 4) * 8 + k0];
#pragma unroll
    for (int j = 0; j < 4; j++) {
      bf16x8v bv = *(const bf16x8v*)&SX[j * 16 + (lane & 15)][(lane >> 4) * 8 + k0];
      accY[0][j] = __builtin_amdgcn_mfma_f32_16x16x32_bf16(a0, bv, accY[0][j], 0, 0, 0);
      accY[1][j] = __builtin_amdgcn_mfma_f32_16x16x32_bf16(a1, bv, accY[1][j], 0, 0, 0);
    }
  }
  int quad = lane >> 4, cn = lane & 15;
  float Dh = Dp[h];
#pragma unroll
  for (int i = 0; i < 2; i++)
#pragma unroll
    for (int j = 0; j < 4; j++)
#pragma unroll
      for (int r = 0; r < 4; r++) {
        int l = w * 32 + i * 16 + quad * 4 + r;
        int p = j * 16 + cn;
        int t = b ? (L_SEQ - 1 - (c * CHUNKL + l)) : (c * CHUNKL + l);
        float xv = b2f(xbc[(size_t)t * CONVDIM + h * HEADDIM + p]);
        size_t yi = ((size_t)b * L_SEQ + c * CHUNKL + l) * DINNER + h * HEADDIM + p;
        Y[yi] = f2b(accY[i][j][r] + xv * Dh);
      }
}

// ---------------- combine: shift, flip, +x*fd, gate, RMSNorm (vectorized) ----------------
__global__ __launch_bounds__(256) void combine_kernel(
    const bf16* __restrict__ Y, const bf16* __restrict__ xbc,
    const bf16* __restrict__ zx, const float* __restrict__ fd,
    const float* __restrict__ norm_w, bf16* __restrict__ yn) {
  int t = blockIdx.x;
  int tid = threadIdx.x;
  int j8 = tid * 8;
  float yf[8], yb[8];
#pragma unroll
  for (int j = 0; j < 8; j++) { yf[j] = 0.f; yb[j] = 0.f; }
  if (t >= 1) {
    bf16x8v v = *(const bf16x8v*)&Y[(size_t)(t - 1) * DINNER + j8];
#pragma unroll
    for (int j = 0; j < 8; j++) yf[j] = sh2f(v[j]);
  }
  if (t <= L_SEQ - 2) {
    bf16x8v v = *(const bf16x8v*)&Y[((size_t)L_SEQ + (L_SEQ - 2 - t)) * DINNER + j8];
#pragma unroll
    for (int j = 0; j < 8; j++) yb[j] = sh2f(v[j]);
  }
  bf16x8v xogv = *(const bf16x8v*)&xbc[(size_t)t * CONVDIM + j8];
  bf16x8v zv = *(const bf16x8v*)&zx[(size_t)t * DPROJ + j8];
  float fdv = fd[t * NHEADS + (j8 >> 6)];
  float yg[8];
  float ss = 0.f;
#pragma unroll
  for (int j = 0; j < 8; j++) {
    float y = yf[j] + yb[j] + sh2f(xogv[j]) * fdv;
    float z = sh2f(zv[j]);
    float g = y * (z / (1.f + __expf(-z)));
    yg[j] = g;
    ss += g * g;
  }
#pragma unroll
  for (int off = 32; off > 0; off >>= 1) ss += __shfl_down(ss, off);
  __shared__ float red[4];
  if ((tid & 63) == 0) red[tid >> 6] = ss;
  __syncthreads();
  float tot = red[0] + red[1] + red[2] + red[3];
  float scale = rsqrtf(tot / (float)DINNER + 1e-5f);
  float4 nw0 = *(const float4*)&norm_w[j8];
  float4 nw1 = *(const float4*)&norm_w[j8 + 4];
  bf16x8v ov;
  ov[0] = f2bs(yg[0] * scale * nw0.x);
  ov[1] = f2bs(yg[1] * scale * nw0.y);
  ov[2] = f2bs(yg[2] * scale * nw0.z);
  ov[3] = f2bs(yg[3] * scale * nw0.w);
  ov[4] = f2bs(yg[4] * scale * nw1.x);
  ov[5] = f2bs(yg[5] * scale * nw1.y);
  ov[6] = f2bs(yg[6] * scale * nw1.z);
  ov[7] = f2bs(yg[7] * scale * nw1.w);
  *(bf16x8v*)&yn[(size_t)t * DINNER + j8] = ov;
}

// ---------------- launch ----------------
extern "C" void kernel_launch(void* const* d_in, const int* in_sizes, int n_in,
                              void* d_out, int out_size, void* d_ws, size_t ws_size,
                              hipStream_t stream) {
  const float* u         = (const float*)d_in[0];
  const float* in_proj_w = (const float*)d_in[1];
  const float* conv_w    = (const float*)d_in[2];
  const float* conv_b    = (const float*)d_in[3];
  const float* dt_bias   = (const float*)d_in[4];
  const float* A_log     = (const float*)d_in[5];
  const float* Dp        = (const float*)d_in[6];
  const float* fc_D_w    = (const float*)d_in[7];
  const float* norm_w    = (const float*)d_in[8];
  const float* out_proj_w= (const float*)d_in[9];
  float* out = (float*)d_out;

  char* base = (char*)d_ws;
  bf16*  zx  = (bf16*)base;  base += (size_t)L_SEQ * DPROJ * 2;                    // 38.3 MB
  bf16*  xbc = (bf16*)base;  base += (size_t)L_SEQ * CONVDIM * 2;                  // 21.0 MB
  float* dt2 = (float*)base; base += (size_t)2 * L_SEQ * NHEADS * 4;               //  1.0 MB
  bf16*  G   = (bf16*)base;  base += (size_t)2 * NCHUNK * CHUNKL * CHUNKL * 4;     //  4.2 MB region
  bf16*  Yb  = (bf16*)base;  base += (size_t)2 * L_SEQ * DINNER * 4;               // 67.1 MB region
  bf16*  stb = (bf16*)base;  base += (size_t)2 * NCHUNK * NHEADS * HEADDIM * DSTATE * 4; // 67.1 MB region
  float* cs  = (float*)base; base += (size_t)2 * NCHUNK * NHEADS * 4;              //  8 KB
  // aliases into dead regions:
  bf16*  u_bf   = (bf16*)Yb;                          // 8.4 MB   (Yb live only after yoff)
  bf16*  w1p_bf = (bf16*)((char*)Yb + 9437184);       // 9.7 MB   (in_proj_w padded to 4736 rows)
  bf16*  w2_bf  = (bf16*)G;                           // 4.2 MB   (G dead after yoff)
  bf16*  yn     = (bf16*)stb;                         // 16.8 MB  (stb dead after yoff)
  float* fd     = (float*)((char*)stb + 33554432);    //  0.5 MB

  // 0. fused casts for MFMA gemm1 (w1 zero-padded to NPAD1 rows)
  cast2_kernel<<<(L_SEQ * DMODEL + NPAD1 * DMODEL) / 256, 256, 0, stream>>>(
      u, in_proj_w, u_bf, w1p_bf);
  // 1a. in_proj main: cols [0,4096) (8-phase 256^2, 256 blocks = exactly 1 round)
  gemm1_8ph<<<(L_SEQ / 256) * G1_GN, 512, 0, stream>>>(u_bf, w1p_bf, zx);
  // 1b. in_proj remainder: cols [4096,4672) (128^2 gemm, 160 blocks)
  gemm_mfma<bf16><<<(L_SEQ / 128) * ((NPAD1 - NSPLIT) / 128), 256, 0, stream>>>(
      u_bf, DMODEL, w1p_bf + (size_t)NSPLIT * DMODEL, DMODEL,
      zx + NSPLIT, DPROJ, DPROJ - NSPLIT, DMODEL,
      L_SEQ / 128, (NPAD1 - NSPLIT) / 128, 0);
  // 2. conv + silu + dt (fused)
  conv_dt_kernel<<<CONV_BLOCKS + (2 * L_SEQ * NHEADS) / 256, 256, 0, stream>>>(
      zx, conv_w, conv_b, xbc, dt_bias, dt2);
  // 3a. G = C B^T per (b,c), quarter-split (MFMA, bf16)
  gmat_kernel<<<2 * NCHUNK * 4, 256, 0, stream>>>(xbc, G);
  // 3b. chunk states (MFMA, bf16)
  chunk_kernel<<<2 * NCHUNK * NHEADS, 256, 0, stream>>>(
      xbc, dt2, A_log, stb, cs);
  // 3c. inter-chunk scan (register-batched)
  scan_kernel<<<(2 * NHEADS * HEADDIM * DSTATE) / 256, 256, 0, stream>>>(stb, cs);
  // 3d. fused Y = Y_diag + Y_off + D*x (MFMA; R6 tiling + T14 reg-preload)
  yoff_kernel<<<2 * NCHUNK * NHEADS, 256, 0, stream>>>(
      xbc, dt2, A_log, G, stb, Dp, Yb);
  // 4a. cast out_proj_w (into dead G region)
  cast_kernel<<<(DMODEL * DINNER + 255) / 256, 256, 0, stream>>>(
      out_proj_w, w2_bf, DMODEL * DINNER, DMODEL * DINNER);
  // 4b. fd = x_og @ fc_D_w^T + D  (k-split across waves, 1024 blocks)
  fc_kernel<<<L_SEQ / 4, 256, 0, stream>>>(xbc, fc_D_w, Dp, fd);
  // 5. combine + gate + RMSNorm
  combine_kernel<<<L_SEQ, 256, 0, stream>>>(Yb, xbc, zx, fd, norm_w, yn);
  // 6. out_proj (MFMA, XCD-swizzled: 256 blocks = 1/CU, swizzle's home case)
  gemm_mfma<float><<<(L_SEQ / 128) * (DMODEL / 128), 256, 0, stream>>>(
      yn, DINNER, w2_bf, DINNER, out, DMODEL, DMODEL, DINNER,
      L_SEQ / 128, DMODEL / 128, 1);
}

// Round 9
// 388.036 us; speedup vs baseline: 1.0441x; 1.0259x over previous
//
#include <hip/hip_runtime.h>
#include <hip/hip_bf16.h>
#include <math.h>

// ---------------- problem constants ----------------
#define L_SEQ   4096
#define DMODEL  1024
#define DINNER  2048
#define NHEADS  32
#define HEADDIM 64
#define DSTATE  128
#define NCHUNK  32
#define CHUNKL  128
#define CONVDIM 2560
#define DPROJ   4672   // 2*DINNER + 2*(2*DSTATE) + 2*NHEADS
#define NPAD1   4736   // DPROJ padded to multiple of 128 (for remainder gemm)
#define NSPLIT  4096   // cols [0,NSPLIT) via 8-phase 256^2 (256 blocks = 1 round);
                       // cols [NSPLIT,DPROJ) via 128^2 gemm (160 blocks)

typedef __hip_bfloat16 bf16;
__device__ __forceinline__ float b2f(bf16 x) { return __bfloat162float(x); }
__device__ __forceinline__ bf16 f2b(float x) { return __float2bfloat16(x); }
__device__ __forceinline__ float sh2f(short s) {
  return __uint_as_float(((unsigned int)(unsigned short)s) << 16);
}
__device__ __forceinline__ short f2bs(float x) {
  bf16 t = __float2bfloat16(x);
  return *reinterpret_cast<short*>(&t);
}

typedef __attribute__((ext_vector_type(8))) short bf16x8v;
typedef __attribute__((ext_vector_type(4))) float f32x4v;

__device__ __forceinline__ float dot8(bf16x8v x, float4 w0, float4 w1) {
  return sh2f(x[0]) * w0.x + sh2f(x[1]) * w0.y + sh2f(x[2]) * w0.z + sh2f(x[3]) * w0.w +
         sh2f(x[4]) * w1.x + sh2f(x[5]) * w1.y + sh2f(x[6]) * w1.z + sh2f(x[7]) * w1.w;
}

// zxbcdt column layout: [0,2048) = z ; [2048,4608) = xBC ; [4608,4672) = dt raw
// xBC_conv channel layout: [0,2048) = x ; fw B = [2048,2176) C = [2176,2304)
//                          bw B = [2304,2432) C = [2432,2560)  (bw streams time-flipped)

// ---------------- fused casts: u -> bf16 and in_proj_w -> bf16 (zero-padded) ----------------
__global__ __launch_bounds__(256) void cast2_kernel(
    const float* __restrict__ u, const float* __restrict__ w1,
    bf16* __restrict__ u_bf, bf16* __restrict__ w1_bf) {
  const int NU = (L_SEQ * DMODEL) / 256;   // 16384 blocks
  int bid = blockIdx.x;
  if (bid < NU) {
    int i = bid * 256 + threadIdx.x;
    u_bf[i] = f2b(u[i]);
  } else {
    int i = (bid - NU) * 256 + threadIdx.x;
    w1_bf[i] = (i < DPROJ * DMODEL) ? f2b(w1[i]) : f2b(0.f);
  }
}

// ---------------- f32 -> bf16 cast ----------------
__global__ __launch_bounds__(256) void cast_kernel(
    const float* __restrict__ src, bf16* __restrict__ dst, int n_src, int n_tot) {
  int i = blockIdx.x * 256 + threadIdx.x;
  if (i < n_tot) dst[i] = (i < n_src) ? f2b(src[i]) : f2b(0.f);
}

// ================= in_proj main: 8-phase 256x256 GEMM (R1-verified body) =================
// C[m,n] = sum_k A[m,k]*B[n,k]; A = u_bf [4096][1024], B = w1p_bf rows [0,4096),
// C = zx cols [0,4096). BK=64, 512 threads = 8 waves (2Mx4N), per-wave C = 128x64.
// Grid = 16 x 16 = 256 blocks = exactly one residency round (128 KiB LDS -> 1/CU).
// Register budget (the R2/R3 lesson): acc[8][4] = 128 regs + a/b frags 64 + addr
// ~= 244 <= 256-reg cap at 2 waves/SIMD. BN=320 (acc 160) does NOT fit -- spills.
// LDS: 2 dbuf slots x (A 256x64 + B 256x64), 16 subtiles of [16r][32c] per 128x64
// half, st_16x32 XOR swizzle via pre-swizzled global source (linear gload_lds dest)
// + swizzled ds_read addr. vmcnt(6) once per K-tile; vmcnt(0) only at t=NT-2.
#define G1_K  1024
#define G1_GN 16            // N tiles of 256 covering [0,4096)
#define G1_NT (G1_K / 64)   // 16 K-tiles

__global__ __launch_bounds__(512, 2) void gemm1_8ph(
    const bf16* __restrict__ A, const bf16* __restrict__ B, bf16* __restrict__ C) {
  __shared__ bf16 Al[2][2][8192];   // [slot][half][subtiled 128x64]  64 KB
  __shared__ bf16 Bl[2][2][8192];   // 64 KB
  const int tid = threadIdx.x;
  const int lane = tid & 63;
  const int w = tid >> 6;        // 0..7
  const int wm = w >> 2;         // 0..1 -> C rows [wm*128, +128)
  const int wn = w & 3;          // 0..3 -> C cols [wn*64, +64)
  const int bm = (blockIdx.x / G1_GN) * 256;
  const int bn = (blockIdx.x % G1_GN) * 256;
  // staging source pre-swizzle (bf16 units): dest r_in = lane>>2, swz bit = r_in bit3
  const int scol = ((lane & 3) ^ (((lane >> 5) & 1) << 1)) * 8;
  // read-side swizzled col within subtile: flip bit4 when row bit3 set
  const int cin = ((lane >> 4) * 8) ^ (((lane >> 3) & 1) << 4);
  const int r16 = lane & 15;
  const bf16* Ag = A + (size_t)bm * G1_K;
  const bf16* Bg = B + (size_t)bn * G1_K;

  // stage one 128x64 half-tile (A: mat=0, B: mat=1) of K-tile tt.
  // wave w fills subtiles w and 8+w (1024B each, linear dest; swizzle via source).
  auto stage = [&](int mat, int tt, int hf) {
    const bf16* g = (mat ? Bg : Ag)
        + (size_t)(hf * 128 + (w >> 1) * 16 + (lane >> 2)) * G1_K
        + tt * 64 + (w & 1) * 32 + scol;
    bf16* d0 = mat ? &Bl[tt & 1][hf][0] : &Al[tt & 1][hf][0];
    __builtin_amdgcn_global_load_lds(
        (const __attribute__((address_space(1))) void*)g,
        (__attribute__((address_space(3))) void*)(d0 + w * 512), 16, 0, 0);
    __builtin_amdgcn_global_load_lds(
        (const __attribute__((address_space(1))) void*)(g + (size_t)64 * G1_K),
        (__attribute__((address_space(3))) void*)(d0 + (8 + w) * 512), 16, 0, 0);
  };

  f32x4v acc[8][4];
#pragma unroll
  for (int i = 0; i < 8; i++)
#pragma unroll
    for (int j = 0; j < 4; j++) acc[i][j] = (f32x4v){0.f, 0.f, 0.f, 0.f};

  // prologue: tile0 {A0,A1,B0,B1}, tile1 {A0,A1,B0} = 7 half-tiles (14 loads)
  stage(0, 0, 0); stage(0, 0, 1); stage(1, 0, 0); stage(1, 0, 1);
  stage(0, 1, 0); stage(0, 1, 1); stage(1, 1, 0);
  asm volatile("s_waitcnt vmcnt(6)" ::: "memory");   // tile0 fully resident
  __builtin_amdgcn_s_barrier();
  __builtin_amdgcn_sched_barrier(0);

#pragma unroll 2
  for (int t = 0; t < G1_NT; ++t) {
    const int slot = t & 1;
    const bf16* Ah = &Al[slot][wm][0];
    const bf16* Bh = &Bl[slot][wn >> 1][0];
    const int brb = (wn & 1) * 4;   // B subtile-row base within half
    bf16x8v a[4][2], b[4][2];
    // ---- phase 0: ds A m0-3 + B n0-1 (12 reads); stage B1(t+1); mfma m0-3 x n0-1
#pragma unroll
    for (int i = 0; i < 4; i++) {
      a[i][0] = *(const bf16x8v*)&Ah[(i * 2 + 0) * 512 + r16 * 32 + cin];
      a[i][1] = *(const bf16x8v*)&Ah[(i * 2 + 1) * 512 + r16 * 32 + cin];
    }
#pragma unroll
    for (int j = 0; j < 2; j++) {
      b[j][0] = *(const bf16x8v*)&Bh[((brb + j) * 2 + 0) * 512 + r16 * 32 + cin];
      b[j][1] = *(const bf16x8v*)&Bh[((brb + j) * 2 + 1) * 512 + r16 * 32 + cin];
    }
    if (t + 1 < G1_NT) stage(1, t + 1, 1);
    __builtin_amdgcn_s_barrier();
    asm volatile("s_waitcnt lgkmcnt(0)" ::: "memory");
    __builtin_amdgcn_s_setprio(1);
#pragma unroll
    for (int i = 0; i < 4; i++)
#pragma unroll
      for (int j = 0; j < 2; j++) {
        acc[i][j] = __builtin_amdgcn_mfma_f32_16x16x32_bf16(a[i][0], b[j][0], acc[i][j], 0, 0, 0);
        acc[i][j] = __builtin_amdgcn_mfma_f32_16x16x32_bf16(a[i][1], b[j][1], acc[i][j], 0, 0, 0);
      }
    __builtin_amdgcn_s_setprio(0);
    __builtin_amdgcn_s_barrier();
    // ---- phase 1: ds B n2-3 (4 reads); mfma m0-3 x n2-3
#pragma unroll
    for (int j = 2; j < 4; j++) {
      b[j][0] = *(const bf16x8v*)&Bh[((brb + j) * 2 + 0) * 512 + r16 * 32 + cin];
      b[j][1] = *(const bf16x8v*)&Bh[((brb + j) * 2 + 1) * 512 + r16 * 32 + cin];
    }
    __builtin_amdgcn_s_barrier();
    asm volatile("s_waitcnt lgkmcnt(0)" ::: "memory");
    __builtin_amdgcn_s_setprio(1);
#pragma unroll
    for (int i = 0; i < 4; i++)
#pragma unroll
      for (int j = 2; j < 4; j++) {
        acc[i][j] = __builtin_amdgcn_mfma_f32_16x16x32_bf16(a[i][0], b[j][0], acc[i][j], 0, 0, 0);
        acc[i][j] = __builtin_amdgcn_mfma_f32_16x16x32_bf16(a[i][1], b[j][1], acc[i][j], 0, 0, 0);
      }
    __builtin_amdgcn_s_setprio(0);
    __builtin_amdgcn_s_barrier();
    // ---- phase 2: ds A m4-7 (8 reads); stage B0(t+2); mfma m4-7 x n2-3
#pragma unroll
    for (int i = 0; i < 4; i++) {
      a[i][0] = *(const bf16x8v*)&Ah[((4 + i) * 2 + 0) * 512 + r16 * 32 + cin];
      a[i][1] = *(const bf16x8v*)&Ah[((4 + i) * 2 + 1) * 512 + r16 * 32 + cin];
    }
    if (t + 2 < G1_NT) stage(1, t + 2, 0);
    __builtin_amdgcn_s_barrier();
    asm volatile("s_waitcnt lgkmcnt(0)" ::: "memory");
    __builtin_amdgcn_s_setprio(1);
#pragma unroll
    for (int i = 0; i < 4; i++)
#pragma unroll
      for (int j = 2; j < 4; j++) {
        acc[4 + i][j] = __builtin_amdgcn_mfma_f32_16x16x32_bf16(a[i][0], b[j][0], acc[4 + i][j], 0, 0, 0);
        acc[4 + i][j] = __builtin_amdgcn_mfma_f32_16x16x32_bf16(a[i][1], b[j][1], acc[4 + i][j], 0, 0, 0);
      }
    __builtin_amdgcn_s_setprio(0);
    __builtin_amdgcn_s_barrier();
    // ---- phase 3: stage A0,A1(t+2); mfma m4-7 x n0-1; counted vmcnt; barrier
    if (t + 2 < G1_NT) { stage(0, t + 2, 0); stage(0, t + 2, 1); }
    __builtin_amdgcn_s_barrier();
    __builtin_amdgcn_s_setprio(1);
#pragma unroll
    for (int i = 0; i < 4; i++)
#pragma unroll
      for (int j = 0; j < 2; j++) {
        acc[4 + i][j] = __builtin_amdgcn_mfma_f32_16x16x32_bf16(a[i][0], b[j][0], acc[4 + i][j], 0, 0, 0);
        acc[4 + i][j] = __builtin_amdgcn_mfma_f32_16x16x32_bf16(a[i][1], b[j][1], acc[4 + i][j], 0, 0, 0);
      }
    __builtin_amdgcn_s_setprio(0);
    if (t < G1_NT - 2)       asm volatile("s_waitcnt vmcnt(6)" ::: "memory");
    else if (t == G1_NT - 2) asm volatile("s_waitcnt vmcnt(0)" ::: "memory");
    __builtin_amdgcn_s_barrier();
    __builtin_amdgcn_sched_barrier(0);
  }

  const int quad = lane >> 4;
  const int cn = lane & 15;
#pragma unroll
  for (int i = 0; i < 8; i++)
#pragma unroll
    for (int j = 0; j < 4; j++) {
      int col = bn + wn * 64 + j * 16 + cn;
      if (col < DPROJ) {
#pragma unroll
        for (int r = 0; r < 4; r++) {
          int row = bm + wm * 128 + i * 16 + quad * 4 + r;
          C[(size_t)row * DPROJ + col] = f2b(acc[i][j][r]);
        }
      }
    }
}

// ---------------- MFMA GEMM: C[m,n] = sum_k A[m,k]*B[n,k], bf16 in, f32 acc ----------------
// (used for the in_proj N-remainder)
template <typename TC>
__global__ __launch_bounds__(256) void gemm_mfma(
    const bf16* __restrict__ A, int lda,
    const bf16* __restrict__ B, int ldb,
    TC* __restrict__ C, int ldc,
    int N, int K, int gridM, int gridN, int swz) {
  __shared__ short As[128][32];
  __shared__ short Bs[128][32];
  int tid = threadIdx.x;
  int lane = tid & 63;
  int w = tid >> 6;            // wave 0..3
  int wr = w >> 1, wc = w & 1; // 2x2 wave grid
  int bid = blockIdx.x;
  int bm, bn;
  if (swz) {
    int mst = gridM >> 3;
    int xk = bid & 7, q = bid >> 3;
    bm = (xk + 8 * (q % mst)) * 128;
    bn = (q / mst) * 128;
  } else {
    bm = (bid / gridN) * 128;
    bn = (bid % gridN) * 128;
  }
  f32x4v acc[4][4];
#pragma unroll
  for (int i = 0; i < 4; i++)
#pragma unroll
    for (int j = 0; j < 4; j++) acc[i][j] = (f32x4v){0.f, 0.f, 0.f, 0.f};

  const bf16* Ab = A + (size_t)(bm + w * 32 + (lane >> 2)) * lda + (lane & 3) * 8;
  const bf16* Bb = B + (size_t)(bn + w * 32 + (lane >> 2)) * ldb + (lane & 3) * 8;

  for (int k0 = 0; k0 < K; k0 += 32) {
    __builtin_amdgcn_global_load_lds(
        (const __attribute__((address_space(1))) void*)(Ab + k0),
        (__attribute__((address_space(3))) void*)&As[w * 32][0], 16, 0, 0);
    __builtin_amdgcn_global_load_lds(
        (const __attribute__((address_space(1))) void*)(Ab + (size_t)16 * lda + k0),
        (__attribute__((address_space(3))) void*)&As[w * 32 + 16][0], 16, 0, 0);
    __builtin_amdgcn_global_load_lds(
        (const __attribute__((address_space(1))) void*)(Bb + k0),
        (__attribute__((address_space(3))) void*)&Bs[w * 32][0], 16, 0, 0);
    __builtin_amdgcn_global_load_lds(
        (const __attribute__((address_space(1))) void*)(Bb + (size_t)16 * ldb + k0),
        (__attribute__((address_space(3))) void*)&Bs[w * 32 + 16][0], 16, 0, 0);
    __syncthreads();
    bf16x8v af[4], bv[4];
#pragma unroll
    for (int i = 0; i < 4; i++)
      af[i] = *(const bf16x8v*)&As[wr * 64 + i * 16 + (lane & 15)][(lane >> 4) * 8];
#pragma unroll
    for (int j = 0; j < 4; j++)
      bv[j] = *(const bf16x8v*)&Bs[wc * 64 + j * 16 + (lane & 15)][(lane >> 4) * 8];
#pragma unroll
    for (int i = 0; i < 4; i++)
#pragma unroll
      for (int j = 0; j < 4; j++)
        acc[i][j] = __builtin_amdgcn_mfma_f32_16x16x32_bf16(af[i], bv[j], acc[i][j], 0, 0, 0);
    __syncthreads();
  }
  int quad = lane >> 4;
  int cn = lane & 15;
#pragma unroll
  for (int i = 0; i < 4; i++) {
#pragma unroll
    for (int j = 0; j < 4; j++) {
      int col = bn + wc * 64 + j * 16 + cn;
      if (col < N) {
#pragma unroll
        for (int r = 0; r < 4; r++) {
          int row = bm + wr * 64 + i * 16 + quad * 4 + r;
          float v = acc[i][j][r];
          if constexpr (sizeof(TC) == 2) C[(size_t)row * ldc + col] = f2b(v);
          else                           C[(size_t)row * ldc + col] = v;
        }
      }
    }
  }
}

// ---------------- out_proj split-K=2: 512 blocks (2/CU, 2 waves/SIMD) ----------------
// R9: the single 256-block out_proj dispatch ran at 1 wave/SIMD (zero TLP,
// Occupancy 9.8%, 330 TF). Split K: ks=0 -> K[0,1024) writes out; ks=1 ->
// K[1024,2048) writes P1 (dead-Yb alias); then out += P1 (add_kernel).
// Body = the proven 128^2 gemm with XCD swizzle (gridM=32, mst=4).
__global__ __launch_bounds__(256) void outproj_ks(
    const bf16* __restrict__ A, const bf16* __restrict__ B,
    float* __restrict__ C0, float* __restrict__ C1) {
  __shared__ short As[128][32];
  __shared__ short Bs[128][32];
  int tid = threadIdx.x;
  int lane = tid & 63;
  int w = tid >> 6;
  int wr = w >> 1, wc = w & 1;
  int bid = blockIdx.x;
  int ks = bid >> 8;            // 0/1 K-half
  int q = bid & 255;
  int xk = q & 7, qq = q >> 3;
  int bm = (xk + 8 * (qq & 3)) * 128;   // 32 m-tiles
  int bn = (qq >> 2) * 128;             // 8 n-tiles
  float* C = ks ? C1 : C0;
  f32x4v acc[4][4];
#pragma unroll
  for (int i = 0; i < 4; i++)
#pragma unroll
    for (int j = 0; j < 4; j++) acc[i][j] = (f32x4v){0.f, 0.f, 0.f, 0.f};

  const bf16* Ab = A + (size_t)(bm + w * 32 + (lane >> 2)) * DINNER + ks * 1024 + (lane & 3) * 8;
  const bf16* Bb = B + (size_t)(bn + w * 32 + (lane >> 2)) * DINNER + ks * 1024 + (lane & 3) * 8;

  for (int k0 = 0; k0 < 1024; k0 += 32) {
    __builtin_amdgcn_global_load_lds(
        (const __attribute__((address_space(1))) void*)(Ab + k0),
        (__attribute__((address_space(3))) void*)&As[w * 32][0], 16, 0, 0);
    __builtin_amdgcn_global_load_lds(
        (const __attribute__((address_space(1))) void*)(Ab + (size_t)16 * DINNER + k0),
        (__attribute__((address_space(3))) void*)&As[w * 32 + 16][0], 16, 0, 0);
    __builtin_amdgcn_global_load_lds(
        (const __attribute__((address_space(1))) void*)(Bb + k0),
        (__attribute__((address_space(3))) void*)&Bs[w * 32][0], 16, 0, 0);
    __builtin_amdgcn_global_load_lds(
        (const __attribute__((address_space(1))) void*)(Bb + (size_t)16 * DINNER + k0),
        (__attribute__((address_space(3))) void*)&Bs[w * 32 + 16][0], 16, 0, 0);
    __syncthreads();
    bf16x8v af[4], bv[4];
#pragma unroll
    for (int i = 0; i < 4; i++)
      af[i] = *(const bf16x8v*)&As[wr * 64 + i * 16 + (lane & 15)][(lane >> 4) * 8];
#pragma unroll
    for (int j = 0; j < 4; j++)
      bv[j] = *(const bf16x8v*)&Bs[wc * 64 + j * 16 + (lane & 15)][(lane >> 4) * 8];
#pragma unroll
    for (int i = 0; i < 4; i++)
#pragma unroll
      for (int j = 0; j < 4; j++)
        acc[i][j] = __builtin_amdgcn_mfma_f32_16x16x32_bf16(af[i], bv[j], acc[i][j], 0, 0, 0);
    __syncthreads();
  }
  int quad = lane >> 4;
  int cn = lane & 15;
#pragma unroll
  for (int i = 0; i < 4; i++)
#pragma unroll
    for (int j = 0; j < 4; j++) {
      int col = bn + wc * 64 + j * 16 + cn;
#pragma unroll
      for (int r = 0; r < 4; r++) {
        int row = bm + wr * 64 + i * 16 + quad * 4 + r;
        C[(size_t)row * DMODEL + col] = acc[i][j][r];
      }
    }
}

// ---------------- out += P1 (vectorized) ----------------
__global__ __launch_bounds__(256) void add_kernel(
    float* __restrict__ out, const float* __restrict__ P) {
  int i = (blockIdx.x * 256 + threadIdx.x) * 4;
  float4 a = *(const float4*)&out[i];
  float4 b = *(const float4*)&P[i];
  a.x += b.x; a.y += b.y; a.z += b.z; a.w += b.w;
  *(float4*)&out[i] = a;
}

// ---------------- fc_D: fd[t][h] = sum_k x[t,k]*W[h,k] + D[h] ----------------
// R6: k split across the 4 waves (512 each; lane g-split -> 256 k/lane, 32-iter
// chain) + 4x grid (1024 blocks = 4/CU, 4 waves/SIMD).
__global__ __launch_bounds__(256) void fc_kernel(
    const bf16* __restrict__ xbc, const float* __restrict__ Wf,
    const float* __restrict__ Dp, float* __restrict__ fd) {
  int lane = threadIdx.x & 63;
  int w = threadIdx.x >> 6;          // wave = k-quarter
  int t0 = blockIdx.x * 4;
  int h = lane & 31;
  int g = lane >> 5;                 // k-eighth within quarter
  int k0 = w * 512 + g * 256;
  const float* wr = Wf + (size_t)h * DINNER + k0;
  const bf16* xr = xbc + (size_t)t0 * CONVDIM + k0;
  float a0 = 0.f, a1 = 0.f, a2 = 0.f, a3 = 0.f;
#pragma unroll 4
  for (int k = 0; k < 256; k += 8) {
    float4 w0 = *(const float4*)(wr + k);
    float4 w1 = *(const float4*)(wr + k + 4);
    bf16x8v x0 = *(const bf16x8v*)(xr + k);
    bf16x8v x1 = *(const bf16x8v*)(xr + CONVDIM + k);
    bf16x8v x2 = *(const bf16x8v*)(xr + 2 * CONVDIM + k);
    bf16x8v x3 = *(const bf16x8v*)(xr + 3 * CONVDIM + k);
    a0 += dot8(x0, w0, w1);
    a1 += dot8(x1, w0, w1);
    a2 += dot8(x2, w0, w1);
    a3 += dot8(x3, w0, w1);
  }
  a0 += __shfl_down(a0, 32);
  a1 += __shfl_down(a1, 32);
  a2 += __shfl_down(a2, 32);
  a3 += __shfl_down(a3, 32);
  __shared__ float red[4][4][32];    // [wave][t][h]
  if (lane < 32) {
    red[w][0][h] = a0; red[w][1][h] = a1; red[w][2][h] = a2; red[w][3][h] = a3;
  }
  __syncthreads();
  int tid = threadIdx.x;
  if (tid < 128) {
    int tt = tid >> 5;
    int hh = tid & 31;
    float s = red[0][tt][hh] + red[1][tt][hh] + red[2][tt][hh] + red[3][tt][hh];
    fd[(t0 + tt) * NHEADS + hh] = s + Dp[hh];
  }
}

// ---------------- conv (4 t/thread) + SiLU, with dt softplus folded in ----------------
#define CONV_BLOCKS ((L_SEQ / 4) * CONVDIM / 256)   // 10240
__global__ __launch_bounds__(256) void conv_dt_kernel(
    const bf16* __restrict__ zx, const float* __restrict__ conv_w,
    const float* __restrict__ conv_b, bf16* __restrict__ xbc,
    const float* __restrict__ dt_bias, float* __restrict__ dt2) {
  int bid = blockIdx.x;
  if (bid < CONV_BLOCKS) {
    int idx = bid * 256 + threadIdx.x;
    int ch = idx % CONVDIM;
    int t0 = (idx / CONVDIM) * 4;
    const bf16* col = zx + DINNER + ch;
    float w0 = conv_w[ch * 4 + 0], w1 = conv_w[ch * 4 + 1];
    float w2 = conv_w[ch * 4 + 2], w3 = conv_w[ch * 4 + 3];
    float bsv = conv_b[ch];
    float x[7];
#pragma unroll
    for (int i = 0; i < 7; i++) {
      int t = t0 - 3 + i;
      x[i] = (t >= 0) ? b2f(col[(size_t)t * DPROJ]) : 0.f;
    }
#pragma unroll
    for (int j = 0; j < 4; j++) {
      float acc = bsv + w0 * x[j] + w1 * x[j + 1] + w2 * x[j + 2] + w3 * x[j + 3];
      xbc[(size_t)(t0 + j) * CONVDIM + ch] = f2b(acc / (1.f + __expf(-acc)));
    }
  } else {
    int idx = (bid - CONV_BLOCKS) * 256 + threadIdx.x;   // 2*L_SEQ*NHEADS
    int h = idx % NHEADS;
    int t = (idx / NHEADS) % L_SEQ;
    int b = idx / (NHEADS * L_SEQ);
    float v;
    if (b == 0) v = b2f(zx[(size_t)t * DPROJ + 4608 + h]);
    else        v = b2f(zx[(size_t)(L_SEQ - 1 - t) * DPROJ + 4608 + NHEADS + h]);
    v += dt_bias[h];
    dt2[idx] = (v > 20.f) ? v : log1pf(expf(v));
  }
}

// ---------------- G[b,c,l,s] = sum_n C[l,n]*B[s,n]  (MFMA, quarter-split) ----------------
__global__ __launch_bounds__(256) void gmat_kernel(
    const bf16* __restrict__ xbc, bf16* __restrict__ G) {
  __shared__ bf16 Cs[32][136];   // C[l0+l][n]  8.5 KB
  __shared__ bf16 Bs[128][136];  // B[s][n]     34 KB
  int blk = blockIdx.x;          // (b*32+c)*4 + quarter
  int quarter = blk & 3;
  int bc = blk >> 2;
  int b = bc / NCHUNK, c = bc % NCHUNK;
  int l0 = quarter * 32;
  int tid = threadIdx.x;
  int lane = tid & 63;
  int w = tid >> 6;
  int bofs = b ? 2304 : 2048;
  int cofs = b ? 2432 : 2176;
  for (int o = tid; o < CHUNKL * DSTATE / 8; o += 256) {   // 2048 vecs
    int s = o >> 4;
    int n8 = (o & 15) * 8;
    int t = b ? (L_SEQ - 1 - (c * CHUNKL + s)) : (c * CHUNKL + s);
    *(bf16x8v*)&Bs[s][n8] = *(const bf16x8v*)&xbc[(size_t)t * CONVDIM + bofs + n8];
  }
  for (int o = tid; o < 32 * DSTATE / 8; o += 256) {       // 512 vecs
    int l = o >> 4;
    int n8 = (o & 15) * 8;
    int t = b ? (L_SEQ - 1 - (c * CHUNKL + l0 + l)) : (c * CHUNKL + l0 + l);
    *(bf16x8v*)&Cs[l][n8] = *(const bf16x8v*)&xbc[(size_t)t * CONVDIM + cofs + n8];
  }
  __syncthreads();
  if (w > quarter) return;   // s-tiles 2w,2w+1 start at s=32w > l0+31: masked at use
  f32x4v acc[2][2];
#pragma unroll
  for (int i = 0; i < 2; i++)
#pragma unroll
    for (int j = 0; j < 2; j++) acc[i][j] = (f32x4v){0.f, 0.f, 0.f, 0.f};
#pragma unroll
  for (int k0 = 0; k0 < 128; k0 += 32) {
    bf16x8v a0 = *(const bf16x8v*)&Cs[(lane & 15)][(lane >> 4) * 8 + k0];
    bf16x8v a1 = *(const bf16x8v*)&Cs[16 + (lane & 15)][(lane >> 4) * 8 + k0];
#pragma unroll
    for (int j = 0; j < 2; j++) {
      bf16x8v bv = *(const bf16x8v*)&Bs[(2 * w + j) * 16 + (lane & 15)][(lane >> 4) * 8 + k0];
      acc[0][j] = __builtin_amdgcn_mfma_f32_16x16x32_bf16(a0, bv, acc[0][j], 0, 0, 0);
      acc[1][j] = __builtin_amdgcn_mfma_f32_16x16x32_bf16(a1, bv, acc[1][j], 0, 0, 0);
    }
  }
  int quad = lane >> 4, cn = lane & 15;
  bf16* Gb = G + (size_t)bc * CHUNKL * CHUNKL;
#pragma unroll
  for (int i = 0; i < 2; i++)
#pragma unroll
    for (int j = 0; j < 2; j++)
#pragma unroll
      for (int r = 0; r < 4; r++) {
        int l = l0 + i * 16 + quad * 4 + r;
        int s = (2 * w + j) * 16 + cn;
        Gb[l * CHUNKL + s] = f2b(acc[i][j][r]);
      }
}

// ---------------- per-(b,c,h): chunk states only (MFMA, bf16 out) ----------------
__global__ __launch_bounds__(256) void chunk_kernel(
    const bf16* __restrict__ xbc, const float* __restrict__ dt2,
    const float* __restrict__ A_log,
    bf16* __restrict__ states, float* __restrict__ csum) {
  int gid = blockIdx.x;           // (b*32+c)*32 + h
  int h = gid % NHEADS;
  int bc = gid / NHEADS;
  int c = bc % NCHUNK, b = bc / NCHUNK;
  int tid = threadIdx.x;
  int lane = tid & 63;
  int w = tid >> 6;
  __shared__ bf16 BdT[128][136];  // [n][l] = B[l][n]*decay[l]  34 KB
  __shared__ bf16 xdtT[64][136];  // [p][s] = x[s,p]*dt[s]      17 KB
  __shared__ float acs[CHUNKL];
  __shared__ float dtl[CHUNKL];
  __shared__ float decays[CHUNKL];
  if (tid < CHUNKL)
    dtl[tid] = dt2[((size_t)b * L_SEQ + c * CHUNKL + tid) * NHEADS + h];
  __syncthreads();
  if (tid == 0) {
    float Ah = -__expf(A_log[h]);
    float s = 0.f;
    for (int l = 0; l < CHUNKL; l++) { s += Ah * dtl[l]; acs[l] = s; }
    csum[gid] = __expf(s);        // stored pre-exponentiated for scan
  }
  __syncthreads();
  if (tid < CHUNKL) decays[tid] = __expf(acs[CHUNKL - 1] - acs[tid]);
  // xdtT[p][s] staging: lane->s (t-strided 16B loads), conflict-free scatter
  for (int o = tid; o < CHUNKL * HEADDIM / 8; o += 256) {   // 1024 vecs
    int s = o & 127;
    int p8 = (o >> 7) * 8;
    int t = b ? (L_SEQ - 1 - (c * CHUNKL + s)) : (c * CHUNKL + s);
    bf16x8v xv = *(const bf16x8v*)&xbc[(size_t)t * CONVDIM + h * HEADDIM + p8];
    float d = dtl[s];
#pragma unroll
    for (int j = 0; j < 8; j++) xdtT[p8 + j][s] = f2b(sh2f(xv[j]) * d);
  }
  __syncthreads();   // decays ready
  // BdT[n][l] staging: lane->l, conflict-free scatter
  for (int o = tid; o < CHUNKL * CHUNKL / 8; o += 256) {    // 2048 vecs
    int l = o & 127;
    int n8 = (o >> 7) * 8;
    int t = b ? (L_SEQ - 1 - (c * CHUNKL + l)) : (c * CHUNKL + l);
    bf16x8v bv = *(const bf16x8v*)&xbc[(size_t)t * CONVDIM + (b ? 2304 : 2048) + n8];
    float d = decays[l];
#pragma unroll
    for (int j = 0; j < 8; j++) BdT[n8 + j][l] = f2b(sh2f(bv[j]) * d);
  }
  __syncthreads();
  // states[p][n] = sum_l xdtT[p][l]*BdT[n][l]; wave w -> p rows [16w,16w+16)
  f32x4v accS[8];
#pragma unroll
  for (int j = 0; j < 8; j++) accS[j] = (f32x4v){0.f, 0.f, 0.f, 0.f};
#pragma unroll
  for (int k0 = 0; k0 < 128; k0 += 32) {
    bf16x8v av = *(const bf16x8v*)&xdtT[w * 16 + (lane & 15)][(lane >> 4) * 8 + k0];
#pragma unroll
    for (int j = 0; j < 8; j++) {
      bf16x8v bv = *(const bf16x8v*)&BdT[j * 16 + (lane & 15)][(lane >> 4) * 8 + k0];
      accS[j] = __builtin_amdgcn_mfma_f32_16x16x32_bf16(av, bv, accS[j], 0, 0, 0);
    }
  }
  int quad = lane >> 4, cn = lane & 15;
  bf16* st = states + (size_t)gid * (HEADDIM * DSTATE);
#pragma unroll
  for (int j = 0; j < 8; j++)
#pragma unroll
    for (int r = 0; r < 4; r++) {
      int p = w * 16 + quad * 4 + r;
      int n = j * 16 + cn;
      st[p * DSTATE + n] = f2b(accS[j][r]);
    }
}

// ---------------- inter-chunk scan: register-batched (independent loads first) --------
__global__ __launch_bounds__(256) void scan_kernel(
    bf16* __restrict__ states, const float* __restrict__ csum) {
  int idx = blockIdx.x * 256 + threadIdx.x;  // 2*NHEADS*HEADDIM*DSTATE
  int n = idx % DSTATE;
  int p = (idx / DSTATE) % HEADDIM;
  int h = (idx / (DSTATE * HEADDIM)) % NHEADS;
  int b = idx / (DSTATE * HEADDIM * NHEADS);
  size_t base = ((size_t)(b * NCHUNK) * NHEADS + h) * (HEADDIM * DSTATE) + p * DSTATE + n;
  const size_t cstride = (size_t)NHEADS * HEADDIM * DSTATE;
  float tmp[NCHUNK], cv[NCHUNK];
#pragma unroll
  for (int c = 0; c < NCHUNK; c++) tmp[c] = b2f(states[base + c * cstride]);
#pragma unroll
  for (int c = 0; c < NCHUNK; c++) cv[c] = csum[(b * NCHUNK + c) * NHEADS + h];
  float S = 0.f;
#pragma unroll
  for (int c = 0; c < NCHUNK; c++) {
    states[base + c * cstride] = f2b(S);
    S = cv[c] * S + tmp[c];
  }
}

// ---------------- fused Y = Y_diag + Y_off + D*x (MFMA, single bf16 write) ----------------
// R8: R6 tiling + wave-parallel shfl_up scan + upper-tri skips + T14 reg-preload
// of Ce/St (global latency hidden under GEMM1).
__global__ __launch_bounds__(256) void yoff_kernel(
    const bf16* __restrict__ xbc, const float* __restrict__ dt2,
    const float* __restrict__ A_log, const bf16* __restrict__ G,
    const bf16* __restrict__ states, const float* __restrict__ Dp,
    bf16* __restrict__ Y) {
  int gid = blockIdx.x;
  int h = gid % NHEADS;
  int bc = gid / NHEADS;
  int c = bc % NCHUNK, b = bc / NCHUNK;
  int tid = threadIdx.x;
  int lane = tid & 63;
  int w = tid >> 6;
  __shared__ bf16 WB[128][136];   // 34 KB (W, then Ce)
  __shared__ bf16 SX[64][136];    // 17 KB (xdtT, then St)
  __shared__ float acs[CHUNKL];
  __shared__ float dtl[CHUNKL];
  __shared__ float eAl[CHUNKL];
  if (tid < CHUNKL)
    dtl[tid] = dt2[((size_t)b * L_SEQ + c * CHUNKL + tid) * NHEADS + h];
  __syncthreads();
  // wave-parallel inclusive scan of Ah*dtl (128 elems, 2/lane, wave 0 only)
  if (tid < 64) {
    float Ah = -__expf(A_log[h]);
    float v0 = Ah * dtl[2 * tid];
    float v1 = Ah * dtl[2 * tid + 1];
    float s = v0 + v1;
#pragma unroll
    for (int off = 1; off < 64; off <<= 1) {
      float t = __shfl_up(s, off);
      if (tid >= off) s += t;
    }
    acs[2 * tid]     = s - v1;
    acs[2 * tid + 1] = s;
  }
  __syncthreads();
  if (tid < CHUNKL) eAl[tid] = __expf(acs[tid]);   // <= 1
  // T14: issue Ce + St global loads NOW; values consumed only after GEMM1.
  bf16x8v ce_r[8], st_r[4];
  {
    int cofs = b ? 2432 : 2176;
#pragma unroll
    for (int it = 0; it < 8; it++) {
      int o = tid + it * 256;
      int l = o >> 4;
      int n8 = (o & 15) * 8;
      int t = b ? (L_SEQ - 1 - (c * CHUNKL + l)) : (c * CHUNKL + l);
      ce_r[it] = *(const bf16x8v*)&xbc[(size_t)t * CONVDIM + cofs + n8];
    }
    const bf16* stp = states + (size_t)gid * (HEADDIM * DSTATE);
#pragma unroll
    for (int it = 0; it < 4; it++) {
      int o = tid + it * 256;
      st_r[it] = *(const bf16x8v*)&stp[o * 8];
    }
  }
  // SX <- xdtT[p][s]: lane->s, conflict-free scatter
  for (int o = tid; o < CHUNKL * HEADDIM / 8; o += 256) {   // 1024 vecs
    int s = o & 127;
    int p8 = (o >> 7) * 8;
    int t = b ? (L_SEQ - 1 - (c * CHUNKL + s)) : (c * CHUNKL + s);
    bf16x8v xv = *(const bf16x8v*)&xbc[(size_t)t * CONVDIM + h * HEADDIM + p8];
    float d = dtl[s];
#pragma unroll
    for (int j = 0; j < 8; j++) SX[p8 + j][s] = f2b(sh2f(xv[j]) * d);
  }
  // WB <- W[l][s] = G*exp(acs[l]-acs[s]) (s<=l): b128 writes; upper-tri vecs
  // (s8 > l) skip the G load and expf entirely.
  {
    const bf16* Gb = G + (size_t)bc * CHUNKL * CHUNKL;
    for (int o = tid; o < CHUNKL * CHUNKL / 8; o += 256) {  // 2048 vecs
      int l = o >> 4;
      int s8 = (o & 15) * 8;
      bf16x8v wv;
      if (s8 > l) {
#pragma unroll
        for (int j = 0; j < 8; j++) wv[j] = 0;
      } else {
        bf16x8v g = *(const bf16x8v*)&Gb[l * CHUNKL + s8];
        float al = acs[l];
#pragma unroll
        for (int j = 0; j < 8; j++) {
          int s = s8 + j;
          float e = (s <= l) ? sh2f(g[j]) * __expf(al - acs[s]) : 0.f;
          wv[j] = f2bs(e);
        }
      }
      *(bf16x8v*)&WB[l][s8] = wv;
    }
  }
  __syncthreads();
  f32x4v accY[2][4];
#pragma unroll
  for (int i = 0; i < 2; i++)
#pragma unroll
    for (int j = 0; j < 4; j++) accY[i][j] = (f32x4v){0.f, 0.f, 0.f, 0.f};
  // Y_diag: A=W rows [32w,32w+32), B=xdtT p-tiles, k=s.
  // Wave-uniform skip: k0 > 32w+31 => A block all-zero (strict upper triangle).
#pragma unroll
  for (int k0 = 0; k0 < 128; k0 += 32) {
    if (k0 > w * 32 + 31) break;
    bf16x8v a0 = *(const bf16x8v*)&WB[w * 32 + (lane & 15)][(lane >> 4) * 8 + k0];
    bf16x8v a1 = *(const bf16x8v*)&WB[w * 32 + 16 + (lane & 15)][(lane >> 4) * 8 + k0];
#pragma unroll
    for (int j = 0; j < 4; j++) {
      bf16x8v bv = *(const bf16x8v*)&SX[j * 16 + (lane & 15)][(lane >> 4) * 8 + k0];
      accY[0][j] = __builtin_amdgcn_mfma_f32_16x16x32_bf16(a0, bv, accY[0][j], 0, 0, 0);
      accY[1][j] = __builtin_amdgcn_mfma_f32_16x16x32_bf16(a1, bv, accY[1][j], 0, 0, 0);
    }
  }
  __syncthreads();   // all phase-1 LDS reads done
  // restage from REGISTERS (global latency already hidden under GEMM1):
  // WB <- Ce*eAl, SX <- St
  {
#pragma unroll
    for (int it = 0; it < 8; it++) {
      int o = tid + it * 256;
      int l = o >> 4;
      int n8 = (o & 15) * 8;
      float e = eAl[l];
      bf16x8v ov;
#pragma unroll
      for (int j = 0; j < 8; j++) ov[j] = f2bs(sh2f(ce_r[it][j]) * e);
      *(bf16x8v*)&WB[l][n8] = ov;
    }
#pragma unroll
    for (int it = 0; it < 4; it++) {
      int o = tid + it * 256;
      int p = o >> 4;
      int n8 = (o & 15) * 8;
      *(bf16x8v*)&SX[p][n8] = st_r[it];
    }
  }
  __syncthreads();
  // Y_off: A=Ce rows, B=St p-tiles, k=n; accumulate into same accY
#pragma unroll
  for (int k0 = 0; k0 < 128; k0 += 32) {
    bf16x8v a0 = *(const bf16x8v*)&WB[w * 32 + (lane & 15)][(lane >> 4) * 8 + k0];
    bf16x8v a1 = *(const bf16x8v*)&WB[w * 32 + 16 + (lane & 15)][(lane >> 4) * 8 + k0];
#pragma unroll
    for (int j = 0; j < 4; j++) {
      bf16x8v bv = *(const bf16x8v*)&SX[j * 16 + (lane & 15)][(lane >> 4) * 8 + k0];
      accY[0][j] = __builtin_amdgcn_mfma_f32_16x16x32_bf16(a0, bv, accY[0][j], 0, 0, 0);
      accY[1][j] = __builtin_amdgcn_mfma_f32_16x16x32_bf16(a1, bv, accY[1][j], 0, 0, 0);
    }
  }
  int quad = lane >> 4, cn = lane & 15;
  float Dh = Dp[h];
#pragma unroll
  for (int i = 0; i < 2; i++)
#pragma unroll
    for (int j = 0; j < 4; j++)
#pragma unroll
      for (int r = 0; r < 4; r++) {
        int l = w * 32 + i * 16 + quad * 4 + r;
        int p = j * 16 + cn;
        int t = b ? (L_SEQ - 1 - (c * CHUNKL + l)) : (c * CHUNKL + l);
        float xv = b2f(xbc[(size_t)t * CONVDIM + h * HEADDIM + p]);
        size_t yi = ((size_t)b * L_SEQ + c * CHUNKL + l) * DINNER + h * HEADDIM + p;
        Y[yi] = f2b(accY[i][j][r] + xv * Dh);
      }
}

// ---------------- combine: shift, flip, +x*fd, gate, RMSNorm (vectorized) ----------------
__global__ __launch_bounds__(256) void combine_kernel(
    const bf16* __restrict__ Y, const bf16* __restrict__ xbc,
    const bf16* __restrict__ zx, const float* __restrict__ fd,
    const float* __restrict__ norm_w, bf16* __restrict__ yn) {
  int t = blockIdx.x;
  int tid = threadIdx.x;
  int j8 = tid * 8;
  float yf[8], yb[8];
#pragma unroll
  for (int j = 0; j < 8; j++) { yf[j] = 0.f; yb[j] = 0.f; }
  if (t >= 1) {
    bf16x8v v = *(const bf16x8v*)&Y[(size_t)(t - 1) * DINNER + j8];
#pragma unroll
    for (int j = 0; j < 8; j++) yf[j] = sh2f(v[j]);
  }
  if (t <= L_SEQ - 2) {
    bf16x8v v = *(const bf16x8v*)&Y[((size_t)L_SEQ + (L_SEQ - 2 - t)) * DINNER + j8];
#pragma unroll
    for (int j = 0; j < 8; j++) yb[j] = sh2f(v[j]);
  }
  bf16x8v xogv = *(const bf16x8v*)&xbc[(size_t)t * CONVDIM + j8];
  bf16x8v zv = *(const bf16x8v*)&zx[(size_t)t * DPROJ + j8];
  float fdv = fd[t * NHEADS + (j8 >> 6)];
  float yg[8];
  float ss = 0.f;
#pragma unroll
  for (int j = 0; j < 8; j++) {
    float y = yf[j] + yb[j] + sh2f(xogv[j]) * fdv;
    float z = sh2f(zv[j]);
    float g = y * (z / (1.f + __expf(-z)));
    yg[j] = g;
    ss += g * g;
  }
#pragma unroll
  for (int off = 32; off > 0; off >>= 1) ss += __shfl_down(ss, off);
  __shared__ float red[4];
  if ((tid & 63) == 0) red[tid >> 6] = ss;
  __syncthreads();
  float tot = red[0] + red[1] + red[2] + red[3];
  float scale = rsqrtf(tot / (float)DINNER + 1e-5f);
  float4 nw0 = *(const float4*)&norm_w[j8];
  float4 nw1 = *(const float4*)&norm_w[j8 + 4];
  bf16x8v ov;
  ov[0] = f2bs(yg[0] * scale * nw0.x);
  ov[1] = f2bs(yg[1] * scale * nw0.y);
  ov[2] = f2bs(yg[2] * scale * nw0.z);
  ov[3] = f2bs(yg[3] * scale * nw0.w);
  ov[4] = f2bs(yg[4] * scale * nw1.x);
  ov[5] = f2bs(yg[5] * scale * nw1.y);
  ov[6] = f2bs(yg[6] * scale * nw1.z);
  ov[7] = f2bs(yg[7] * scale * nw1.w);
  *(bf16x8v*)&yn[(size_t)t * DINNER + j8] = ov;
}

// ---------------- launch ----------------
extern "C" void kernel_launch(void* const* d_in, const int* in_sizes, int n_in,
                              void* d_out, int out_size, void* d_ws, size_t ws_size,
                              hipStream_t stream) {
  const float* u         = (const float*)d_in[0];
  const float* in_proj_w = (const float*)d_in[1];
  const float* conv_w    = (const float*)d_in[2];
  const float* conv_b    = (const float*)d_in[3];
  const float* dt_bias   = (const float*)d_in[4];
  const float* A_log     = (const float*)d_in[5];
  const float* Dp        = (const float*)d_in[6];
  const float* fc_D_w    = (const float*)d_in[7];
  const float* norm_w    = (const float*)d_in[8];
  const float* out_proj_w= (const float*)d_in[9];
  float* out = (float*)d_out;

  char* base = (char*)d_ws;
  bf16*  zx  = (bf16*)base;  base += (size_t)L_SEQ * DPROJ * 2;                    // 38.3 MB
  bf16*  xbc = (bf16*)base;  base += (size_t)L_SEQ * CONVDIM * 2;                  // 21.0 MB
  float* dt2 = (float*)base; base += (size_t)2 * L_SEQ * NHEADS * 4;               //  1.0 MB
  bf16*  G   = (bf16*)base;  base += (size_t)2 * NCHUNK * CHUNKL * CHUNKL * 4;     //  4.2 MB region
  bf16*  Yb  = (bf16*)base;  base += (size_t)2 * L_SEQ * DINNER * 4;               // 67.1 MB region
  bf16*  stb = (bf16*)base;  base += (size_t)2 * NCHUNK * NHEADS * HEADDIM * DSTATE * 4; // 67.1 MB region
  float* cs  = (float*)base; base += (size_t)2 * NCHUNK * NHEADS * 4;              //  8 KB
  // aliases into dead regions:
  bf16*  u_bf   = (bf16*)Yb;                          // 8.4 MB   (Yb live only after yoff)
  bf16*  w1p_bf = (bf16*)((char*)Yb + 9437184);       // 9.7 MB   (in_proj_w padded to 4736 rows)
  bf16*  w2_bf  = (bf16*)G;                           // 4.2 MB   (G dead after yoff)
  bf16*  yn     = (bf16*)stb;                         // 16.8 MB  (stb dead after yoff)
  float* fd     = (float*)((char*)stb + 33554432);    //  0.5 MB
  float* p1     = (float*)Yb;                         // 16.8 MB  (Yb dead after combine)

  // 0. fused casts for MFMA gemm1 (w1 zero-padded to NPAD1 rows)
  cast2_kernel<<<(L_SEQ * DMODEL + NPAD1 * DMODEL) / 256, 256, 0, stream>>>(
      u, in_proj_w, u_bf, w1p_bf);
  // 1a. in_proj main: cols [0,4096) (8-phase 256^2, 256 blocks = exactly 1 round)
  gemm1_8ph<<<(L_SEQ / 256) * G1_GN, 512, 0, stream>>>(u_bf, w1p_bf, zx);
  // 1b. in_proj remainder: cols [4096,4672) (128^2 gemm, 160 blocks)
  gemm_mfma<bf16><<<(L_SEQ / 128) * ((NPAD1 - NSPLIT) / 128), 256, 0, stream>>>(
      u_bf, DMODEL, w1p_bf + (size_t)NSPLIT * DMODEL, DMODEL,
      zx + NSPLIT, DPROJ, DPROJ - NSPLIT, DMODEL,
      L_SEQ / 128, (NPAD1 - NSPLIT) / 128, 0);
  // 2. conv + silu + dt (fused)
  conv_dt_kernel<<<CONV_BLOCKS + (2 * L_SEQ * NHEADS) / 256, 256, 0, stream>>>(
      zx, conv_w, conv_b, xbc, dt_bias, dt2);
  // 3a. G = C B^T per (b,c), quarter-split (MFMA, bf16)
  gmat_kernel<<<2 * NCHUNK * 4, 256, 0, stream>>>(xbc, G);
  // 3b. chunk states (MFMA, bf16)
  chunk_kernel<<<2 * NCHUNK * NHEADS, 256, 0, stream>>>(
      xbc, dt2, A_log, stb, cs);
  // 3c. inter-chunk scan (register-batched)
  scan_kernel<<<(2 * NHEADS * HEADDIM * DSTATE) / 256, 256, 0, stream>>>(stb, cs);
  // 3d. fused Y = Y_diag + Y_off + D*x (MFMA; R6 tiling + T14 reg-preload)
  yoff_kernel<<<2 * NCHUNK * NHEADS, 256, 0, stream>>>(
      xbc, dt2, A_log, G, stb, Dp, Yb);
  // 4a. cast out_proj_w (into dead G region)
  cast_kernel<<<(DMODEL * DINNER + 255) / 256, 256, 0, stream>>>(
      out_proj_w, w2_bf, DMODEL * DINNER, DMODEL * DINNER);
  // 4b. fd = x_og @ fc_D_w^T + D  (k-split across waves, 1024 blocks)
  fc_kernel<<<L_SEQ / 4, 256, 0, stream>>>(xbc, fc_D_w, Dp, fd);
  // 5. combine + gate + RMSNorm
  combine_kernel<<<L_SEQ, 256, 0, stream>>>(Yb, xbc, zx, fd, norm_w, yn);
  // 6. out_proj split-K=2 (512 blocks = 2/CU) + add pass
  outproj_ks<<<512, 256, 0, stream>>>(yn, w2_bf, out, p1);
  add_kernel<<<(L_SEQ * DMODEL) / 1024, 256, 0, stream>>>(out, p1);
}

// Round 10
// 354.454 us; speedup vs baseline: 1.1431x; 1.0947x over previous
//
#include <hip/hip_runtime.h>
#include <hip/hip_bf16.h>
#include <math.h>

// ---------------- problem constants ----------------
#define L_SEQ   4096
#define DMODEL  1024
#define DINNER  2048
#define NHEADS  32
#define HEADDIM 64
#define DSTATE  128
#define NCHUNK  32
#define CHUNKL  128
#define CONVDIM 2560
#define DPROJ   4672   // 2*DINNER + 2*(2*DSTATE) + 2*NHEADS
#define NPAD1   4736   // DPROJ padded to multiple of 128 (for remainder gemm)
#define NSPLIT  4096   // cols [0,NSPLIT) via 8-phase 256^2 (256 blocks = 1 round);
                       // cols [NSPLIT,DPROJ) via 128^2 gemm (160 blocks)

typedef __hip_bfloat16 bf16;
__device__ __forceinline__ float b2f(bf16 x) { return __bfloat162float(x); }
__device__ __forceinline__ bf16 f2b(float x) { return __float2bfloat16(x); }
__device__ __forceinline__ float sh2f(short s) {
  return __uint_as_float(((unsigned int)(unsigned short)s) << 16);
}
__device__ __forceinline__ short f2bs(float x) {
  bf16 t = __float2bfloat16(x);
  return *reinterpret_cast<short*>(&t);
}

typedef __attribute__((ext_vector_type(8))) short bf16x8v;
typedef __attribute__((ext_vector_type(4))) float f32x4v;

// zxbcdt column layout: [0,2048) = z ; [2048,4608) = xBC ; [4608,4672) = dt raw
// xBC_conv channel layout: [0,2048) = x ; fw B = [2048,2176) C = [2176,2304)
//                          bw B = [2304,2432) C = [2432,2560)  (bw streams time-flipped)

// ---------------- fused casts: u -> bf16 and in_proj_w -> bf16 (zero-padded) ----------------
__global__ __launch_bounds__(256) void cast2_kernel(
    const float* __restrict__ u, const float* __restrict__ w1,
    bf16* __restrict__ u_bf, bf16* __restrict__ w1_bf) {
  const int NU = (L_SEQ * DMODEL) / 256;   // 16384 blocks
  int bid = blockIdx.x;
  if (bid < NU) {
    int i = bid * 256 + threadIdx.x;
    u_bf[i] = f2b(u[i]);
  } else {
    int i = (bid - NU) * 256 + threadIdx.x;
    w1_bf[i] = (i < DPROJ * DMODEL) ? f2b(w1[i]) : f2b(0.f);
  }
}

// ---------------- f32 -> bf16 cast ----------------
__global__ __launch_bounds__(256) void cast_kernel(
    const float* __restrict__ src, bf16* __restrict__ dst, int n_src, int n_tot) {
  int i = blockIdx.x * 256 + threadIdx.x;
  if (i < n_tot) dst[i] = (i < n_src) ? f2b(src[i]) : f2b(0.f);
}

// ================= in_proj main: 8-phase 256x256 GEMM (R1-verified body) =================
// C[m,n] = sum_k A[m,k]*B[n,k]; A = u_bf [4096][1024], B = w1p_bf rows [0,4096),
// C = zx cols [0,4096). BK=64, 512 threads = 8 waves (2Mx4N), per-wave C = 128x64.
// Grid = 16 x 16 = 256 blocks = exactly one residency round (128 KiB LDS -> 1/CU).
// Register budget (the R2/R3 lesson): acc[8][4] = 128 regs + a/b frags 64 + addr
// ~= 244 <= 256-reg cap at 2 waves/SIMD. BN=320 (acc 160) does NOT fit -- spills.
// LDS: 2 dbuf slots x (A 256x64 + B 256x64), 16 subtiles of [16r][32c] per 128x64
// half, st_16x32 XOR swizzle via pre-swizzled global source (linear gload_lds dest)
// + swizzled ds_read addr. vmcnt(6) once per K-tile; vmcnt(0) only at t=NT-2.
#define G1_K  1024
#define G1_GN 16            // N tiles of 256 covering [0,4096)
#define G1_NT (G1_K / 64)   // 16 K-tiles

__global__ __launch_bounds__(512, 2) void gemm1_8ph(
    const bf16* __restrict__ A, const bf16* __restrict__ B, bf16* __restrict__ C) {
  __shared__ bf16 Al[2][2][8192];   // [slot][half][subtiled 128x64]  64 KB
  __shared__ bf16 Bl[2][2][8192];   // 64 KB
  const int tid = threadIdx.x;
  const int lane = tid & 63;
  const int w = tid >> 6;        // 0..7
  const int wm = w >> 2;         // 0..1 -> C rows [wm*128, +128)
  const int wn = w & 3;          // 0..3 -> C cols [wn*64, +64)
  const int bm = (blockIdx.x / G1_GN) * 256;
  const int bn = (blockIdx.x % G1_GN) * 256;
  // staging source pre-swizzle (bf16 units): dest r_in = lane>>2, swz bit = r_in bit3
  const int scol = ((lane & 3) ^ (((lane >> 5) & 1) << 1)) * 8;
  // read-side swizzled col within subtile: flip bit4 when row bit3 set
  const int cin = ((lane >> 4) * 8) ^ (((lane >> 3) & 1) << 4);
  const int r16 = lane & 15;
  const bf16* Ag = A + (size_t)bm * G1_K;
  const bf16* Bg = B + (size_t)bn * G1_K;

  // stage one 128x64 half-tile (A: mat=0, B: mat=1) of K-tile tt.
  // wave w fills subtiles w and 8+w (1024B each, linear dest; swizzle via source).
  auto stage = [&](int mat, int tt, int hf) {
    const bf16* g = (mat ? Bg : Ag)
        + (size_t)(hf * 128 + (w >> 1) * 16 + (lane >> 2)) * G1_K
        + tt * 64 + (w & 1) * 32 + scol;
    bf16* d0 = mat ? &Bl[tt & 1][hf][0] : &Al[tt & 1][hf][0];
    __builtin_amdgcn_global_load_lds(
        (const __attribute__((address_space(1))) void*)g,
        (__attribute__((address_space(3))) void*)(d0 + w * 512), 16, 0, 0);
    __builtin_amdgcn_global_load_lds(
        (const __attribute__((address_space(1))) void*)(g + (size_t)64 * G1_K),
        (__attribute__((address_space(3))) void*)(d0 + (8 + w) * 512), 16, 0, 0);
  };

  f32x4v acc[8][4];
#pragma unroll
  for (int i = 0; i < 8; i++)
#pragma unroll
    for (int j = 0; j < 4; j++) acc[i][j] = (f32x4v){0.f, 0.f, 0.f, 0.f};

  // prologue: tile0 {A0,A1,B0,B1}, tile1 {A0,A1,B0} = 7 half-tiles (14 loads)
  stage(0, 0, 0); stage(0, 0, 1); stage(1, 0, 0); stage(1, 0, 1);
  stage(0, 1, 0); stage(0, 1, 1); stage(1, 1, 0);
  asm volatile("s_waitcnt vmcnt(6)" ::: "memory");   // tile0 fully resident
  __builtin_amdgcn_s_barrier();
  __builtin_amdgcn_sched_barrier(0);

#pragma unroll 2
  for (int t = 0; t < G1_NT; ++t) {
    const int slot = t & 1;
    const bf16* Ah = &Al[slot][wm][0];
    const bf16* Bh = &Bl[slot][wn >> 1][0];
    const int brb = (wn & 1) * 4;   // B subtile-row base within half
    bf16x8v a[4][2], b[4][2];
    // ---- phase 0: ds A m0-3 + B n0-1 (12 reads); stage B1(t+1); mfma m0-3 x n0-1
#pragma unroll
    for (int i = 0; i < 4; i++) {
      a[i][0] = *(const bf16x8v*)&Ah[(i * 2 + 0) * 512 + r16 * 32 + cin];
      a[i][1] = *(const bf16x8v*)&Ah[(i * 2 + 1) * 512 + r16 * 32 + cin];
    }
#pragma unroll
    for (int j = 0; j < 2; j++) {
      b[j][0] = *(const bf16x8v*)&Bh[((brb + j) * 2 + 0) * 512 + r16 * 32 + cin];
      b[j][1] = *(const bf16x8v*)&Bh[((brb + j) * 2 + 1) * 512 + r16 * 32 + cin];
    }
    if (t + 1 < G1_NT) stage(1, t + 1, 1);
    __builtin_amdgcn_s_barrier();
    asm volatile("s_waitcnt lgkmcnt(0)" ::: "memory");
    __builtin_amdgcn_s_setprio(1);
#pragma unroll
    for (int i = 0; i < 4; i++)
#pragma unroll
      for (int j = 0; j < 2; j++) {
        acc[i][j] = __builtin_amdgcn_mfma_f32_16x16x32_bf16(a[i][0], b[j][0], acc[i][j], 0, 0, 0);
        acc[i][j] = __builtin_amdgcn_mfma_f32_16x16x32_bf16(a[i][1], b[j][1], acc[i][j], 0, 0, 0);
      }
    __builtin_amdgcn_s_setprio(0);
    __builtin_amdgcn_s_barrier();
    // ---- phase 1: ds B n2-3 (4 reads); mfma m0-3 x n2-3
#pragma unroll
    for (int j = 2; j < 4; j++) {
      b[j][0] = *(const bf16x8v*)&Bh[((brb + j) * 2 + 0) * 512 + r16 * 32 + cin];
      b[j][1] = *(const bf16x8v*)&Bh[((brb + j) * 2 + 1) * 512 + r16 * 32 + cin];
    }
    __builtin_amdgcn_s_barrier();
    asm volatile("s_waitcnt lgkmcnt(0)" ::: "memory");
    __builtin_amdgcn_s_setprio(1);
#pragma unroll
    for (int i = 0; i < 4; i++)
#pragma unroll
      for (int j = 2; j < 4; j++) {
        acc[i][j] = __builtin_amdgcn_mfma_f32_16x16x32_bf16(a[i][0], b[j][0], acc[i][j], 0, 0, 0);
        acc[i][j] = __builtin_amdgcn_mfma_f32_16x16x32_bf16(a[i][1], b[j][1], acc[i][j], 0, 0, 0);
      }
    __builtin_amdgcn_s_setprio(0);
    __builtin_amdgcn_s_barrier();
    // ---- phase 2: ds A m4-7 (8 reads); stage B0(t+2); mfma m4-7 x n2-3
#pragma unroll
    for (int i = 0; i < 4; i++) {
      a[i][0] = *(const bf16x8v*)&Ah[((4 + i) * 2 + 0) * 512 + r16 * 32 + cin];
      a[i][1] = *(const bf16x8v*)&Ah[((4 + i) * 2 + 1) * 512 + r16 * 32 + cin];
    }
    if (t + 2 < G1_NT) stage(1, t + 2, 0);
    __builtin_amdgcn_s_barrier();
    asm volatile("s_waitcnt lgkmcnt(0)" ::: "memory");
    __builtin_amdgcn_s_setprio(1);
#pragma unroll
    for (int i = 0; i < 4; i++)
#pragma unroll
      for (int j = 2; j < 4; j++) {
        acc[4 + i][j] = __builtin_amdgcn_mfma_f32_16x16x32_bf16(a[i][0], b[j][0], acc[4 + i][j], 0, 0, 0);
        acc[4 + i][j] = __builtin_amdgcn_mfma_f32_16x16x32_bf16(a[i][1], b[j][1], acc[4 + i][j], 0, 0, 0);
      }
    __builtin_amdgcn_s_setprio(0);
    __builtin_amdgcn_s_barrier();
    // ---- phase 3: stage A0,A1(t+2); mfma m4-7 x n0-1; counted vmcnt; barrier
    if (t + 2 < G1_NT) { stage(0, t + 2, 0); stage(0, t + 2, 1); }
    __builtin_amdgcn_s_barrier();
    __builtin_amdgcn_s_setprio(1);
#pragma unroll
    for (int i = 0; i < 4; i++)
#pragma unroll
      for (int j = 0; j < 2; j++) {
        acc[4 + i][j] = __builtin_amdgcn_mfma_f32_16x16x32_bf16(a[i][0], b[j][0], acc[4 + i][j], 0, 0, 0);
        acc[4 + i][j] = __builtin_amdgcn_mfma_f32_16x16x32_bf16(a[i][1], b[j][1], acc[4 + i][j], 0, 0, 0);
      }
    __builtin_amdgcn_s_setprio(0);
    if (t < G1_NT - 2)       asm volatile("s_waitcnt vmcnt(6)" ::: "memory");
    else if (t == G1_NT - 2) asm volatile("s_waitcnt vmcnt(0)" ::: "memory");
    __builtin_amdgcn_s_barrier();
    __builtin_amdgcn_sched_barrier(0);
  }

  const int quad = lane >> 4;
  const int cn = lane & 15;
#pragma unroll
  for (int i = 0; i < 8; i++)
#pragma unroll
    for (int j = 0; j < 4; j++) {
      int col = bn + wn * 64 + j * 16 + cn;
      if (col < DPROJ) {
#pragma unroll
        for (int r = 0; r < 4; r++) {
          int row = bm + wm * 128 + i * 16 + quad * 4 + r;
          C[(size_t)row * DPROJ + col] = f2b(acc[i][j][r]);
        }
      }
    }
}

// ---------------- MFMA GEMM: C[m,n] = sum_k A[m,k]*B[n,k], bf16 in, f32 acc ----------------
// (used for the in_proj N-remainder)
template <typename TC>
__global__ __launch_bounds__(256) void gemm_mfma(
    const bf16* __restrict__ A, int lda,
    const bf16* __restrict__ B, int ldb,
    TC* __restrict__ C, int ldc,
    int N, int K, int gridM, int gridN, int swz) {
  __shared__ short As[128][32];
  __shared__ short Bs[128][32];
  int tid = threadIdx.x;
  int lane = tid & 63;
  int w = tid >> 6;            // wave 0..3
  int wr = w >> 1, wc = w & 1; // 2x2 wave grid
  int bid = blockIdx.x;
  int bm, bn;
  if (swz) {
    int mst = gridM >> 3;
    int xk = bid & 7, q = bid >> 3;
    bm = (xk + 8 * (q % mst)) * 128;
    bn = (q / mst) * 128;
  } else {
    bm = (bid / gridN) * 128;
    bn = (bid % gridN) * 128;
  }
  f32x4v acc[4][4];
#pragma unroll
  for (int i = 0; i < 4; i++)
#pragma unroll
    for (int j = 0; j < 4; j++) acc[i][j] = (f32x4v){0.f, 0.f, 0.f, 0.f};

  const bf16* Ab = A + (size_t)(bm + w * 32 + (lane >> 2)) * lda + (lane & 3) * 8;
  const bf16* Bb = B + (size_t)(bn + w * 32 + (lane >> 2)) * ldb + (lane & 3) * 8;

  for (int k0 = 0; k0 < K; k0 += 32) {
    __builtin_amdgcn_global_load_lds(
        (const __attribute__((address_space(1))) void*)(Ab + k0),
        (__attribute__((address_space(3))) void*)&As[w * 32][0], 16, 0, 0);
    __builtin_amdgcn_global_load_lds(
        (const __attribute__((address_space(1))) void*)(Ab + (size_t)16 * lda + k0),
        (__attribute__((address_space(3))) void*)&As[w * 32 + 16][0], 16, 0, 0);
    __builtin_amdgcn_global_load_lds(
        (const __attribute__((address_space(1))) void*)(Bb + k0),
        (__attribute__((address_space(3))) void*)&Bs[w * 32][0], 16, 0, 0);
    __builtin_amdgcn_global_load_lds(
        (const __attribute__((address_space(1))) void*)(Bb + (size_t)16 * ldb + k0),
        (__attribute__((address_space(3))) void*)&Bs[w * 32 + 16][0], 16, 0, 0);
    __syncthreads();
    bf16x8v af[4], bv[4];
#pragma unroll
    for (int i = 0; i < 4; i++)
      af[i] = *(const bf16x8v*)&As[wr * 64 + i * 16 + (lane & 15)][(lane >> 4) * 8];
#pragma unroll
    for (int j = 0; j < 4; j++)
      bv[j] = *(const bf16x8v*)&Bs[wc * 64 + j * 16 + (lane & 15)][(lane >> 4) * 8];
#pragma unroll
    for (int i = 0; i < 4; i++)
#pragma unroll
      for (int j = 0; j < 4; j++)
        acc[i][j] = __builtin_amdgcn_mfma_f32_16x16x32_bf16(af[i], bv[j], acc[i][j], 0, 0, 0);
    __syncthreads();
  }
  int quad = lane >> 4;
  int cn = lane & 15;
#pragma unroll
  for (int i = 0; i < 4; i++) {
#pragma unroll
    for (int j = 0; j < 4; j++) {
      int col = bn + wc * 64 + j * 16 + cn;
      if (col < N) {
#pragma unroll
        for (int r = 0; r < 4; r++) {
          int row = bm + wr * 64 + i * 16 + quad * 4 + r;
          float v = acc[i][j][r];
          if constexpr (sizeof(TC) == 2) C[(size_t)row * ldc + col] = f2b(v);
          else                           C[(size_t)row * ldc + col] = v;
        }
      }
    }
  }
}

// ---------------- out_proj split-K=2: 512 blocks (2/CU, 2 waves/SIMD) ----------------
// R9: ks=0 -> K[0,1024) writes out; ks=1 -> K[1024,2048) writes P1; out += P1.
__global__ __launch_bounds__(256) void outproj_ks(
    const bf16* __restrict__ A, const bf16* __restrict__ B,
    float* __restrict__ C0, float* __restrict__ C1) {
  __shared__ short As[128][32];
  __shared__ short Bs[128][32];
  int tid = threadIdx.x;
  int lane = tid & 63;
  int w = tid >> 6;
  int wr = w >> 1, wc = w & 1;
  int bid = blockIdx.x;
  int ks = bid >> 8;            // 0/1 K-half
  int q = bid & 255;
  int xk = q & 7, qq = q >> 3;
  int bm = (xk + 8 * (qq & 3)) * 128;   // 32 m-tiles
  int bn = (qq >> 2) * 128;             // 8 n-tiles
  float* C = ks ? C1 : C0;
  f32x4v acc[4][4];
#pragma unroll
  for (int i = 0; i < 4; i++)
#pragma unroll
    for (int j = 0; j < 4; j++) acc[i][j] = (f32x4v){0.f, 0.f, 0.f, 0.f};

  const bf16* Ab = A + (size_t)(bm + w * 32 + (lane >> 2)) * DINNER + ks * 1024 + (lane & 3) * 8;
  const bf16* Bb = B + (size_t)(bn + w * 32 + (lane >> 2)) * DINNER + ks * 1024 + (lane & 3) * 8;

  for (int k0 = 0; k0 < 1024; k0 += 32) {
    __builtin_amdgcn_global_load_lds(
        (const __attribute__((address_space(1))) void*)(Ab + k0),
        (__attribute__((address_space(3))) void*)&As[w * 32][0], 16, 0, 0);
    __builtin_amdgcn_global_load_lds(
        (const __attribute__((address_space(1))) void*)(Ab + (size_t)16 * DINNER + k0),
        (__attribute__((address_space(3))) void*)&As[w * 32 + 16][0], 16, 0, 0);
    __builtin_amdgcn_global_load_lds(
        (const __attribute__((address_space(1))) void*)(Bb + k0),
        (__attribute__((address_space(3))) void*)&Bs[w * 32][0], 16, 0, 0);
    __builtin_amdgcn_global_load_lds(
        (const __attribute__((address_space(1))) void*)(Bb + (size_t)16 * DINNER + k0),
        (__attribute__((address_space(3))) void*)&Bs[w * 32 + 16][0], 16, 0, 0);
    __syncthreads();
    bf16x8v af[4], bv[4];
#pragma unroll
    for (int i = 0; i < 4; i++)
      af[i] = *(const bf16x8v*)&As[wr * 64 + i * 16 + (lane & 15)][(lane >> 4) * 8];
#pragma unroll
    for (int j = 0; j < 4; j++)
      bv[j] = *(const bf16x8v*)&Bs[wc * 64 + j * 16 + (lane & 15)][(lane >> 4) * 8];
#pragma unroll
    for (int i = 0; i < 4; i++)
#pragma unroll
      for (int j = 0; j < 4; j++)
        acc[i][j] = __builtin_amdgcn_mfma_f32_16x16x32_bf16(af[i], bv[j], acc[i][j], 0, 0, 0);
    __syncthreads();
  }
  int quad = lane >> 4;
  int cn = lane & 15;
#pragma unroll
  for (int i = 0; i < 4; i++)
#pragma unroll
    for (int j = 0; j < 4; j++) {
      int col = bn + wc * 64 + j * 16 + cn;
#pragma unroll
      for (int r = 0; r < 4; r++) {
        int row = bm + wr * 64 + i * 16 + quad * 4 + r;
        C[(size_t)row * DMODEL + col] = acc[i][j][r];
      }
    }
}

// ---------------- out += P1 (vectorized) ----------------
__global__ __launch_bounds__(256) void add_kernel(
    float* __restrict__ out, const float* __restrict__ P) {
  int i = (blockIdx.x * 256 + threadIdx.x) * 4;
  float4 a = *(const float4*)&out[i];
  float4 b = *(const float4*)&P[i];
  a.x += b.x; a.y += b.y; a.z += b.z; a.w += b.w;
  *(float4*)&out[i] = a;
}

// ---------------- fc via MFMA split-K=16 ----------------
// R10: old fc_kernel was a per-lane W-row gather (64 lanes -> 64 cachelines per
// load, VGPR=28 no prefetch depth, MfmaUtil 0, 50 us profiled for 0.54 GFLOP).
// New: fdp[ks][t][h] partial GEMM (M=4096, N=32, K-chunk=128), grid = 32 m-tiles
// x 16 k-chunks = 512 blocks (2/CU, 2 waves/SIMD); then fc_reduce sums + D.
#define FC_KS 16
__global__ __launch_bounds__(256) void fc_mfma(
    const bf16* __restrict__ xbc, const bf16* __restrict__ Wb,
    float* __restrict__ fdp) {
  __shared__ short As[128][32];
  __shared__ short Bs[32][32];
  int tid = threadIdx.x;
  int lane = tid & 63;
  int w = tid >> 6;
  int bid = blockIdx.x;
  int ks = bid & (FC_KS - 1);
  int bm = (bid / FC_KS) * 128;
  f32x4v acc[2][2];
#pragma unroll
  for (int i = 0; i < 2; i++)
#pragma unroll
    for (int j = 0; j < 2; j++) acc[i][j] = (f32x4v){0.f, 0.f, 0.f, 0.f};

  const bf16* Ab = xbc + (size_t)(bm + w * 32 + (lane >> 2)) * CONVDIM + ks * 128 + (lane & 3) * 8;
  const bf16* Bb = Wb + (size_t)(lane >> 2) * DINNER + ks * 128 + (lane & 3) * 8;

  for (int k0 = 0; k0 < 128; k0 += 32) {
    __builtin_amdgcn_global_load_lds(
        (const __attribute__((address_space(1))) void*)(Ab + k0),
        (__attribute__((address_space(3))) void*)&As[w * 32][0], 16, 0, 0);
    __builtin_amdgcn_global_load_lds(
        (const __attribute__((address_space(1))) void*)(Ab + (size_t)16 * CONVDIM + k0),
        (__attribute__((address_space(3))) void*)&As[w * 32 + 16][0], 16, 0, 0);
    if (w == 0) {
      __builtin_amdgcn_global_load_lds(
          (const __attribute__((address_space(1))) void*)(Bb + k0),
          (__attribute__((address_space(3))) void*)&Bs[0][0], 16, 0, 0);
      __builtin_amdgcn_global_load_lds(
          (const __attribute__((address_space(1))) void*)(Bb + (size_t)16 * DINNER + k0),
          (__attribute__((address_space(3))) void*)&Bs[16][0], 16, 0, 0);
    }
    __syncthreads();
    bf16x8v af[2], bv[2];
#pragma unroll
    for (int i = 0; i < 2; i++)
      af[i] = *(const bf16x8v*)&As[w * 32 + i * 16 + (lane & 15)][(lane >> 4) * 8];
#pragma unroll
    for (int j = 0; j < 2; j++)
      bv[j] = *(const bf16x8v*)&Bs[j * 16 + (lane & 15)][(lane >> 4) * 8];
#pragma unroll
    for (int i = 0; i < 2; i++)
#pragma unroll
      for (int j = 0; j < 2; j++)
        acc[i][j] = __builtin_amdgcn_mfma_f32_16x16x32_bf16(af[i], bv[j], acc[i][j], 0, 0, 0);
    __syncthreads();
  }
  int quad = lane >> 4;
  int cn = lane & 15;
  float* outp = fdp + (size_t)ks * (L_SEQ * NHEADS);
#pragma unroll
  for (int i = 0; i < 2; i++)
#pragma unroll
    for (int j = 0; j < 2; j++)
#pragma unroll
      for (int r = 0; r < 4; r++) {
        int row = bm + w * 32 + i * 16 + quad * 4 + r;
        int col = j * 16 + cn;
        outp[(size_t)row * NHEADS + col] = acc[i][j][r];
      }
}

__global__ __launch_bounds__(256) void fc_reduce(
    const float* __restrict__ fdp, const float* __restrict__ Dp,
    float* __restrict__ fd) {
  int i = blockIdx.x * 256 + threadIdx.x;   // L_SEQ*NHEADS
  float s = Dp[i & (NHEADS - 1)];
#pragma unroll
  for (int ks = 0; ks < FC_KS; ks++) s += fdp[(size_t)ks * (L_SEQ * NHEADS) + i];
  fd[i] = s;
}

// ---------------- conv (4 t/thread) + SiLU, with dt softplus folded in ----------------
#define CONV_BLOCKS ((L_SEQ / 4) * CONVDIM / 256)   // 10240
__global__ __launch_bounds__(256) void conv_dt_kernel(
    const bf16* __restrict__ zx, const float* __restrict__ conv_w,
    const float* __restrict__ conv_b, bf16* __restrict__ xbc,
    const float* __restrict__ dt_bias, float* __restrict__ dt2) {
  int bid = blockIdx.x;
  if (bid < CONV_BLOCKS) {
    int idx = bid * 256 + threadIdx.x;
    int ch = idx % CONVDIM;
    int t0 = (idx / CONVDIM) * 4;
    const bf16* col = zx + DINNER + ch;
    float w0 = conv_w[ch * 4 + 0], w1 = conv_w[ch * 4 + 1];
    float w2 = conv_w[ch * 4 + 2], w3 = conv_w[ch * 4 + 3];
    float bsv = conv_b[ch];
    float x[7];
#pragma unroll
    for (int i = 0; i < 7; i++) {
      int t = t0 - 3 + i;
      x[i] = (t >= 0) ? b2f(col[(size_t)t * DPROJ]) : 0.f;
    }
#pragma unroll
    for (int j = 0; j < 4; j++) {
      float acc = bsv + w0 * x[j] + w1 * x[j + 1] + w2 * x[j + 2] + w3 * x[j + 3];
      xbc[(size_t)(t0 + j) * CONVDIM + ch] = f2b(acc / (1.f + __expf(-acc)));
    }
  } else {
    int idx = (bid - CONV_BLOCKS) * 256 + threadIdx.x;   // 2*L_SEQ*NHEADS
    int h = idx % NHEADS;
    int t = (idx / NHEADS) % L_SEQ;
    int b = idx / (NHEADS * L_SEQ);
    float v;
    if (b == 0) v = b2f(zx[(size_t)t * DPROJ + 4608 + h]);
    else        v = b2f(zx[(size_t)(L_SEQ - 1 - t) * DPROJ + 4608 + NHEADS + h]);
    v += dt_bias[h];
    dt2[idx] = (v > 20.f) ? v : log1pf(expf(v));
  }
}

// ---------------- G[b,c,l,s] = sum_n C[l,n]*B[s,n]  (MFMA, quarter-split) ----------------
__global__ __launch_bounds__(256) void gmat_kernel(
    const bf16* __restrict__ xbc, bf16* __restrict__ G) {
  __shared__ bf16 Cs[32][136];   // C[l0+l][n]  8.5 KB
  __shared__ bf16 Bs[128][136];  // B[s][n]     34 KB
  int blk = blockIdx.x;          // (b*32+c)*4 + quarter
  int quarter = blk & 3;
  int bc = blk >> 2;
  int b = bc / NCHUNK, c = bc % NCHUNK;
  int l0 = quarter * 32;
  int tid = threadIdx.x;
  int lane = tid & 63;
  int w = tid >> 6;
  int bofs = b ? 2304 : 2048;
  int cofs = b ? 2432 : 2176;
  for (int o = tid; o < CHUNKL * DSTATE / 8; o += 256) {   // 2048 vecs
    int s = o >> 4;
    int n8 = (o & 15) * 8;
    int t = b ? (L_SEQ - 1 - (c * CHUNKL + s)) : (c * CHUNKL + s);
    *(bf16x8v*)&Bs[s][n8] = *(const bf16x8v*)&xbc[(size_t)t * CONVDIM + bofs + n8];
  }
  for (int o = tid; o < 32 * DSTATE / 8; o += 256) {       // 512 vecs
    int l = o >> 4;
    int n8 = (o & 15) * 8;
    int t = b ? (L_SEQ - 1 - (c * CHUNKL + l0 + l)) : (c * CHUNKL + l0 + l);
    *(bf16x8v*)&Cs[l][n8] = *(const bf16x8v*)&xbc[(size_t)t * CONVDIM + cofs + n8];
  }
  __syncthreads();
  if (w > quarter) return;   // s-tiles 2w,2w+1 start at s=32w > l0+31: masked at use
  f32x4v acc[2][2];
#pragma unroll
  for (int i = 0; i < 2; i++)
#pragma unroll
    for (int j = 0; j < 2; j++) acc[i][j] = (f32x4v){0.f, 0.f, 0.f, 0.f};
#pragma unroll
  for (int k0 = 0; k0 < 128; k0 += 32) {
    bf16x8v a0 = *(const bf16x8v*)&Cs[(lane & 15)][(lane >> 4) * 8 + k0];
    bf16x8v a1 = *(const bf16x8v*)&Cs[16 + (lane & 15)][(lane >> 4) * 8 + k0];
#pragma unroll
    for (int j = 0; j < 2; j++) {
      bf16x8v bv = *(const bf16x8v*)&Bs[(2 * w + j) * 16 + (lane & 15)][(lane >> 4) * 8 + k0];
      acc[0][j] = __builtin_amdgcn_mfma_f32_16x16x32_bf16(a0, bv, acc[0][j], 0, 0, 0);
      acc[1][j] = __builtin_amdgcn_mfma_f32_16x16x32_bf16(a1, bv, acc[1][j], 0, 0, 0);
    }
  }
  int quad = lane >> 4, cn = lane & 15;
  bf16* Gb = G + (size_t)bc * CHUNKL * CHUNKL;
#pragma unroll
  for (int i = 0; i < 2; i++)
#pragma unroll
    for (int j = 0; j < 2; j++)
#pragma unroll
      for (int r = 0; r < 4; r++) {
        int l = l0 + i * 16 + quad * 4 + r;
        int s = (2 * w + j) * 16 + cn;
        Gb[l * CHUNKL + s] = f2b(acc[i][j][r]);
      }
}

// ---------------- per-(b,c,h): chunk states only (MFMA, bf16 out) ----------------
__global__ __launch_bounds__(256) void chunk_kernel(
    const bf16* __restrict__ xbc, const float* __restrict__ dt2,
    const float* __restrict__ A_log,
    bf16* __restrict__ states, float* __restrict__ csum) {
  int gid = blockIdx.x;           // (b*32+c)*32 + h
  int h = gid % NHEADS;
  int bc = gid / NHEADS;
  int c = bc % NCHUNK, b = bc / NCHUNK;
  int tid = threadIdx.x;
  int lane = tid & 63;
  int w = tid >> 6;
  __shared__ bf16 BdT[128][136];  // [n][l] = B[l][n]*decay[l]  34 KB
  __shared__ bf16 xdtT[64][136];  // [p][s] = x[s,p]*dt[s]      17 KB
  __shared__ float acs[CHUNKL];
  __shared__ float dtl[CHUNKL];
  __shared__ float decays[CHUNKL];
  if (tid < CHUNKL)
    dtl[tid] = dt2[((size_t)b * L_SEQ + c * CHUNKL + tid) * NHEADS + h];
  __syncthreads();
  if (tid == 0) {
    float Ah = -__expf(A_log[h]);
    float s = 0.f;
    for (int l = 0; l < CHUNKL; l++) { s += Ah * dtl[l]; acs[l] = s; }
    csum[gid] = __expf(s);        // stored pre-exponentiated for scan
  }
  __syncthreads();
  if (tid < CHUNKL) decays[tid] = __expf(acs[CHUNKL - 1] - acs[tid]);
  // xdtT[p][s] staging: lane->s (t-strided 16B loads), conflict-free scatter
  for (int o = tid; o < CHUNKL * HEADDIM / 8; o += 256) {   // 1024 vecs
    int s = o & 127;
    int p8 = (o >> 7) * 8;
    int t = b ? (L_SEQ - 1 - (c * CHUNKL + s)) : (c * CHUNKL + s);
    bf16x8v xv = *(const bf16x8v*)&xbc[(size_t)t * CONVDIM + h * HEADDIM + p8];
    float d = dtl[s];
#pragma unroll
    for (int j = 0; j < 8; j++) xdtT[p8 + j][s] = f2b(sh2f(xv[j]) * d);
  }
  __syncthreads();   // decays ready
  // BdT[n][l] staging: lane->l, conflict-free scatter
  for (int o = tid; o < CHUNKL * CHUNKL / 8; o += 256) {    // 2048 vecs
    int l = o & 127;
    int n8 = (o >> 7) * 8;
    int t = b ? (L_SEQ - 1 - (c * CHUNKL + l)) : (c * CHUNKL + l);
    bf16x8v bv = *(const bf16x8v*)&xbc[(size_t)t * CONVDIM + (b ? 2304 : 2048) + n8];
    float d = decays[l];
#pragma unroll
    for (int j = 0; j < 8; j++) BdT[n8 + j][l] = f2b(sh2f(bv[j]) * d);
  }
  __syncthreads();
  // states[p][n] = sum_l xdtT[p][l]*BdT[n][l]; wave w -> p rows [16w,16w+16)
  f32x4v accS[8];
#pragma unroll
  for (int j = 0; j < 8; j++) accS[j] = (f32x4v){0.f, 0.f, 0.f, 0.f};
#pragma unroll
  for (int k0 = 0; k0 < 128; k0 += 32) {
    bf16x8v av = *(const bf16x8v*)&xdtT[w * 16 + (lane & 15)][(lane >> 4) * 8 + k0];
#pragma unroll
    for (int j = 0; j < 8; j++) {
      bf16x8v bv = *(const bf16x8v*)&BdT[j * 16 + (lane & 15)][(lane >> 4) * 8 + k0];
      accS[j] = __builtin_amdgcn_mfma_f32_16x16x32_bf16(av, bv, accS[j], 0, 0, 0);
    }
  }
  int quad = lane >> 4, cn = lane & 15;
  bf16* st = states + (size_t)gid * (HEADDIM * DSTATE);
#pragma unroll
  for (int j = 0; j < 8; j++)
#pragma unroll
    for (int r = 0; r < 4; r++) {
      int p = w * 16 + quad * 4 + r;
      int n = j * 16 + cn;
      st[p * DSTATE + n] = f2b(accS[j][r]);
    }
}

// ---------------- inter-chunk scan: register-batched (independent loads first) --------
__global__ __launch_bounds__(256) void scan_kernel(
    bf16* __restrict__ states, const float* __restrict__ csum) {
  int idx = blockIdx.x * 256 + threadIdx.x;  // 2*NHEADS*HEADDIM*DSTATE
  int n = idx % DSTATE;
  int p = (idx / DSTATE) % HEADDIM;
  int h = (idx / (DSTATE * HEADDIM)) % NHEADS;
  int b = idx / (DSTATE * HEADDIM * NHEADS);
  size_t base = ((size_t)(b * NCHUNK) * NHEADS + h) * (HEADDIM * DSTATE) + p * DSTATE + n;
  const size_t cstride = (size_t)NHEADS * HEADDIM * DSTATE;
  float tmp[NCHUNK], cv[NCHUNK];
#pragma unroll
  for (int c = 0; c < NCHUNK; c++) tmp[c] = b2f(states[base + c * cstride]);
#pragma unroll
  for (int c = 0; c < NCHUNK; c++) cv[c] = csum[(b * NCHUNK + c) * NHEADS + h];
  float S = 0.f;
#pragma unroll
  for (int c = 0; c < NCHUNK; c++) {
    states[base + c * cstride] = f2b(S);
    S = cv[c] * S + tmp[c];
  }
}

// ---------------- fused Y = Y_diag + Y_off + D*x (MFMA, single bf16 write) ----------------
// R8: R6 tiling + wave-parallel shfl_up scan + upper-tri skips + T14 reg-preload
// of Ce/St (global latency hidden under GEMM1).
__global__ __launch_bounds__(256) void yoff_kernel(
    const bf16* __restrict__ xbc, const float* __restrict__ dt2,
    const float* __restrict__ A_log, const bf16* __restrict__ G,
    const bf16* __restrict__ states, const float* __restrict__ Dp,
    bf16* __restrict__ Y) {
  int gid = blockIdx.x;
  int h = gid % NHEADS;
  int bc = gid / NHEADS;
  int c = bc % NCHUNK, b = bc / NCHUNK;
  int tid = threadIdx.x;
  int lane = tid & 63;
  int w = tid >> 6;
  __shared__ bf16 WB[128][136];   // 34 KB (W, then Ce)
  __shared__ bf16 SX[64][136];    // 17 KB (xdtT, then St)
  __shared__ float acs[CHUNKL];
  __shared__ float dtl[CHUNKL];
  __shared__ float eAl[CHUNKL];
  if (tid < CHUNKL)
    dtl[tid] = dt2[((size_t)b * L_SEQ + c * CHUNKL + tid) * NHEADS + h];
  __syncthreads();
  // wave-parallel inclusive scan of Ah*dtl (128 elems, 2/lane, wave 0 only)
  if (tid < 64) {
    float Ah = -__expf(A_log[h]);
    float v0 = Ah * dtl[2 * tid];
    float v1 = Ah * dtl[2 * tid + 1];
    float s = v0 + v1;
#pragma unroll
    for (int off = 1; off < 64; off <<= 1) {
      float t = __shfl_up(s, off);
      if (tid >= off) s += t;
    }
    acs[2 * tid]     = s - v1;
    acs[2 * tid + 1] = s;
  }
  __syncthreads();
  if (tid < CHUNKL) eAl[tid] = __expf(acs[tid]);   // <= 1
  // T14: issue Ce + St global loads NOW; values consumed only after GEMM1.
  bf16x8v ce_r[8], st_r[4];
  {
    int cofs = b ? 2432 : 2176;
#pragma unroll
    for (int it = 0; it < 8; it++) {
      int o = tid + it * 256;
      int l = o >> 4;
      int n8 = (o & 15) * 8;
      int t = b ? (L_SEQ - 1 - (c * CHUNKL + l)) : (c * CHUNKL + l);
      ce_r[it] = *(const bf16x8v*)&xbc[(size_t)t * CONVDIM + cofs + n8];
    }
    const bf16* stp = states + (size_t)gid * (HEADDIM * DSTATE);
#pragma unroll
    for (int it = 0; it < 4; it++) {
      int o = tid + it * 256;
      st_r[it] = *(const bf16x8v*)&stp[o * 8];
    }
  }
  // SX <- xdtT[p][s]: lane->s, conflict-free scatter
  for (int o = tid; o < CHUNKL * HEADDIM / 8; o += 256) {   // 1024 vecs
    int s = o & 127;
    int p8 = (o >> 7) * 8;
    int t = b ? (L_SEQ - 1 - (c * CHUNKL + s)) : (c * CHUNKL + s);
    bf16x8v xv = *(const bf16x8v*)&xbc[(size_t)t * CONVDIM + h * HEADDIM + p8];
    float d = dtl[s];
#pragma unroll
    for (int j = 0; j < 8; j++) SX[p8 + j][s] = f2b(sh2f(xv[j]) * d);
  }
  // WB <- W[l][s] = G*exp(acs[l]-acs[s]) (s<=l): b128 writes; upper-tri vecs
  // (s8 > l) skip the G load and expf entirely.
  {
    const bf16* Gb = G + (size_t)bc * CHUNKL * CHUNKL;
    for (int o = tid; o < CHUNKL * CHUNKL / 8; o += 256) {  // 2048 vecs
      int l = o >> 4;
      int s8 = (o & 15) * 8;
      bf16x8v wv;
      if (s8 > l) {
#pragma unroll
        for (int j = 0; j < 8; j++) wv[j] = 0;
      } else {
        bf16x8v g = *(const bf16x8v*)&Gb[l * CHUNKL + s8];
        float al = acs[l];
#pragma unroll
        for (int j = 0; j < 8; j++) {
          int s = s8 + j;
          float e = (s <= l) ? sh2f(g[j]) * __expf(al - acs[s]) : 0.f;
          wv[j] = f2bs(e);
        }
      }
      *(bf16x8v*)&WB[l][s8] = wv;
    }
  }
  __syncthreads();
  f32x4v accY[2][4];
#pragma unroll
  for (int i = 0; i < 2; i++)
#pragma unroll
    for (int j = 0; j < 4; j++) accY[i][j] = (f32x4v){0.f, 0.f, 0.f, 0.f};
  // Y_diag: A=W rows [32w,32w+32), B=xdtT p-tiles, k=s.
  // Wave-uniform skip: k0 > 32w+31 => A block all-zero (strict upper triangle).
#pragma unroll
  for (int k0 = 0; k0 < 128; k0 += 32) {
    if (k0 > w * 32 + 31) break;
    bf16x8v a0 = *(const bf16x8v*)&WB[w * 32 + (lane & 15)][(lane >> 4) * 8 + k0];
    bf16x8v a1 = *(const bf16x8v*)&WB[w * 32 + 16 + (lane & 15)][(lane >> 4) * 8 + k0];
#pragma unroll
    for (int j = 0; j < 4; j++) {
      bf16x8v bv = *(const bf16x8v*)&SX[j * 16 + (lane & 15)][(lane >> 4) * 8 + k0];
      accY[0][j] = __builtin_amdgcn_mfma_f32_16x16x32_bf16(a0, bv, accY[0][j], 0, 0, 0);
      accY[1][j] = __builtin_amdgcn_mfma_f32_16x16x32_bf16(a1, bv, accY[1][j], 0, 0, 0);
    }
  }
  __syncthreads();   // all phase-1 LDS reads done
  // restage from REGISTERS (global latency already hidden under GEMM1):
  // WB <- Ce*eAl, SX <- St
  {
#pragma unroll
    for (int it = 0; it < 8; it++) {
      int o = tid + it * 256;
      int l = o >> 4;
      int n8 = (o & 15) * 8;
      float e = eAl[l];
      bf16x8v ov;
#pragma unroll
      for (int j = 0; j < 8; j++) ov[j] = f2bs(sh2f(ce_r[it][j]) * e);
      *(bf16x8v*)&WB[l][n8] = ov;
    }
#pragma unroll
    for (int it = 0; it < 4; it++) {
      int o = tid + it * 256;
      int p = o >> 4;
      int n8 = (o & 15) * 8;
      *(bf16x8v*)&SX[p][n8] = st_r[it];
    }
  }
  __syncthreads();
  // Y_off: A=Ce rows, B=St p-tiles, k=n; accumulate into same accY
#pragma unroll
  for (int k0 = 0; k0 < 128; k0 += 32) {
    bf16x8v a0 = *(const bf16x8v*)&WB[w * 32 + (lane & 15)][(lane >> 4) * 8 + k0];
    bf16x8v a1 = *(const bf16x8v*)&WB[w * 32 + 16 + (lane & 15)][(lane >> 4) * 8 + k0];
#pragma unroll
    for (int j = 0; j < 4; j++) {
      bf16x8v bv = *(const bf16x8v*)&SX[j * 16 + (lane & 15)][(lane >> 4) * 8 + k0];
      accY[0][j] = __builtin_amdgcn_mfma_f32_16x16x32_bf16(a0, bv, accY[0][j], 0, 0, 0);
      accY[1][j] = __builtin_amdgcn_mfma_f32_16x16x32_bf16(a1, bv, accY[1][j], 0, 0, 0);
    }
  }
  int quad = lane >> 4, cn = lane & 15;
  float Dh = Dp[h];
#pragma unroll
  for (int i = 0; i < 2; i++)
#pragma unroll
    for (int j = 0; j < 4; j++)
#pragma unroll
      for (int r = 0; r < 4; r++) {
        int l = w * 32 + i * 16 + quad * 4 + r;
        int p = j * 16 + cn;
        int t = b ? (L_SEQ - 1 - (c * CHUNKL + l)) : (c * CHUNKL + l);
        float xv = b2f(xbc[(size_t)t * CONVDIM + h * HEADDIM + p]);
        size_t yi = ((size_t)b * L_SEQ + c * CHUNKL + l) * DINNER + h * HEADDIM + p;
        Y[yi] = f2b(accY[i][j][r] + xv * Dh);
      }
}

// ---------------- combine: shift, flip, +x*fd, gate, RMSNorm (vectorized) ----------------
__global__ __launch_bounds__(256) void combine_kernel(
    const bf16* __restrict__ Y, const bf16* __restrict__ xbc,
    const bf16* __restrict__ zx, const float* __restrict__ fd,
    const float* __restrict__ norm_w, bf16* __restrict__ yn) {
  int t = blockIdx.x;
  int tid = threadIdx.x;
  int j8 = tid * 8;
  float yf[8], yb[8];
#pragma unroll
  for (int j = 0; j < 8; j++) { yf[j] = 0.f; yb[j] = 0.f; }
  if (t >= 1) {
    bf16x8v v = *(const bf16x8v*)&Y[(size_t)(t - 1) * DINNER + j8];
#pragma unroll
    for (int j = 0; j < 8; j++) yf[j] = sh2f(v[j]);
  }
  if (t <= L_SEQ - 2) {
    bf16x8v v = *(const bf16x8v*)&Y[((size_t)L_SEQ + (L_SEQ - 2 - t)) * DINNER + j8];
#pragma unroll
    for (int j = 0; j < 8; j++) yb[j] = sh2f(v[j]);
  }
  bf16x8v xogv = *(const bf16x8v*)&xbc[(size_t)t * CONVDIM + j8];
  bf16x8v zv = *(const bf16x8v*)&zx[(size_t)t * DPROJ + j8];
  float fdv = fd[t * NHEADS + (j8 >> 6)];
  float yg[8];
  float ss = 0.f;
#pragma unroll
  for (int j = 0; j < 8; j++) {
    float y = yf[j] + yb[j] + sh2f(xogv[j]) * fdv;
    float z = sh2f(zv[j]);
    float g = y * (z / (1.f + __expf(-z)));
    yg[j] = g;
    ss += g * g;
  }
#pragma unroll
  for (int off = 32; off > 0; off >>= 1) ss += __shfl_down(ss, off);
  __shared__ float red[4];
  if ((tid & 63) == 0) red[tid >> 6] = ss;
  __syncthreads();
  float tot = red[0] + red[1] + red[2] + red[3];
  float scale = rsqrtf(tot / (float)DINNER + 1e-5f);
  float4 nw0 = *(const float4*)&norm_w[j8];
  float4 nw1 = *(const float4*)&norm_w[j8 + 4];
  bf16x8v ov;
  ov[0] = f2bs(yg[0] * scale * nw0.x);
  ov[1] = f2bs(yg[1] * scale * nw0.y);
  ov[2] = f2bs(yg[2] * scale * nw0.z);
  ov[3] = f2bs(yg[3] * scale * nw0.w);
  ov[4] = f2bs(yg[4] * scale * nw1.x);
  ov[5] = f2bs(yg[5] * scale * nw1.y);
  ov[6] = f2bs(yg[6] * scale * nw1.z);
  ov[7] = f2bs(yg[7] * scale * nw1.w);
  *(bf16x8v*)&yn[(size_t)t * DINNER + j8] = ov;
}

// ---------------- launch ----------------
extern "C" void kernel_launch(void* const* d_in, const int* in_sizes, int n_in,
                              void* d_out, int out_size, void* d_ws, size_t ws_size,
                              hipStream_t stream) {
  const float* u         = (const float*)d_in[0];
  const float* in_proj_w = (const float*)d_in[1];
  const float* conv_w    = (const float*)d_in[2];
  const float* conv_b    = (const float*)d_in[3];
  const float* dt_bias   = (const float*)d_in[4];
  const float* A_log     = (const float*)d_in[5];
  const float* Dp        = (const float*)d_in[6];
  const float* fc_D_w    = (const float*)d_in[7];
  const float* norm_w    = (const float*)d_in[8];
  const float* out_proj_w= (const float*)d_in[9];
  float* out = (float*)d_out;

  char* base = (char*)d_ws;
  bf16*  zx  = (bf16*)base;  base += (size_t)L_SEQ * DPROJ * 2;                    // 38.3 MB
  bf16*  xbc = (bf16*)base;  base += (size_t)L_SEQ * CONVDIM * 2;                  // 21.0 MB
  float* dt2 = (float*)base; base += (size_t)2 * L_SEQ * NHEADS * 4;               //  1.0 MB
  bf16*  G   = (bf16*)base;  base += (size_t)2 * NCHUNK * CHUNKL * CHUNKL * 4;     //  4.2 MB region
  bf16*  Yb  = (bf16*)base;  base += (size_t)2 * L_SEQ * DINNER * 4;               // 67.1 MB region
  bf16*  stb = (bf16*)base;  base += (size_t)2 * NCHUNK * NHEADS * HEADDIM * DSTATE * 4; // 67.1 MB region
  float* cs  = (float*)base; base += (size_t)2 * NCHUNK * NHEADS * 4;              //  8 KB
  // aliases into dead regions:
  bf16*  u_bf   = (bf16*)Yb;                          // 8.4 MB   (Yb live only after yoff)
  bf16*  w1p_bf = (bf16*)((char*)Yb + 9437184);       // 9.7 MB   (in_proj_w padded to 4736 rows)
  bf16*  w2_bf  = (bf16*)G;                           // 4.2 MB   (G dead after yoff)
  bf16*  yn     = (bf16*)stb;                         // 16.8 MB  (stb dead after yoff)
  float* fd     = (float*)((char*)stb + 33554432);    //  0.5 MB  (32 MB offset)
  bf16*  wf_bf  = (bf16*)((char*)stb + 35651584);     //  128 KB  (34 MB offset)
  float* fdp    = (float*)((char*)stb + 37748736);    //  8 MB    (36 MB offset)
  float* p1     = (float*)Yb;                         // 16.8 MB  (Yb dead after combine)

  // 0. fused casts for MFMA gemm1 (w1 zero-padded to NPAD1 rows)
  cast2_kernel<<<(L_SEQ * DMODEL + NPAD1 * DMODEL) / 256, 256, 0, stream>>>(
      u, in_proj_w, u_bf, w1p_bf);
  // 1a. in_proj main: cols [0,4096) (8-phase 256^2, 256 blocks = exactly 1 round)
  gemm1_8ph<<<(L_SEQ / 256) * G1_GN, 512, 0, stream>>>(u_bf, w1p_bf, zx);
  // 1b. in_proj remainder: cols [4096,4672) (128^2 gemm, 160 blocks)
  gemm_mfma<bf16><<<(L_SEQ / 128) * ((NPAD1 - NSPLIT) / 128), 256, 0, stream>>>(
      u_bf, DMODEL, w1p_bf + (size_t)NSPLIT * DMODEL, DMODEL,
      zx + NSPLIT, DPROJ, DPROJ - NSPLIT, DMODEL,
      L_SEQ / 128, (NPAD1 - NSPLIT) / 128, 0);
  // 2. conv + silu + dt (fused)
  conv_dt_kernel<<<CONV_BLOCKS + (2 * L_SEQ * NHEADS) / 256, 256, 0, stream>>>(
      zx, conv_w, conv_b, xbc, dt_bias, dt2);
  // 3a. G = C B^T per (b,c), quarter-split (MFMA, bf16)
  gmat_kernel<<<2 * NCHUNK * 4, 256, 0, stream>>>(xbc, G);
  // 3b. chunk states (MFMA, bf16)
  chunk_kernel<<<2 * NCHUNK * NHEADS, 256, 0, stream>>>(
      xbc, dt2, A_log, stb, cs);
  // 3c. inter-chunk scan (register-batched)
  scan_kernel<<<(2 * NHEADS * HEADDIM * DSTATE) / 256, 256, 0, stream>>>(stb, cs);
  // 3d. fused Y = Y_diag + Y_off + D*x (MFMA; R6 tiling + T14 reg-preload)
  yoff_kernel<<<2 * NCHUNK * NHEADS, 256, 0, stream>>>(
      xbc, dt2, A_log, G, stb, Dp, Yb);
  // 4a. casts into dead regions: out_proj_w -> w2_bf (G), fc_D_w -> wf_bf (stb)
  cast_kernel<<<(DMODEL * DINNER + 255) / 256, 256, 0, stream>>>(
      out_proj_w, w2_bf, DMODEL * DINNER, DMODEL * DINNER);
  cast_kernel<<<(NHEADS * DINNER + 255) / 256, 256, 0, stream>>>(
      fc_D_w, wf_bf, NHEADS * DINNER, NHEADS * DINNER);
  // 4b. fd = x_og @ fc_D_w^T + D  (MFMA split-K=16: 512 blocks, then reduce)
  fc_mfma<<<(L_SEQ / 128) * FC_KS, 256, 0, stream>>>(xbc, wf_bf, fdp);
  fc_reduce<<<(L_SEQ * NHEADS) / 256, 256, 0, stream>>>(fdp, Dp, fd);
  // 5. combine + gate + RMSNorm
  combine_kernel<<<L_SEQ, 256, 0, stream>>>(Yb, xbc, zx, fd, norm_w, yn);
  // 6. out_proj split-K=2 (512 blocks = 2/CU) + add pass
  outproj_ks<<<512, 256, 0, stream>>>(yn, w2_bf, out, p1);
  add_kernel<<<(L_SEQ * DMODEL) / 1024, 256, 0, stream>>>(out, p1);
}

// Round 11
// 353.362 us; speedup vs baseline: 1.1466x; 1.0031x over previous
//
#include <hip/hip_runtime.h>
#include <hip/hip_bf16.h>
#include <math.h>

// ---------------- problem constants ----------------
#define L_SEQ   4096
#define DMODEL  1024
#define DINNER  2048
#define NHEADS  32
#define HEADDIM 64
#define DSTATE  128
#define NCHUNK  32
#define CHUNKL  128
#define CONVDIM 2560
#define DPROJ   4672   // 2*DINNER + 2*(2*DSTATE) + 2*NHEADS
#define NPAD1   4736   // DPROJ padded to multiple of 128 (for remainder gemm)
#define NSPLIT  4096   // cols [0,NSPLIT) via 8-phase 256^2 (256 blocks = 1 round);
                       // cols [NSPLIT,DPROJ) via 128^2 gemm (160 blocks)

typedef __hip_bfloat16 bf16;
__device__ __forceinline__ float b2f(bf16 x) { return __bfloat162float(x); }
__device__ __forceinline__ bf16 f2b(float x) { return __float2bfloat16(x); }
__device__ __forceinline__ float sh2f(short s) {
  return __uint_as_float(((unsigned int)(unsigned short)s) << 16);
}
__device__ __forceinline__ short f2bs(float x) {
  bf16 t = __float2bfloat16(x);
  return *reinterpret_cast<short*>(&t);
}

typedef __attribute__((ext_vector_type(8))) short bf16x8v;
typedef __attribute__((ext_vector_type(4))) float f32x4v;

// zxbcdt column layout: [0,2048) = z ; [2048,4608) = xBC ; [4608,4672) = dt raw
// xBC_conv channel layout: [0,2048) = x ; fw B = [2048,2176) C = [2176,2304)
//                          bw B = [2304,2432) C = [2432,2560)  (bw streams time-flipped)

// ---------------- fused casts: u -> bf16 and in_proj_w -> bf16 (zero-padded) ----------------
__global__ __launch_bounds__(256) void cast2_kernel(
    const float* __restrict__ u, const float* __restrict__ w1,
    bf16* __restrict__ u_bf, bf16* __restrict__ w1_bf) {
  const int NU = (L_SEQ * DMODEL) / 256;   // 16384 blocks
  int bid = blockIdx.x;
  if (bid < NU) {
    int i = bid * 256 + threadIdx.x;
    u_bf[i] = f2b(u[i]);
  } else {
    int i = (bid - NU) * 256 + threadIdx.x;
    w1_bf[i] = (i < DPROJ * DMODEL) ? f2b(w1[i]) : f2b(0.f);
  }
}

// ---------------- f32 -> bf16 cast ----------------
__global__ __launch_bounds__(256) void cast_kernel(
    const float* __restrict__ src, bf16* __restrict__ dst, int n_src, int n_tot) {
  int i = blockIdx.x * 256 + threadIdx.x;
  if (i < n_tot) dst[i] = (i < n_src) ? f2b(src[i]) : f2b(0.f);
}

// ================= in_proj main: 8-phase 256x256 GEMM (R1-verified body) =================
#define G1_K  1024
#define G1_GN 16            // N tiles of 256 covering [0,4096)
#define G1_NT (G1_K / 64)   // 16 K-tiles

__global__ __launch_bounds__(512, 2) void gemm1_8ph(
    const bf16* __restrict__ A, const bf16* __restrict__ B, bf16* __restrict__ C) {
  __shared__ bf16 Al[2][2][8192];   // [slot][half][subtiled 128x64]  64 KB
  __shared__ bf16 Bl[2][2][8192];   // 64 KB
  const int tid = threadIdx.x;
  const int lane = tid & 63;
  const int w = tid >> 6;        // 0..7
  const int wm = w >> 2;         // 0..1 -> C rows [wm*128, +128)
  const int wn = w & 3;          // 0..3 -> C cols [wn*64, +64)
  const int bm = (blockIdx.x / G1_GN) * 256;
  const int bn = (blockIdx.x % G1_GN) * 256;
  const int scol = ((lane & 3) ^ (((lane >> 5) & 1) << 1)) * 8;
  const int cin = ((lane >> 4) * 8) ^ (((lane >> 3) & 1) << 4);
  const int r16 = lane & 15;
  const bf16* Ag = A + (size_t)bm * G1_K;
  const bf16* Bg = B + (size_t)bn * G1_K;

  auto stage = [&](int mat, int tt, int hf) {
    const bf16* g = (mat ? Bg : Ag)
        + (size_t)(hf * 128 + (w >> 1) * 16 + (lane >> 2)) * G1_K
        + tt * 64 + (w & 1) * 32 + scol;
    bf16* d0 = mat ? &Bl[tt & 1][hf][0] : &Al[tt & 1][hf][0];
    __builtin_amdgcn_global_load_lds(
        (const __attribute__((address_space(1))) void*)g,
        (__attribute__((address_space(3))) void*)(d0 + w * 512), 16, 0, 0);
    __builtin_amdgcn_global_load_lds(
        (const __attribute__((address_space(1))) void*)(g + (size_t)64 * G1_K),
        (__attribute__((address_space(3))) void*)(d0 + (8 + w) * 512), 16, 0, 0);
  };

  f32x4v acc[8][4];
#pragma unroll
  for (int i = 0; i < 8; i++)
#pragma unroll
    for (int j = 0; j < 4; j++) acc[i][j] = (f32x4v){0.f, 0.f, 0.f, 0.f};

  stage(0, 0, 0); stage(0, 0, 1); stage(1, 0, 0); stage(1, 0, 1);
  stage(0, 1, 0); stage(0, 1, 1); stage(1, 1, 0);
  asm volatile("s_waitcnt vmcnt(6)" ::: "memory");
  __builtin_amdgcn_s_barrier();
  __builtin_amdgcn_sched_barrier(0);

#pragma unroll 2
  for (int t = 0; t < G1_NT; ++t) {
    const int slot = t & 1;
    const bf16* Ah = &Al[slot][wm][0];
    const bf16* Bh = &Bl[slot][wn >> 1][0];
    const int brb = (wn & 1) * 4;
    bf16x8v a[4][2], b[4][2];
    // ---- phase 0
#pragma unroll
    for (int i = 0; i < 4; i++) {
      a[i][0] = *(const bf16x8v*)&Ah[(i * 2 + 0) * 512 + r16 * 32 + cin];
      a[i][1] = *(const bf16x8v*)&Ah[(i * 2 + 1) * 512 + r16 * 32 + cin];
    }
#pragma unroll
    for (int j = 0; j < 2; j++) {
      b[j][0] = *(const bf16x8v*)&Bh[((brb + j) * 2 + 0) * 512 + r16 * 32 + cin];
      b[j][1] = *(const bf16x8v*)&Bh[((brb + j) * 2 + 1) * 512 + r16 * 32 + cin];
    }
    if (t + 1 < G1_NT) stage(1, t + 1, 1);
    __builtin_amdgcn_s_barrier();
    asm volatile("s_waitcnt lgkmcnt(0)" ::: "memory");
    __builtin_amdgcn_s_setprio(1);
#pragma unroll
    for (int i = 0; i < 4; i++)
#pragma unroll
      for (int j = 0; j < 2; j++) {
        acc[i][j] = __builtin_amdgcn_mfma_f32_16x16x32_bf16(a[i][0], b[j][0], acc[i][j], 0, 0, 0);
        acc[i][j] = __builtin_amdgcn_mfma_f32_16x16x32_bf16(a[i][1], b[j][1], acc[i][j], 0, 0, 0);
      }
    __builtin_amdgcn_s_setprio(0);
    __builtin_amdgcn_s_barrier();
    // ---- phase 1
#pragma unroll
    for (int j = 2; j < 4; j++) {
      b[j][0] = *(const bf16x8v*)&Bh[((brb + j) * 2 + 0) * 512 + r16 * 32 + cin];
      b[j][1] = *(const bf16x8v*)&Bh[((brb + j) * 2 + 1) * 512 + r16 * 32 + cin];
    }
    __builtin_amdgcn_s_barrier();
    asm volatile("s_waitcnt lgkmcnt(0)" ::: "memory");
    __builtin_amdgcn_s_setprio(1);
#pragma unroll
    for (int i = 0; i < 4; i++)
#pragma unroll
      for (int j = 2; j < 4; j++) {
        acc[i][j] = __builtin_amdgcn_mfma_f32_16x16x32_bf16(a[i][0], b[j][0], acc[i][j], 0, 0, 0);
        acc[i][j] = __builtin_amdgcn_mfma_f32_16x16x32_bf16(a[i][1], b[j][1], acc[i][j], 0, 0, 0);
      }
    __builtin_amdgcn_s_setprio(0);
    __builtin_amdgcn_s_barrier();
    // ---- phase 2
#pragma unroll
    for (int i = 0; i < 4; i++) {
      a[i][0] = *(const bf16x8v*)&Ah[((4 + i) * 2 + 0) * 512 + r16 * 32 + cin];
      a[i][1] = *(const bf16x8v*)&Ah[((4 + i) * 2 + 1) * 512 + r16 * 32 + cin];
    }
    if (t + 2 < G1_NT) stage(1, t + 2, 0);
    __builtin_amdgcn_s_barrier();
    asm volatile("s_waitcnt lgkmcnt(0)" ::: "memory");
    __builtin_amdgcn_s_setprio(1);
#pragma unroll
    for (int i = 0; i < 4; i++)
#pragma unroll
      for (int j = 2; j < 4; j++) {
        acc[4 + i][j] = __builtin_amdgcn_mfma_f32_16x16x32_bf16(a[i][0], b[j][0], acc[4 + i][j], 0, 0, 0);
        acc[4 + i][j] = __builtin_amdgcn_mfma_f32_16x16x32_bf16(a[i][1], b[j][1], acc[4 + i][j], 0, 0, 0);
      }
    __builtin_amdgcn_s_setprio(0);
    __builtin_amdgcn_s_barrier();
    // ---- phase 3
    if (t + 2 < G1_NT) { stage(0, t + 2, 0); stage(0, t + 2, 1); }
    __builtin_amdgcn_s_barrier();
    __builtin_amdgcn_s_setprio(1);
#pragma unroll
    for (int i = 0; i < 4; i++)
#pragma unroll
      for (int j = 0; j < 2; j++) {
        acc[4 + i][j] = __builtin_amdgcn_mfma_f32_16x16x32_bf16(a[i][0], b[j][0], acc[4 + i][j], 0, 0, 0);
        acc[4 + i][j] = __builtin_amdgcn_mfma_f32_16x16x32_bf16(a[i][1], b[j][1], acc[4 + i][j], 0, 0, 0);
      }
    __builtin_amdgcn_s_setprio(0);
    if (t < G1_NT - 2)       asm volatile("s_waitcnt vmcnt(6)" ::: "memory");
    else if (t == G1_NT - 2) asm volatile("s_waitcnt vmcnt(0)" ::: "memory");
    __builtin_amdgcn_s_barrier();
    __builtin_amdgcn_sched_barrier(0);
  }

  const int quad = lane >> 4;
  const int cn = lane & 15;
#pragma unroll
  for (int i = 0; i < 8; i++)
#pragma unroll
    for (int j = 0; j < 4; j++) {
      int col = bn + wn * 64 + j * 16 + cn;
      if (col < DPROJ) {
#pragma unroll
        for (int r = 0; r < 4; r++) {
          int row = bm + wm * 128 + i * 16 + quad * 4 + r;
          C[(size_t)row * DPROJ + col] = f2b(acc[i][j][r]);
        }
      }
    }
}

// ---------------- MFMA GEMM: C[m,n] = sum_k A[m,k]*B[n,k], bf16 in, f32 acc ----------------
// (used for the in_proj N-remainder)
template <typename TC>
__global__ __launch_bounds__(256) void gemm_mfma(
    const bf16* __restrict__ A, int lda,
    const bf16* __restrict__ B, int ldb,
    TC* __restrict__ C, int ldc,
    int N, int K, int gridM, int gridN, int swz) {
  __shared__ short As[128][32];
  __shared__ short Bs[128][32];
  int tid = threadIdx.x;
  int lane = tid & 63;
  int w = tid >> 6;            // wave 0..3
  int wr = w >> 1, wc = w & 1; // 2x2 wave grid
  int bid = blockIdx.x;
  int bm, bn;
  if (swz) {
    int mst = gridM >> 3;
    int xk = bid & 7, q = bid >> 3;
    bm = (xk + 8 * (q % mst)) * 128;
    bn = (q / mst) * 128;
  } else {
    bm = (bid / gridN) * 128;
    bn = (bid % gridN) * 128;
  }
  f32x4v acc[4][4];
#pragma unroll
  for (int i = 0; i < 4; i++)
#pragma unroll
    for (int j = 0; j < 4; j++) acc[i][j] = (f32x4v){0.f, 0.f, 0.f, 0.f};

  const bf16* Ab = A + (size_t)(bm + w * 32 + (lane >> 2)) * lda + (lane & 3) * 8;
  const bf16* Bb = B + (size_t)(bn + w * 32 + (lane >> 2)) * ldb + (lane & 3) * 8;

  for (int k0 = 0; k0 < K; k0 += 32) {
    __builtin_amdgcn_global_load_lds(
        (const __attribute__((address_space(1))) void*)(Ab + k0),
        (__attribute__((address_space(3))) void*)&As[w * 32][0], 16, 0, 0);
    __builtin_amdgcn_global_load_lds(
        (const __attribute__((address_space(1))) void*)(Ab + (size_t)16 * lda + k0),
        (__attribute__((address_space(3))) void*)&As[w * 32 + 16][0], 16, 0, 0);
    __builtin_amdgcn_global_load_lds(
        (const __attribute__((address_space(1))) void*)(Bb + k0),
        (__attribute__((address_space(3))) void*)&Bs[w * 32][0], 16, 0, 0);
    __builtin_amdgcn_global_load_lds(
        (const __attribute__((address_space(1))) void*)(Bb + (size_t)16 * ldb + k0),
        (__attribute__((address_space(3))) void*)&Bs[w * 32 + 16][0], 16, 0, 0);
    __syncthreads();
    bf16x8v af[4], bv[4];
#pragma unroll
    for (int i = 0; i < 4; i++)
      af[i] = *(const bf16x8v*)&As[wr * 64 + i * 16 + (lane & 15)][(lane >> 4) * 8];
#pragma unroll
    for (int j = 0; j < 4; j++)
      bv[j] = *(const bf16x8v*)&Bs[wc * 64 + j * 16 + (lane & 15)][(lane >> 4) * 8];
#pragma unroll
    for (int i = 0; i < 4; i++)
#pragma unroll
      for (int j = 0; j < 4; j++)
        acc[i][j] = __builtin_amdgcn_mfma_f32_16x16x32_bf16(af[i], bv[j], acc[i][j], 0, 0, 0);
    __syncthreads();
  }
  int quad = lane >> 4;
  int cn = lane & 15;
#pragma unroll
  for (int i = 0; i < 4; i++) {
#pragma unroll
    for (int j = 0; j < 4; j++) {
      int col = bn + wc * 64 + j * 16 + cn;
      if (col < N) {
#pragma unroll
        for (int r = 0; r < 4; r++) {
          int row = bm + wr * 64 + i * 16 + quad * 4 + r;
          float v = acc[i][j][r];
          if constexpr (sizeof(TC) == 2) C[(size_t)row * ldc + col] = f2b(v);
          else                           C[(size_t)row * ldc + col] = v;
        }
      }
    }
  }
}

// ---------------- out_proj split-K=2: 512 blocks (2/CU, 2 waves/SIMD) ----------------
__global__ __launch_bounds__(256) void outproj_ks(
    const bf16* __restrict__ A, const bf16* __restrict__ B,
    float* __restrict__ C0, float* __restrict__ C1) {
  __shared__ short As[128][32];
  __shared__ short Bs[128][32];
  int tid = threadIdx.x;
  int lane = tid & 63;
  int w = tid >> 6;
  int wr = w >> 1, wc = w & 1;
  int bid = blockIdx.x;
  int ks = bid >> 8;            // 0/1 K-half
  int q = bid & 255;
  int xk = q & 7, qq = q >> 3;
  int bm = (xk + 8 * (qq & 3)) * 128;   // 32 m-tiles
  int bn = (qq >> 2) * 128;             // 8 n-tiles
  float* C = ks ? C1 : C0;
  f32x4v acc[4][4];
#pragma unroll
  for (int i = 0; i < 4; i++)
#pragma unroll
    for (int j = 0; j < 4; j++) acc[i][j] = (f32x4v){0.f, 0.f, 0.f, 0.f};

  const bf16* Ab = A + (size_t)(bm + w * 32 + (lane >> 2)) * DINNER + ks * 1024 + (lane & 3) * 8;
  const bf16* Bb = B + (size_t)(bn + w * 32 + (lane >> 2)) * DINNER + ks * 1024 + (lane & 3) * 8;

  for (int k0 = 0; k0 < 1024; k0 += 32) {
    __builtin_amdgcn_global_load_lds(
        (const __attribute__((address_space(1))) void*)(Ab + k0),
        (__attribute__((address_space(3))) void*)&As[w * 32][0], 16, 0, 0);
    __builtin_amdgcn_global_load_lds(
        (const __attribute__((address_space(1))) void*)(Ab + (size_t)16 * DINNER + k0),
        (__attribute__((address_space(3))) void*)&As[w * 32 + 16][0], 16, 0, 0);
    __builtin_amdgcn_global_load_lds(
        (const __attribute__((address_space(1))) void*)(Bb + k0),
        (__attribute__((address_space(3))) void*)&Bs[w * 32][0], 16, 0, 0);
    __builtin_amdgcn_global_load_lds(
        (const __attribute__((address_space(1))) void*)(Bb + (size_t)16 * DINNER + k0),
        (__attribute__((address_space(3))) void*)&Bs[w * 32 + 16][0], 16, 0, 0);
    __syncthreads();
    bf16x8v af[4], bv[4];
#pragma unroll
    for (int i = 0; i < 4; i++)
      af[i] = *(const bf16x8v*)&As[wr * 64 + i * 16 + (lane & 15)][(lane >> 4) * 8];
#pragma unroll
    for (int j = 0; j < 4; j++)
      bv[j] = *(const bf16x8v*)&Bs[wc * 64 + j * 16 + (lane & 15)][(lane >> 4) * 8];
#pragma unroll
    for (int i = 0; i < 4; i++)
#pragma unroll
      for (int j = 0; j < 4; j++)
        acc[i][j] = __builtin_amdgcn_mfma_f32_16x16x32_bf16(af[i], bv[j], acc[i][j], 0, 0, 0);
    __syncthreads();
  }
  int quad = lane >> 4;
  int cn = lane & 15;
#pragma unroll
  for (int i = 0; i < 4; i++)
#pragma unroll
    for (int j = 0; j < 4; j++) {
      int col = bn + wc * 64 + j * 16 + cn;
#pragma unroll
      for (int r = 0; r < 4; r++) {
        int row = bm + wr * 64 + i * 16 + quad * 4 + r;
        C[(size_t)row * DMODEL + col] = acc[i][j][r];
      }
    }
}

// ---------------- out += P1 (vectorized) ----------------
__global__ __launch_bounds__(256) void add_kernel(
    float* __restrict__ out, const float* __restrict__ P) {
  int i = (blockIdx.x * 256 + threadIdx.x) * 4;
  float4 a = *(const float4*)&out[i];
  float4 b = *(const float4*)&P[i];
  a.x += b.x; a.y += b.y; a.z += b.z; a.w += b.w;
  *(float4*)&out[i] = a;
}

// ---------------- fc via MFMA split-K=16 ----------------
#define FC_KS 16
__global__ __launch_bounds__(256) void fc_mfma(
    const bf16* __restrict__ xbc, const bf16* __restrict__ Wb,
    float* __restrict__ fdp) {
  __shared__ short As[128][32];
  __shared__ short Bs[32][32];
  int tid = threadIdx.x;
  int lane = tid & 63;
  int w = tid >> 6;
  int bid = blockIdx.x;
  int ks = bid & (FC_KS - 1);
  int bm = (bid / FC_KS) * 128;
  f32x4v acc[2][2];
#pragma unroll
  for (int i = 0; i < 2; i++)
#pragma unroll
    for (int j = 0; j < 2; j++) acc[i][j] = (f32x4v){0.f, 0.f, 0.f, 0.f};

  const bf16* Ab = xbc + (size_t)(bm + w * 32 + (lane >> 2)) * CONVDIM + ks * 128 + (lane & 3) * 8;
  const bf16* Bb = Wb + (size_t)(lane >> 2) * DINNER + ks * 128 + (lane & 3) * 8;

  for (int k0 = 0; k0 < 128; k0 += 32) {
    __builtin_amdgcn_global_load_lds(
        (const __attribute__((address_space(1))) void*)(Ab + k0),
        (__attribute__((address_space(3))) void*)&As[w * 32][0], 16, 0, 0);
    __builtin_amdgcn_global_load_lds(
        (const __attribute__((address_space(1))) void*)(Ab + (size_t)16 * CONVDIM + k0),
        (__attribute__((address_space(3))) void*)&As[w * 32 + 16][0], 16, 0, 0);
    if (w == 0) {
      __builtin_amdgcn_global_load_lds(
          (const __attribute__((address_space(1))) void*)(Bb + k0),
          (__attribute__((address_space(3))) void*)&Bs[0][0], 16, 0, 0);
      __builtin_amdgcn_global_load_lds(
          (const __attribute__((address_space(1))) void*)(Bb + (size_t)16 * DINNER + k0),
          (__attribute__((address_space(3))) void*)&Bs[16][0], 16, 0, 0);
    }
    __syncthreads();
    bf16x8v af[2], bv[2];
#pragma unroll
    for (int i = 0; i < 2; i++)
      af[i] = *(const bf16x8v*)&As[w * 32 + i * 16 + (lane & 15)][(lane >> 4) * 8];
#pragma unroll
    for (int j = 0; j < 2; j++)
      bv[j] = *(const bf16x8v*)&Bs[j * 16 + (lane & 15)][(lane >> 4) * 8];
#pragma unroll
    for (int i = 0; i < 2; i++)
#pragma unroll
      for (int j = 0; j < 2; j++)
        acc[i][j] = __builtin_amdgcn_mfma_f32_16x16x32_bf16(af[i], bv[j], acc[i][j], 0, 0, 0);
    __syncthreads();
  }
  int quad = lane >> 4;
  int cn = lane & 15;
  float* outp = fdp + (size_t)ks * (L_SEQ * NHEADS);
#pragma unroll
  for (int i = 0; i < 2; i++)
#pragma unroll
    for (int j = 0; j < 2; j++)
#pragma unroll
      for (int r = 0; r < 4; r++) {
        int row = bm + w * 32 + i * 16 + quad * 4 + r;
        int col = j * 16 + cn;
        outp[(size_t)row * NHEADS + col] = acc[i][j][r];
      }
}

__global__ __launch_bounds__(256) void fc_reduce(
    const float* __restrict__ fdp, const float* __restrict__ Dp,
    float* __restrict__ fd) {
  int i = blockIdx.x * 256 + threadIdx.x;   // L_SEQ*NHEADS
  float s = Dp[i & (NHEADS - 1)];
#pragma unroll
  for (int ks = 0; ks < FC_KS; ks++) s += fdp[(size_t)ks * (L_SEQ * NHEADS) + i];
  fd[i] = s;
}

// ---------------- conv (4 t/thread) + SiLU, with dt softplus folded in ----------------
#define CONV_BLOCKS ((L_SEQ / 4) * CONVDIM / 256)   // 10240
__global__ __launch_bounds__(256) void conv_dt_kernel(
    const bf16* __restrict__ zx, const float* __restrict__ conv_w,
    const float* __restrict__ conv_b, bf16* __restrict__ xbc,
    const float* __restrict__ dt_bias, float* __restrict__ dt2) {
  int bid = blockIdx.x;
  if (bid < CONV_BLOCKS) {
    int idx = bid * 256 + threadIdx.x;
    int ch = idx % CONVDIM;
    int t0 = (idx / CONVDIM) * 4;
    const bf16* col = zx + DINNER + ch;
    float w0 = conv_w[ch * 4 + 0], w1 = conv_w[ch * 4 + 1];
    float w2 = conv_w[ch * 4 + 2], w3 = conv_w[ch * 4 + 3];
    float bsv = conv_b[ch];
    float x[7];
#pragma unroll
    for (int i = 0; i < 7; i++) {
      int t = t0 - 3 + i;
      x[i] = (t >= 0) ? b2f(col[(size_t)t * DPROJ]) : 0.f;
    }
#pragma unroll
    for (int j = 0; j < 4; j++) {
      float acc = bsv + w0 * x[j] + w1 * x[j + 1] + w2 * x[j + 2] + w3 * x[j + 3];
      xbc[(size_t)(t0 + j) * CONVDIM + ch] = f2b(acc / (1.f + __expf(-acc)));
    }
  } else {
    int idx = (bid - CONV_BLOCKS) * 256 + threadIdx.x;   // 2*L_SEQ*NHEADS
    int h = idx % NHEADS;
    int t = (idx / NHEADS) % L_SEQ;
    int b = idx / (NHEADS * L_SEQ);
    float v;
    if (b == 0) v = b2f(zx[(size_t)t * DPROJ + 4608 + h]);
    else        v = b2f(zx[(size_t)(L_SEQ - 1 - t) * DPROJ + 4608 + NHEADS + h]);
    v += dt_bias[h];
    dt2[idx] = (v > 20.f) ? v : log1pf(expf(v));
  }
}

// ---------------- G[b,c,l,s] = sum_n C[l,n]*B[s,n]  (MFMA, quarter-split) ----------------
__global__ __launch_bounds__(256) void gmat_kernel(
    const bf16* __restrict__ xbc, bf16* __restrict__ G) {
  __shared__ bf16 Cs[32][136];   // C[l0+l][n]  8.5 KB
  __shared__ bf16 Bs[128][136];  // B[s][n]     34 KB
  int blk = blockIdx.x;          // (b*32+c)*4 + quarter
  int quarter = blk & 3;
  int bc = blk >> 2;
  int b = bc / NCHUNK, c = bc % NCHUNK;
  int l0 = quarter * 32;
  int tid = threadIdx.x;
  int lane = tid & 63;
  int w = tid >> 6;
  int bofs = b ? 2304 : 2048;
  int cofs = b ? 2432 : 2176;
  for (int o = tid; o < CHUNKL * DSTATE / 8; o += 256) {   // 2048 vecs
    int s = o >> 4;
    int n8 = (o & 15) * 8;
    int t = b ? (L_SEQ - 1 - (c * CHUNKL + s)) : (c * CHUNKL + s);
    *(bf16x8v*)&Bs[s][n8] = *(const bf16x8v*)&xbc[(size_t)t * CONVDIM + bofs + n8];
  }
  for (int o = tid; o < 32 * DSTATE / 8; o += 256) {       // 512 vecs
    int l = o >> 4;
    int n8 = (o & 15) * 8;
    int t = b ? (L_SEQ - 1 - (c * CHUNKL + l0 + l)) : (c * CHUNKL + l0 + l);
    *(bf16x8v*)&Cs[l][n8] = *(const bf16x8v*)&xbc[(size_t)t * CONVDIM + cofs + n8];
  }
  __syncthreads();
  if (w > quarter) return;   // s-tiles 2w,2w+1 start at s=32w > l0+31: masked at use
  f32x4v acc[2][2];
#pragma unroll
  for (int i = 0; i < 2; i++)
#pragma unroll
    for (int j = 0; j < 2; j++) acc[i][j] = (f32x4v){0.f, 0.f, 0.f, 0.f};
#pragma unroll
  for (int k0 = 0; k0 < 128; k0 += 32) {
    bf16x8v a0 = *(const bf16x8v*)&Cs[(lane & 15)][(lane >> 4) * 8 + k0];
    bf16x8v a1 = *(const bf16x8v*)&Cs[16 + (lane & 15)][(lane >> 4) * 8 + k0];
#pragma unroll
    for (int j = 0; j < 2; j++) {
      bf16x8v bv = *(const bf16x8v*)&Bs[(2 * w + j) * 16 + (lane & 15)][(lane >> 4) * 8 + k0];
      acc[0][j] = __builtin_amdgcn_mfma_f32_16x16x32_bf16(a0, bv, acc[0][j], 0, 0, 0);
      acc[1][j] = __builtin_amdgcn_mfma_f32_16x16x32_bf16(a1, bv, acc[1][j], 0, 0, 0);
    }
  }
  int quad = lane >> 4, cn = lane & 15;
  bf16* Gb = G + (size_t)bc * CHUNKL * CHUNKL;
#pragma unroll
  for (int i = 0; i < 2; i++)
#pragma unroll
    for (int j = 0; j < 2; j++)
#pragma unroll
      for (int r = 0; r < 4; r++) {
        int l = l0 + i * 16 + quad * 4 + r;
        int s = (2 * w + j) * 16 + cn;
        Gb[l * CHUNKL + s] = f2b(acc[i][j][r]);
      }
}

// ---------------- per-(b,c,h): chunk states only (MFMA, bf16 out) ----------------
// R11: serial tid-0 cumsum replaced by the R7-verified wave-parallel shfl_up
// scan (2 elems/lane, wave 0); csum written by lane 63 (holds inclusive total).
__global__ __launch_bounds__(256) void chunk_kernel(
    const bf16* __restrict__ xbc, const float* __restrict__ dt2,
    const float* __restrict__ A_log,
    bf16* __restrict__ states, float* __restrict__ csum) {
  int gid = blockIdx.x;           // (b*32+c)*32 + h
  int h = gid % NHEADS;
  int bc = gid / NHEADS;
  int c = bc % NCHUNK, b = bc / NCHUNK;
  int tid = threadIdx.x;
  int lane = tid & 63;
  int w = tid >> 6;
  __shared__ bf16 BdT[128][136];  // [n][l] = B[l][n]*decay[l]  34 KB
  __shared__ bf16 xdtT[64][136];  // [p][s] = x[s,p]*dt[s]      17 KB
  __shared__ float acs[CHUNKL];
  __shared__ float dtl[CHUNKL];
  __shared__ float decays[CHUNKL];
  if (tid < CHUNKL)
    dtl[tid] = dt2[((size_t)b * L_SEQ + c * CHUNKL + tid) * NHEADS + h];
  __syncthreads();
  if (tid < 64) {
    float Ah = -__expf(A_log[h]);
    float v0 = Ah * dtl[2 * tid];
    float v1 = Ah * dtl[2 * tid + 1];
    float s = v0 + v1;
#pragma unroll
    for (int off = 1; off < 64; off <<= 1) {
      float t = __shfl_up(s, off);
      if (tid >= off) s += t;
    }
    acs[2 * tid]     = s - v1;
    acs[2 * tid + 1] = s;
    if (tid == 63) csum[gid] = __expf(s);   // pre-exponentiated total for scan
  }
  __syncthreads();
  if (tid < CHUNKL) decays[tid] = __expf(acs[CHUNKL - 1] - acs[tid]);
  // xdtT[p][s] staging: lane->s (t-strided 16B loads), conflict-free scatter
  for (int o = tid; o < CHUNKL * HEADDIM / 8; o += 256) {   // 1024 vecs
    int s = o & 127;
    int p8 = (o >> 7) * 8;
    int t = b ? (L_SEQ - 1 - (c * CHUNKL + s)) : (c * CHUNKL + s);
    bf16x8v xv = *(const bf16x8v*)&xbc[(size_t)t * CONVDIM + h * HEADDIM + p8];
    float d = dtl[s];
#pragma unroll
    for (int j = 0; j < 8; j++) xdtT[p8 + j][s] = f2b(sh2f(xv[j]) * d);
  }
  __syncthreads();   // decays ready
  // BdT[n][l] staging: lane->l, conflict-free scatter
  for (int o = tid; o < CHUNKL * CHUNKL / 8; o += 256) {    // 2048 vecs
    int l = o & 127;
    int n8 = (o >> 7) * 8;
    int t = b ? (L_SEQ - 1 - (c * CHUNKL + l)) : (c * CHUNKL + l);
    bf16x8v bv = *(const bf16x8v*)&xbc[(size_t)t * CONVDIM + (b ? 2304 : 2048) + n8];
    float d = decays[l];
#pragma unroll
    for (int j = 0; j < 8; j++) BdT[n8 + j][l] = f2b(sh2f(bv[j]) * d);
  }
  __syncthreads();
  // states[p][n] = sum_l xdtT[p][l]*BdT[n][l]; wave w -> p rows [16w,16w+16)
  f32x4v accS[8];
#pragma unroll
  for (int j = 0; j < 8; j++) accS[j] = (f32x4v){0.f, 0.f, 0.f, 0.f};
#pragma unroll
  for (int k0 = 0; k0 < 128; k0 += 32) {
    bf16x8v av = *(const bf16x8v*)&xdtT[w * 16 + (lane & 15)][(lane >> 4) * 8 + k0];
#pragma unroll
    for (int j = 0; j < 8; j++) {
      bf16x8v bv = *(const bf16x8v*)&BdT[j * 16 + (lane & 15)][(lane >> 4) * 8 + k0];
      accS[j] = __builtin_amdgcn_mfma_f32_16x16x32_bf16(av, bv, accS[j], 0, 0, 0);
    }
  }
  int quad = lane >> 4, cn = lane & 15;
  bf16* st = states + (size_t)gid * (HEADDIM * DSTATE);
#pragma unroll
  for (int j = 0; j < 8; j++)
#pragma unroll
    for (int r = 0; r < 4; r++) {
      int p = w * 16 + quad * 4 + r;
      int n = j * 16 + cn;
      st[p * DSTATE + n] = f2b(accS[j][r]);
    }
}

// ---------------- inter-chunk scan: register-batched (independent loads first) --------
__global__ __launch_bounds__(256) void scan_kernel(
    bf16* __restrict__ states, const float* __restrict__ csum) {
  int idx = blockIdx.x * 256 + threadIdx.x;  // 2*NHEADS*HEADDIM*DSTATE
  int n = idx % DSTATE;
  int p = (idx / DSTATE) % HEADDIM;
  int h = (idx / (DSTATE * HEADDIM)) % NHEADS;
  int b = idx / (DSTATE * HEADDIM * NHEADS);
  size_t base = ((size_t)(b * NCHUNK) * NHEADS + h) * (HEADDIM * DSTATE) + p * DSTATE + n;
  const size_t cstride = (size_t)NHEADS * HEADDIM * DSTATE;
  float tmp[NCHUNK], cv[NCHUNK];
#pragma unroll
  for (int c = 0; c < NCHUNK; c++) tmp[c] = b2f(states[base + c * cstride]);
#pragma unroll
  for (int c = 0; c < NCHUNK; c++) cv[c] = csum[(b * NCHUNK + c) * NHEADS + h];
  float S = 0.f;
#pragma unroll
  for (int c = 0; c < NCHUNK; c++) {
    states[base + c * cstride] = f2b(S);
    S = cv[c] * S + tmp[c];
  }
}

// ---------------- fused Y = Y_diag + Y_off + D*x (MFMA, single bf16 write) ----------------
// R11: R8 body + (a) epilogue x values preloaded into registers in the T14 block
// (their global latency now hides under staging+GEMM1+GEMM2 instead of sitting
// exposed at the end); (b) s_setprio(1) around both MFMA clusters (T5: 3
// independent blocks/CU at different phases = the attn-like regime where it
// measured +4-7%); launch_bounds(256,3) pins 3 waves/SIMD vs the +64 VGPR.
__global__ __launch_bounds__(256, 3) void yoff_kernel(
    const bf16* __restrict__ xbc, const float* __restrict__ dt2,
    const float* __restrict__ A_log, const bf16* __restrict__ G,
    const bf16* __restrict__ states, const float* __restrict__ Dp,
    bf16* __restrict__ Y) {
  int gid = blockIdx.x;
  int h = gid % NHEADS;
  int bc = gid / NHEADS;
  int c = bc % NCHUNK, b = bc / NCHUNK;
  int tid = threadIdx.x;
  int lane = tid & 63;
  int w = tid >> 6;
  __shared__ bf16 WB[128][136];   // 34 KB (W, then Ce)
  __shared__ bf16 SX[64][136];    // 17 KB (xdtT, then St)
  __shared__ float acs[CHUNKL];
  __shared__ float dtl[CHUNKL];
  __shared__ float eAl[CHUNKL];
  if (tid < CHUNKL)
    dtl[tid] = dt2[((size_t)b * L_SEQ + c * CHUNKL + tid) * NHEADS + h];
  __syncthreads();
  // wave-parallel inclusive scan of Ah*dtl (128 elems, 2/lane, wave 0 only)
  if (tid < 64) {
    float Ah = -__expf(A_log[h]);
    float v0 = Ah * dtl[2 * tid];
    float v1 = Ah * dtl[2 * tid + 1];
    float s = v0 + v1;
#pragma unroll
    for (int off = 1; off < 64; off <<= 1) {
      float t = __shfl_up(s, off);
      if (tid >= off) s += t;
    }
    acs[2 * tid]     = s - v1;
    acs[2 * tid + 1] = s;
  }
  __syncthreads();
  if (tid < CHUNKL) eAl[tid] = __expf(acs[tid]);   // <= 1
  // T14: issue Ce + St + epilogue-x global loads NOW; consumed after GEMM1/2.
  bf16x8v ce_r[8], st_r[4];
  float xe[2][4][4];
  {
    int cofs = b ? 2432 : 2176;
#pragma unroll
    for (int it = 0; it < 8; it++) {
      int o = tid + it * 256;
      int l = o >> 4;
      int n8 = (o & 15) * 8;
      int t = b ? (L_SEQ - 1 - (c * CHUNKL + l)) : (c * CHUNKL + l);
      ce_r[it] = *(const bf16x8v*)&xbc[(size_t)t * CONVDIM + cofs + n8];
    }
    const bf16* stp = states + (size_t)gid * (HEADDIM * DSTATE);
#pragma unroll
    for (int it = 0; it < 4; it++) {
      int o = tid + it * 256;
      st_r[it] = *(const bf16x8v*)&stp[o * 8];
    }
    int quad0 = lane >> 4, cn0 = lane & 15;
#pragma unroll
    for (int i = 0; i < 2; i++)
#pragma unroll
      for (int j = 0; j < 4; j++)
#pragma unroll
        for (int r = 0; r < 4; r++) {
          int l = w * 32 + i * 16 + quad0 * 4 + r;
          int p = j * 16 + cn0;
          int t = b ? (L_SEQ - 1 - (c * CHUNKL + l)) : (c * CHUNKL + l);
          xe[i][j][r] = b2f(xbc[(size_t)t * CONVDIM + h * HEADDIM + p]);
        }
  }
  // SX <- xdtT[p][s]: lane->s, conflict-free scatter
  for (int o = tid; o < CHUNKL * HEADDIM / 8; o += 256) {   // 1024 vecs
    int s = o & 127;
    int p8 = (o >> 7) * 8;
    int t = b ? (L_SEQ - 1 - (c * CHUNKL + s)) : (c * CHUNKL + s);
    bf16x8v xv = *(const bf16x8v*)&xbc[(size_t)t * CONVDIM + h * HEADDIM + p8];
    float d = dtl[s];
#pragma unroll
    for (int j = 0; j < 8; j++) SX[p8 + j][s] = f2b(sh2f(xv[j]) * d);
  }
  // WB <- W[l][s] = G*exp(acs[l]-acs[s]) (s<=l): b128 writes; upper-tri vecs
  // (s8 > l) skip the G load and expf entirely.
  {
    const bf16* Gb = G + (size_t)bc * CHUNKL * CHUNKL;
    for (int o = tid; o < CHUNKL * CHUNKL / 8; o += 256) {  // 2048 vecs
      int l = o >> 4;
      int s8 = (o & 15) * 8;
      bf16x8v wv;
      if (s8 > l) {
#pragma unroll
        for (int j = 0; j < 8; j++) wv[j] = 0;
      } else {
        bf16x8v g = *(const bf16x8v*)&Gb[l * CHUNKL + s8];
        float al = acs[l];
#pragma unroll
        for (int j = 0; j < 8; j++) {
          int s = s8 + j;
          float e = (s <= l) ? sh2f(g[j]) * __expf(al - acs[s]) : 0.f;
          wv[j] = f2bs(e);
        }
      }
      *(bf16x8v*)&WB[l][s8] = wv;
    }
  }
  __syncthreads();
  f32x4v accY[2][4];
#pragma unroll
  for (int i = 0; i < 2; i++)
#pragma unroll
    for (int j = 0; j < 4; j++) accY[i][j] = (f32x4v){0.f, 0.f, 0.f, 0.f};
  // Y_diag: A=W rows [32w,32w+32), B=xdtT p-tiles, k=s.
  // Wave-uniform skip: k0 > 32w+31 => A block all-zero (strict upper triangle).
  __builtin_amdgcn_s_setprio(1);
#pragma unroll
  for (int k0 = 0; k0 < 128; k0 += 32) {
    if (k0 > w * 32 + 31) break;
    bf16x8v a0 = *(const bf16x8v*)&WB[w * 32 + (lane & 15)][(lane >> 4) * 8 + k0];
    bf16x8v a1 = *(const bf16x8v*)&WB[w * 32 + 16 + (lane & 15)][(lane >> 4) * 8 + k0];
#pragma unroll
    for (int j = 0; j < 4; j++) {
      bf16x8v bv = *(const bf16x8v*)&SX[j * 16 + (lane & 15)][(lane >> 4) * 8 + k0];
      accY[0][j] = __builtin_amdgcn_mfma_f32_16x16x32_bf16(a0, bv, accY[0][j], 0, 0, 0);
      accY[1][j] = __builtin_amdgcn_mfma_f32_16x16x32_bf16(a1, bv, accY[1][j], 0, 0, 0);
    }
  }
  __builtin_amdgcn_s_setprio(0);
  __syncthreads();   // all phase-1 LDS reads done
  // restage from REGISTERS (global latency already hidden under GEMM1):
  // WB <- Ce*eAl, SX <- St
  {
#pragma unroll
    for (int it = 0; it < 8; it++) {
      int o = tid + it * 256;
      int l = o >> 4;
      int n8 = (o & 15) * 8;
      float e = eAl[l];
      bf16x8v ov;
#pragma unroll
      for (int j = 0; j < 8; j++) ov[j] = f2bs(sh2f(ce_r[it][j]) * e);
      *(bf16x8v*)&WB[l][n8] = ov;
    }
#pragma unroll
    for (int it = 0; it < 4; it++) {
      int o = tid + it * 256;
      int p = o >> 4;
      int n8 = (o & 15) * 8;
      *(bf16x8v*)&SX[p][n8] = st_r[it];
    }
  }
  __syncthreads();
  // Y_off: A=Ce rows, B=St p-tiles, k=n; accumulate into same accY
  __builtin_amdgcn_s_setprio(1);
#pragma unroll
  for (int k0 = 0; k0 < 128; k0 += 32) {
    bf16x8v a0 = *(const bf16x8v*)&WB[w * 32 + (lane & 15)][(lane >> 4) * 8 + k0];
    bf16x8v a1 = *(const bf16x8v*)&WB[w * 32 + 16 + (lane & 15)][(lane >> 4) * 8 + k0];
#pragma unroll
    for (int j = 0; j < 4; j++) {
      bf16x8v bv = *(const bf16x8v*)&SX[j * 16 + (lane & 15)][(lane >> 4) * 8 + k0];
      accY[0][j] = __builtin_amdgcn_mfma_f32_16x16x32_bf16(a0, bv, accY[0][j], 0, 0, 0);
      accY[1][j] = __builtin_amdgcn_mfma_f32_16x16x32_bf16(a1, bv, accY[1][j], 0, 0, 0);
    }
  }
  __builtin_amdgcn_s_setprio(0);
  int quad = lane >> 4, cn = lane & 15;
  float Dh = Dp[h];
#pragma unroll
  for (int i = 0; i < 2; i++)
#pragma unroll
    for (int j = 0; j < 4; j++)
#pragma unroll
      for (int r = 0; r < 4; r++) {
        int l = w * 32 + i * 16 + quad * 4 + r;
        int p = j * 16 + cn;
        size_t yi = ((size_t)b * L_SEQ + c * CHUNKL + l) * DINNER + h * HEADDIM + p;
        Y[yi] = f2b(accY[i][j][r] + xe[i][j][r] * Dh);
      }
}

// ---------------- combine: shift, flip, +x*fd, gate, RMSNorm (vectorized) ----------------
__global__ __launch_bounds__(256) void combine_kernel(
    const bf16* __restrict__ Y, const bf16* __restrict__ xbc,
    const bf16* __restrict__ zx, const float* __restrict__ fd,
    const float* __restrict__ norm_w, bf16* __restrict__ yn) {
  int t = blockIdx.x;
  int tid = threadIdx.x;
  int j8 = tid * 8;
  float yf[8], yb[8];
#pragma unroll
  for (int j = 0; j < 8; j++) { yf[j] = 0.f; yb[j] = 0.f; }
  if (t >= 1) {
    bf16x8v v = *(const bf16x8v*)&Y[(size_t)(t - 1) * DINNER + j8];
#pragma unroll
    for (int j = 0; j < 8; j++) yf[j] = sh2f(v[j]);
  }
  if (t <= L_SEQ - 2) {
    bf16x8v v = *(const bf16x8v*)&Y[((size_t)L_SEQ + (L_SEQ - 2 - t)) * DINNER + j8];
#pragma unroll
    for (int j = 0; j < 8; j++) yb[j] = sh2f(v[j]);
  }
  bf16x8v xogv = *(const bf16x8v*)&xbc[(size_t)t * CONVDIM + j8];
  bf16x8v zv = *(const bf16x8v*)&zx[(size_t)t * DPROJ + j8];
  float fdv = fd[t * NHEADS + (j8 >> 6)];
  float yg[8];
  float ss = 0.f;
#pragma unroll
  for (int j = 0; j < 8; j++) {
    float y = yf[j] + yb[j] + sh2f(xogv[j]) * fdv;
    float z = sh2f(zv[j]);
    float g = y * (z / (1.f + __expf(-z)));
    yg[j] = g;
    ss += g * g;
  }
#pragma unroll
  for (int off = 32; off > 0; off >>= 1) ss += __shfl_down(ss, off);
  __shared__ float red[4];
  if ((tid & 63) == 0) red[tid >> 6] = ss;
  __syncthreads();
  float tot = red[0] + red[1] + red[2] + red[3];
  float scale = rsqrtf(tot / (float)DINNER + 1e-5f);
  float4 nw0 = *(const float4*)&norm_w[j8];
  float4 nw1 = *(const float4*)&norm_w[j8 + 4];
  bf16x8v ov;
  ov[0] = f2bs(yg[0] * scale * nw0.x);
  ov[1] = f2bs(yg[1] * scale * nw0.y);
  ov[2] = f2bs(yg[2] * scale * nw0.z);
  ov[3] = f2bs(yg[3] * scale * nw0.w);
  ov[4] = f2bs(yg[4] * scale * nw1.x);
  ov[5] = f2bs(yg[5] * scale * nw1.y);
  ov[6] = f2bs(yg[6] * scale * nw1.z);
  ov[7] = f2bs(yg[7] * scale * nw1.w);
  *(bf16x8v*)&yn[(size_t)t * DINNER + j8] = ov;
}

// ---------------- launch ----------------
extern "C" void kernel_launch(void* const* d_in, const int* in_sizes, int n_in,
                              void* d_out, int out_size, void* d_ws, size_t ws_size,
                              hipStream_t stream) {
  const float* u         = (const float*)d_in[0];
  const float* in_proj_w = (const float*)d_in[1];
  const float* conv_w    = (const float*)d_in[2];
  const float* conv_b    = (const float*)d_in[3];
  const float* dt_bias   = (const float*)d_in[4];
  const float* A_log     = (const float*)d_in[5];
  const float* Dp        = (const float*)d_in[6];
  const float* fc_D_w    = (const float*)d_in[7];
  const float* norm_w    = (const float*)d_in[8];
  const float* out_proj_w= (const float*)d_in[9];
  float* out = (float*)d_out;

  char* base = (char*)d_ws;
  bf16*  zx  = (bf16*)base;  base += (size_t)L_SEQ * DPROJ * 2;                    // 38.3 MB
  bf16*  xbc = (bf16*)base;  base += (size_t)L_SEQ * CONVDIM * 2;                  // 21.0 MB
  float* dt2 = (float*)base; base += (size_t)2 * L_SEQ * NHEADS * 4;               //  1.0 MB
  bf16*  G   = (bf16*)base;  base += (size_t)2 * NCHUNK * CHUNKL * CHUNKL * 4;     //  4.2 MB region
  bf16*  Yb  = (bf16*)base;  base += (size_t)2 * L_SEQ * DINNER * 4;               // 67.1 MB region
  bf16*  stb = (bf16*)base;  base += (size_t)2 * NCHUNK * NHEADS * HEADDIM * DSTATE * 4; // 67.1 MB region
  float* cs  = (float*)base; base += (size_t)2 * NCHUNK * NHEADS * 4;              //  8 KB
  // aliases into dead regions:
  bf16*  u_bf   = (bf16*)Yb;                          // 8.4 MB   (Yb live only after yoff)
  bf16*  w1p_bf = (bf16*)((char*)Yb + 9437184);       // 9.7 MB   (in_proj_w padded to 4736 rows)
  bf16*  w2_bf  = (bf16*)G;                           // 4.2 MB   (G dead after yoff)
  bf16*  yn     = (bf16*)stb;                         // 16.8 MB  (stb dead after yoff)
  float* fd     = (float*)((char*)stb + 33554432);    //  0.5 MB  (32 MB offset)
  bf16*  wf_bf  = (bf16*)((char*)stb + 35651584);     //  128 KB  (34 MB offset)
  float* fdp    = (float*)((char*)stb + 37748736);    //  8 MB    (36 MB offset)
  float* p1     = (float*)Yb;                         // 16.8 MB  (Yb dead after combine)

  // 0. fused casts for MFMA gemm1 (w1 zero-padded to NPAD1 rows)
  cast2_kernel<<<(L_SEQ * DMODEL + NPAD1 * DMODEL) / 256, 256, 0, stream>>>(
      u, in_proj_w, u_bf, w1p_bf);
  // 1a. in_proj main: cols [0,4096) (8-phase 256^2, 256 blocks = exactly 1 round)
  gemm1_8ph<<<(L_SEQ / 256) * G1_GN, 512, 0, stream>>>(u_bf, w1p_bf, zx);
  // 1b. in_proj remainder: cols [4096,4672) (128^2 gemm, 160 blocks)
  gemm_mfma<bf16><<<(L_SEQ / 128) * ((NPAD1 - NSPLIT) / 128), 256, 0, stream>>>(
      u_bf, DMODEL, w1p_bf + (size_t)NSPLIT * DMODEL, DMODEL,
      zx + NSPLIT, DPROJ, DPROJ - NSPLIT, DMODEL,
      L_SEQ / 128, (NPAD1 - NSPLIT) / 128, 0);
  // 2. conv + silu + dt (fused)
  conv_dt_kernel<<<CONV_BLOCKS + (2 * L_SEQ * NHEADS) / 256, 256, 0, stream>>>(
      zx, conv_w, conv_b, xbc, dt_bias, dt2);
  // 3a. G = C B^T per (b,c), quarter-split (MFMA, bf16)
  gmat_kernel<<<2 * NCHUNK * 4, 256, 0, stream>>>(xbc, G);
  // 3b. chunk states (MFMA, bf16; wave-parallel scan)
  chunk_kernel<<<2 * NCHUNK * NHEADS, 256, 0, stream>>>(
      xbc, dt2, A_log, stb, cs);
  // 3c. inter-chunk scan (register-batched)
  scan_kernel<<<(2 * NHEADS * HEADDIM * DSTATE) / 256, 256, 0, stream>>>(stb, cs);
  // 3d. fused Y = Y_diag + Y_off + D*x (MFMA; T14 full preload + setprio)
  yoff_kernel<<<2 * NCHUNK * NHEADS, 256, 0, stream>>>(
      xbc, dt2, A_log, G, stb, Dp, Yb);
  // 4a. casts into dead regions: out_proj_w -> w2_bf (G), fc_D_w -> wf_bf (stb)
  cast_kernel<<<(DMODEL * DINNER + 255) / 256, 256, 0, stream>>>(
      out_proj_w, w2_bf, DMODEL * DINNER, DMODEL * DINNER);
  cast_kernel<<<(NHEADS * DINNER + 255) / 256, 256, 0, stream>>>(
      fc_D_w, wf_bf, NHEADS * DINNER, NHEADS * DINNER);
  // 4b. fd = x_og @ fc_D_w^T + D  (MFMA split-K=16: 512 blocks, then reduce)
  fc_mfma<<<(L_SEQ / 128) * FC_KS, 256, 0, stream>>>(xbc, wf_bf, fdp);
  fc_reduce<<<(L_SEQ * NHEADS) / 256, 256, 0, stream>>>(fdp, Dp, fd);
  // 5. combine + gate + RMSNorm
  combine_kernel<<<L_SEQ, 256, 0, stream>>>(Yb, xbc, zx, fd, norm_w, yn);
  // 6. out_proj split-K=2 (512 blocks = 2/CU) + add pass
  outproj_ks<<<512, 256, 0, stream>>>(yn, w2_bf, out, p1);
  add_kernel<<<(L_SEQ * DMODEL) / 1024, 256, 0, stream>>>(out, p1);
}

// Round 12
// 351.632 us; speedup vs baseline: 1.1522x; 1.0049x over previous
//
#include <hip/hip_runtime.h>
#include <hip/hip_bf16.h>
#include <math.h>

// ---------------- problem constants ----------------
#define L_SEQ   4096
#define DMODEL  1024
#define DINNER  2048
#define NHEADS  32
#define HEADDIM 64
#define DSTATE  128
#define NCHUNK  32
#define CHUNKL  128
#define CONVDIM 2560
#define DPROJ   4672   // 2*DINNER + 2*(2*DSTATE) + 2*NHEADS
#define NPAD1   4736   // DPROJ padded to multiple of 128 (for remainder gemm)
#define NSPLIT  4096   // cols [0,NSPLIT) via 8-phase 256^2 (256 blocks = 1 round);
                       // cols [NSPLIT,DPROJ) via 128^2 gemm (160 blocks)

typedef __hip_bfloat16 bf16;
__device__ __forceinline__ float b2f(bf16 x) { return __bfloat162float(x); }
__device__ __forceinline__ bf16 f2b(float x) { return __float2bfloat16(x); }
__device__ __forceinline__ float sh2f(short s) {
  return __uint_as_float(((unsigned int)(unsigned short)s) << 16);
}
__device__ __forceinline__ short f2bs(float x) {
  bf16 t = __float2bfloat16(x);
  return *reinterpret_cast<short*>(&t);
}

typedef __attribute__((ext_vector_type(8))) short bf16x8v;
typedef __attribute__((ext_vector_type(4))) float f32x4v;

// zxbcdt column layout: [0,2048) = z ; [2048,4608) = xBC ; [4608,4672) = dt raw
// xBC_conv channel layout: [0,2048) = x ; fw B = [2048,2176) C = [2176,2304)
//                          bw B = [2304,2432) C = [2432,2560)  (bw streams time-flipped)

// ---------------- fused casts: u -> bf16 and in_proj_w -> bf16 (zero-padded) ----------------
__global__ __launch_bounds__(256) void cast2_kernel(
    const float* __restrict__ u, const float* __restrict__ w1,
    bf16* __restrict__ u_bf, bf16* __restrict__ w1_bf) {
  const int NU = (L_SEQ * DMODEL) / 256;   // 16384 blocks
  int bid = blockIdx.x;
  if (bid < NU) {
    int i = bid * 256 + threadIdx.x;
    u_bf[i] = f2b(u[i]);
  } else {
    int i = (bid - NU) * 256 + threadIdx.x;
    w1_bf[i] = (i < DPROJ * DMODEL) ? f2b(w1[i]) : f2b(0.f);
  }
}

// ---------------- f32 -> bf16 cast ----------------
__global__ __launch_bounds__(256) void cast_kernel(
    const float* __restrict__ src, bf16* __restrict__ dst, int n_src, int n_tot) {
  int i = blockIdx.x * 256 + threadIdx.x;
  if (i < n_tot) dst[i] = (i < n_src) ? f2b(src[i]) : f2b(0.f);
}

// ================= in_proj main: 8-phase 256x256 GEMM (R1-verified body) =================
#define G1_K  1024
#define G1_GN 16            // N tiles of 256 covering [0,4096)
#define G1_NT (G1_K / 64)   // 16 K-tiles

__global__ __launch_bounds__(512, 2) void gemm1_8ph(
    const bf16* __restrict__ A, const bf16* __restrict__ B, bf16* __restrict__ C) {
  __shared__ bf16 Al[2][2][8192];   // [slot][half][subtiled 128x64]  64 KB
  __shared__ bf16 Bl[2][2][8192];   // 64 KB
  const int tid = threadIdx.x;
  const int lane = tid & 63;
  const int w = tid >> 6;        // 0..7
  const int wm = w >> 2;         // 0..1 -> C rows [wm*128, +128)
  const int wn = w & 3;          // 0..3 -> C cols [wn*64, +64)
  const int bm = (blockIdx.x / G1_GN) * 256;
  const int bn = (blockIdx.x % G1_GN) * 256;
  const int scol = ((lane & 3) ^ (((lane >> 5) & 1) << 1)) * 8;
  const int cin = ((lane >> 4) * 8) ^ (((lane >> 3) & 1) << 4);
  const int r16 = lane & 15;
  const bf16* Ag = A + (size_t)bm * G1_K;
  const bf16* Bg = B + (size_t)bn * G1_K;

  auto stage = [&](int mat, int tt, int hf) {
    const bf16* g = (mat ? Bg : Ag)
        + (size_t)(hf * 128 + (w >> 1) * 16 + (lane >> 2)) * G1_K
        + tt * 64 + (w & 1) * 32 + scol;
    bf16* d0 = mat ? &Bl[tt & 1][hf][0] : &Al[tt & 1][hf][0];
    __builtin_amdgcn_global_load_lds(
        (const __attribute__((address_space(1))) void*)g,
        (__attribute__((address_space(3))) void*)(d0 + w * 512), 16, 0, 0);
    __builtin_amdgcn_global_load_lds(
        (const __attribute__((address_space(1))) void*)(g + (size_t)64 * G1_K),
        (__attribute__((address_space(3))) void*)(d0 + (8 + w) * 512), 16, 0, 0);
  };

  f32x4v acc[8][4];
#pragma unroll
  for (int i = 0; i < 8; i++)
#pragma unroll
    for (int j = 0; j < 4; j++) acc[i][j] = (f32x4v){0.f, 0.f, 0.f, 0.f};

  stage(0, 0, 0); stage(0, 0, 1); stage(1, 0, 0); stage(1, 0, 1);
  stage(0, 1, 0); stage(0, 1, 1); stage(1, 1, 0);
  asm volatile("s_waitcnt vmcnt(6)" ::: "memory");
  __builtin_amdgcn_s_barrier();
  __builtin_amdgcn_sched_barrier(0);

#pragma unroll 2
  for (int t = 0; t < G1_NT; ++t) {
    const int slot = t & 1;
    const bf16* Ah = &Al[slot][wm][0];
    const bf16* Bh = &Bl[slot][wn >> 1][0];
    const int brb = (wn & 1) * 4;
    bf16x8v a[4][2], b[4][2];
    // ---- phase 0
#pragma unroll
    for (int i = 0; i < 4; i++) {
      a[i][0] = *(const bf16x8v*)&Ah[(i * 2 + 0) * 512 + r16 * 32 + cin];
      a[i][1] = *(const bf16x8v*)&Ah[(i * 2 + 1) * 512 + r16 * 32 + cin];
    }
#pragma unroll
    for (int j = 0; j < 2; j++) {
      b[j][0] = *(const bf16x8v*)&Bh[((brb + j) * 2 + 0) * 512 + r16 * 32 + cin];
      b[j][1] = *(const bf16x8v*)&Bh[((brb + j) * 2 + 1) * 512 + r16 * 32 + cin];
    }
    if (t + 1 < G1_NT) stage(1, t + 1, 1);
    __builtin_amdgcn_s_barrier();
    asm volatile("s_waitcnt lgkmcnt(0)" ::: "memory");
    __builtin_amdgcn_s_setprio(1);
#pragma unroll
    for (int i = 0; i < 4; i++)
#pragma unroll
      for (int j = 0; j < 2; j++) {
        acc[i][j] = __builtin_amdgcn_mfma_f32_16x16x32_bf16(a[i][0], b[j][0], acc[i][j], 0, 0, 0);
        acc[i][j] = __builtin_amdgcn_mfma_f32_16x16x32_bf16(a[i][1], b[j][1], acc[i][j], 0, 0, 0);
      }
    __builtin_amdgcn_s_setprio(0);
    __builtin_amdgcn_s_barrier();
    // ---- phase 1
#pragma unroll
    for (int j = 2; j < 4; j++) {
      b[j][0] = *(const bf16x8v*)&Bh[((brb + j) * 2 + 0) * 512 + r16 * 32 + cin];
      b[j][1] = *(const bf16x8v*)&Bh[((brb + j) * 2 + 1) * 512 + r16 * 32 + cin];
    }
    __builtin_amdgcn_s_barrier();
    asm volatile("s_waitcnt lgkmcnt(0)" ::: "memory");
    __builtin_amdgcn_s_setprio(1);
#pragma unroll
    for (int i = 0; i < 4; i++)
#pragma unroll
      for (int j = 2; j < 4; j++) {
        acc[i][j] = __builtin_amdgcn_mfma_f32_16x16x32_bf16(a[i][0], b[j][0], acc[i][j], 0, 0, 0);
        acc[i][j] = __builtin_amdgcn_mfma_f32_16x16x32_bf16(a[i][1], b[j][1], acc[i][j], 0, 0, 0);
      }
    __builtin_amdgcn_s_setprio(0);
    __builtin_amdgcn_s_barrier();
    // ---- phase 2
#pragma unroll
    for (int i = 0; i < 4; i++) {
      a[i][0] = *(const bf16x8v*)&Ah[((4 + i) * 2 + 0) * 512 + r16 * 32 + cin];
      a[i][1] = *(const bf16x8v*)&Ah[((4 + i) * 2 + 1) * 512 + r16 * 32 + cin];
    }
    if (t + 2 < G1_NT) stage(1, t + 2, 0);
    __builtin_amdgcn_s_barrier();
    asm volatile("s_waitcnt lgkmcnt(0)" ::: "memory");
    __builtin_amdgcn_s_setprio(1);
#pragma unroll
    for (int i = 0; i < 4; i++)
#pragma unroll
      for (int j = 2; j < 4; j++) {
        acc[4 + i][j] = __builtin_amdgcn_mfma_f32_16x16x32_bf16(a[i][0], b[j][0], acc[4 + i][j], 0, 0, 0);
        acc[4 + i][j] = __builtin_amdgcn_mfma_f32_16x16x32_bf16(a[i][1], b[j][1], acc[4 + i][j], 0, 0, 0);
      }
    __builtin_amdgcn_s_setprio(0);
    __builtin_amdgcn_s_barrier();
    // ---- phase 3
    if (t + 2 < G1_NT) { stage(0, t + 2, 0); stage(0, t + 2, 1); }
    __builtin_amdgcn_s_barrier();
    __builtin_amdgcn_s_setprio(1);
#pragma unroll
    for (int i = 0; i < 4; i++)
#pragma unroll
      for (int j = 0; j < 2; j++) {
        acc[4 + i][j] = __builtin_amdgcn_mfma_f32_16x16x32_bf16(a[i][0], b[j][0], acc[4 + i][j], 0, 0, 0);
        acc[4 + i][j] = __builtin_amdgcn_mfma_f32_16x16x32_bf16(a[i][1], b[j][1], acc[4 + i][j], 0, 0, 0);
      }
    __builtin_amdgcn_s_setprio(0);
    if (t < G1_NT - 2)       asm volatile("s_waitcnt vmcnt(6)" ::: "memory");
    else if (t == G1_NT - 2) asm volatile("s_waitcnt vmcnt(0)" ::: "memory");
    __builtin_amdgcn_s_barrier();
    __builtin_amdgcn_sched_barrier(0);
  }

  const int quad = lane >> 4;
  const int cn = lane & 15;
#pragma unroll
  for (int i = 0; i < 8; i++)
#pragma unroll
    for (int j = 0; j < 4; j++) {
      int col = bn + wn * 64 + j * 16 + cn;
      if (col < DPROJ) {
#pragma unroll
        for (int r = 0; r < 4; r++) {
          int row = bm + wm * 128 + i * 16 + quad * 4 + r;
          C[(size_t)row * DPROJ + col] = f2b(acc[i][j][r]);
        }
      }
    }
}

// ---------------- MFMA GEMM: C[m,n] = sum_k A[m,k]*B[n,k], bf16 in, f32 acc ----------------
// (used for the in_proj N-remainder)
template <typename TC>
__global__ __launch_bounds__(256) void gemm_mfma(
    const bf16* __restrict__ A, int lda,
    const bf16* __restrict__ B, int ldb,
    TC* __restrict__ C, int ldc,
    int N, int K, int gridM, int gridN, int swz) {
  __shared__ short As[128][32];
  __shared__ short Bs[128][32];
  int tid = threadIdx.x;
  int lane = tid & 63;
  int w = tid >> 6;            // wave 0..3
  int wr = w >> 1, wc = w & 1; // 2x2 wave grid
  int bid = blockIdx.x;
  int bm, bn;
  if (swz) {
    int mst = gridM >> 3;
    int xk = bid & 7, q = bid >> 3;
    bm = (xk + 8 * (q % mst)) * 128;
    bn = (q / mst) * 128;
  } else {
    bm = (bid / gridN) * 128;
    bn = (bid % gridN) * 128;
  }
  f32x4v acc[4][4];
#pragma unroll
  for (int i = 0; i < 4; i++)
#pragma unroll
    for (int j = 0; j < 4; j++) acc[i][j] = (f32x4v){0.f, 0.f, 0.f, 0.f};

  const bf16* Ab = A + (size_t)(bm + w * 32 + (lane >> 2)) * lda + (lane & 3) * 8;
  const bf16* Bb = B + (size_t)(bn + w * 32 + (lane >> 2)) * ldb + (lane & 3) * 8;

  for (int k0 = 0; k0 < K; k0 += 32) {
    __builtin_amdgcn_global_load_lds(
        (const __attribute__((address_space(1))) void*)(Ab + k0),
        (__attribute__((address_space(3))) void*)&As[w * 32][0], 16, 0, 0);
    __builtin_amdgcn_global_load_lds(
        (const __attribute__((address_space(1))) void*)(Ab + (size_t)16 * lda + k0),
        (__attribute__((address_space(3))) void*)&As[w * 32 + 16][0], 16, 0, 0);
    __builtin_amdgcn_global_load_lds(
        (const __attribute__((address_space(1))) void*)(Bb + k0),
        (__attribute__((address_space(3))) void*)&Bs[w * 32][0], 16, 0, 0);
    __builtin_amdgcn_global_load_lds(
        (const __attribute__((address_space(1))) void*)(Bb + (size_t)16 * ldb + k0),
        (__attribute__((address_space(3))) void*)&Bs[w * 32 + 16][0], 16, 0, 0);
    __syncthreads();
    bf16x8v af[4], bv[4];
#pragma unroll
    for (int i = 0; i < 4; i++)
      af[i] = *(const bf16x8v*)&As[wr * 64 + i * 16 + (lane & 15)][(lane >> 4) * 8];
#pragma unroll
    for (int j = 0; j < 4; j++)
      bv[j] = *(const bf16x8v*)&Bs[wc * 64 + j * 16 + (lane & 15)][(lane >> 4) * 8];
#pragma unroll
    for (int i = 0; i < 4; i++)
#pragma unroll
      for (int j = 0; j < 4; j++)
        acc[i][j] = __builtin_amdgcn_mfma_f32_16x16x32_bf16(af[i], bv[j], acc[i][j], 0, 0, 0);
    __syncthreads();
  }
  int quad = lane >> 4;
  int cn = lane & 15;
#pragma unroll
  for (int i = 0; i < 4; i++) {
#pragma unroll
    for (int j = 0; j < 4; j++) {
      int col = bn + wc * 64 + j * 16 + cn;
      if (col < N) {
#pragma unroll
        for (int r = 0; r < 4; r++) {
          int row = bm + wr * 64 + i * 16 + quad * 4 + r;
          float v = acc[i][j][r];
          if constexpr (sizeof(TC) == 2) C[(size_t)row * ldc + col] = f2b(v);
          else                           C[(size_t)row * ldc + col] = v;
        }
      }
    }
  }
}

// ---------------- out_proj split-K=2: 512 blocks (2/CU, 2 waves/SIMD) ----------------
__global__ __launch_bounds__(256) void outproj_ks(
    const bf16* __restrict__ A, const bf16* __restrict__ B,
    float* __restrict__ C0, float* __restrict__ C1) {
  __shared__ short As[128][32];
  __shared__ short Bs[128][32];
  int tid = threadIdx.x;
  int lane = tid & 63;
  int w = tid >> 6;
  int wr = w >> 1, wc = w & 1;
  int bid = blockIdx.x;
  int ks = bid >> 8;            // 0/1 K-half
  int q = bid & 255;
  int xk = q & 7, qq = q >> 3;
  int bm = (xk + 8 * (qq & 3)) * 128;   // 32 m-tiles
  int bn = (qq >> 2) * 128;             // 8 n-tiles
  float* C = ks ? C1 : C0;
  f32x4v acc[4][4];
#pragma unroll
  for (int i = 0; i < 4; i++)
#pragma unroll
    for (int j = 0; j < 4; j++) acc[i][j] = (f32x4v){0.f, 0.f, 0.f, 0.f};

  const bf16* Ab = A + (size_t)(bm + w * 32 + (lane >> 2)) * DINNER + ks * 1024 + (lane & 3) * 8;
  const bf16* Bb = B + (size_t)(bn + w * 32 + (lane >> 2)) * DINNER + ks * 1024 + (lane & 3) * 8;

  for (int k0 = 0; k0 < 1024; k0 += 32) {
    __builtin_amdgcn_global_load_lds(
        (const __attribute__((address_space(1))) void*)(Ab + k0),
        (__attribute__((address_space(3))) void*)&As[w * 32][0], 16, 0, 0);
    __builtin_amdgcn_global_load_lds(
        (const __attribute__((address_space(1))) void*)(Ab + (size_t)16 * DINNER + k0),
        (__attribute__((address_space(3))) void*)&As[w * 32 + 16][0], 16, 0, 0);
    __builtin_amdgcn_global_load_lds(
        (const __attribute__((address_space(1))) void*)(Bb + k0),
        (__attribute__((address_space(3))) void*)&Bs[w * 32][0], 16, 0, 0);
    __builtin_amdgcn_global_load_lds(
        (const __attribute__((address_space(1))) void*)(Bb + (size_t)16 * DINNER + k0),
        (__attribute__((address_space(3))) void*)&Bs[w * 32 + 16][0], 16, 0, 0);
    __syncthreads();
    bf16x8v af[4], bv[4];
#pragma unroll
    for (int i = 0; i < 4; i++)
      af[i] = *(const bf16x8v*)&As[wr * 64 + i * 16 + (lane & 15)][(lane >> 4) * 8];
#pragma unroll
    for (int j = 0; j < 4; j++)
      bv[j] = *(const bf16x8v*)&Bs[wc * 64 + j * 16 + (lane & 15)][(lane >> 4) * 8];
#pragma unroll
    for (int i = 0; i < 4; i++)
#pragma unroll
      for (int j = 0; j < 4; j++)
        acc[i][j] = __builtin_amdgcn_mfma_f32_16x16x32_bf16(af[i], bv[j], acc[i][j], 0, 0, 0);
    __syncthreads();
  }
  int quad = lane >> 4;
  int cn = lane & 15;
#pragma unroll
  for (int i = 0; i < 4; i++)
#pragma unroll
    for (int j = 0; j < 4; j++) {
      int col = bn + wc * 64 + j * 16 + cn;
#pragma unroll
      for (int r = 0; r < 4; r++) {
        int row = bm + wr * 64 + i * 16 + quad * 4 + r;
        C[(size_t)row * DMODEL + col] = acc[i][j][r];
      }
    }
}

// ---------------- out += P1 (vectorized) ----------------
__global__ __launch_bounds__(256) void add_kernel(
    float* __restrict__ out, const float* __restrict__ P) {
  int i = (blockIdx.x * 256 + threadIdx.x) * 4;
  float4 a = *(const float4*)&out[i];
  float4 b = *(const float4*)&P[i];
  a.x += b.x; a.y += b.y; a.z += b.z; a.w += b.w;
  *(float4*)&out[i] = a;
}

// ---------------- fc via MFMA split-K=16 ----------------
#define FC_KS 16
__global__ __launch_bounds__(256) void fc_mfma(
    const bf16* __restrict__ xbc, const bf16* __restrict__ Wb,
    float* __restrict__ fdp) {
  __shared__ short As[128][32];
  __shared__ short Bs[32][32];
  int tid = threadIdx.x;
  int lane = tid & 63;
  int w = tid >> 6;
  int bid = blockIdx.x;
  int ks = bid & (FC_KS - 1);
  int bm = (bid / FC_KS) * 128;
  f32x4v acc[2][2];
#pragma unroll
  for (int i = 0; i < 2; i++)
#pragma unroll
    for (int j = 0; j < 2; j++) acc[i][j] = (f32x4v){0.f, 0.f, 0.f, 0.f};

  const bf16* Ab = xbc + (size_t)(bm + w * 32 + (lane >> 2)) * CONVDIM + ks * 128 + (lane & 3) * 8;
  const bf16* Bb = Wb + (size_t)(lane >> 2) * DINNER + ks * 128 + (lane & 3) * 8;

  for (int k0 = 0; k0 < 128; k0 += 32) {
    __builtin_amdgcn_global_load_lds(
        (const __attribute__((address_space(1))) void*)(Ab + k0),
        (__attribute__((address_space(3))) void*)&As[w * 32][0], 16, 0, 0);
    __builtin_amdgcn_global_load_lds(
        (const __attribute__((address_space(1))) void*)(Ab + (size_t)16 * CONVDIM + k0),
        (__attribute__((address_space(3))) void*)&As[w * 32 + 16][0], 16, 0, 0);
    if (w == 0) {
      __builtin_amdgcn_global_load_lds(
          (const __attribute__((address_space(1))) void*)(Bb + k0),
          (__attribute__((address_space(3))) void*)&Bs[0][0], 16, 0, 0);
      __builtin_amdgcn_global_load_lds(
          (const __attribute__((address_space(1))) void*)(Bb + (size_t)16 * DINNER + k0),
          (__attribute__((address_space(3))) void*)&Bs[16][0], 16, 0, 0);
    }
    __syncthreads();
    bf16x8v af[2], bv[2];
#pragma unroll
    for (int i = 0; i < 2; i++)
      af[i] = *(const bf16x8v*)&As[w * 32 + i * 16 + (lane & 15)][(lane >> 4) * 8];
#pragma unroll
    for (int j = 0; j < 2; j++)
      bv[j] = *(const bf16x8v*)&Bs[j * 16 + (lane & 15)][(lane >> 4) * 8];
#pragma unroll
    for (int i = 0; i < 2; i++)
#pragma unroll
      for (int j = 0; j < 2; j++)
        acc[i][j] = __builtin_amdgcn_mfma_f32_16x16x32_bf16(af[i], bv[j], acc[i][j], 0, 0, 0);
    __syncthreads();
  }
  int quad = lane >> 4;
  int cn = lane & 15;
  float* outp = fdp + (size_t)ks * (L_SEQ * NHEADS);
#pragma unroll
  for (int i = 0; i < 2; i++)
#pragma unroll
    for (int j = 0; j < 2; j++)
#pragma unroll
      for (int r = 0; r < 4; r++) {
        int row = bm + w * 32 + i * 16 + quad * 4 + r;
        int col = j * 16 + cn;
        outp[(size_t)row * NHEADS + col] = acc[i][j][r];
      }
}

__global__ __launch_bounds__(256) void fc_reduce(
    const float* __restrict__ fdp, const float* __restrict__ Dp,
    float* __restrict__ fd) {
  int i = blockIdx.x * 256 + threadIdx.x;   // L_SEQ*NHEADS
  float s = Dp[i & (NHEADS - 1)];
#pragma unroll
  for (int ks = 0; ks < FC_KS; ks++) s += fdp[(size_t)ks * (L_SEQ * NHEADS) + i];
  fd[i] = s;
}

// ---------------- conv (4 t/thread) + SiLU, with dt softplus folded in ----------------
#define CONV_BLOCKS ((L_SEQ / 4) * CONVDIM / 256)   // 10240
__global__ __launch_bounds__(256) void conv_dt_kernel(
    const bf16* __restrict__ zx, const float* __restrict__ conv_w,
    const float* __restrict__ conv_b, bf16* __restrict__ xbc,
    const float* __restrict__ dt_bias, float* __restrict__ dt2) {
  int bid = blockIdx.x;
  if (bid < CONV_BLOCKS) {
    int idx = bid * 256 + threadIdx.x;
    int ch = idx % CONVDIM;
    int t0 = (idx / CONVDIM) * 4;
    const bf16* col = zx + DINNER + ch;
    float w0 = conv_w[ch * 4 + 0], w1 = conv_w[ch * 4 + 1];
    float w2 = conv_w[ch * 4 + 2], w3 = conv_w[ch * 4 + 3];
    float bsv = conv_b[ch];
    float x[7];
#pragma unroll
    for (int i = 0; i < 7; i++) {
      int t = t0 - 3 + i;
      x[i] = (t >= 0) ? b2f(col[(size_t)t * DPROJ]) : 0.f;
    }
#pragma unroll
    for (int j = 0; j < 4; j++) {
      float acc = bsv + w0 * x[j] + w1 * x[j + 1] + w2 * x[j + 2] + w3 * x[j + 3];
      xbc[(size_t)(t0 + j) * CONVDIM + ch] = f2b(acc / (1.f + __expf(-acc)));
    }
  } else {
    int idx = (bid - CONV_BLOCKS) * 256 + threadIdx.x;   // 2*L_SEQ*NHEADS
    int h = idx % NHEADS;
    int t = (idx / NHEADS) % L_SEQ;
    int b = idx / (NHEADS * L_SEQ);
    float v;
    if (b == 0) v = b2f(zx[(size_t)t * DPROJ + 4608 + h]);
    else        v = b2f(zx[(size_t)(L_SEQ - 1 - t) * DPROJ + 4608 + NHEADS + h]);
    v += dt_bias[h];
    dt2[idx] = (v > 20.f) ? v : log1pf(expf(v));
  }
}

// ---------------- G[b,c,l,s] = sum_n C[l,n]*B[s,n]  (MFMA, quarter-split) ----------------
__global__ __launch_bounds__(256) void gmat_kernel(
    const bf16* __restrict__ xbc, bf16* __restrict__ G) {
  __shared__ bf16 Cs[32][136];   // C[l0+l][n]  8.5 KB
  __shared__ bf16 Bs[128][136];  // B[s][n]     34 KB
  int blk = blockIdx.x;          // (b*32+c)*4 + quarter
  int quarter = blk & 3;
  int bc = blk >> 2;
  int b = bc / NCHUNK, c = bc % NCHUNK;
  int l0 = quarter * 32;
  int tid = threadIdx.x;
  int lane = tid & 63;
  int w = tid >> 6;
  int bofs = b ? 2304 : 2048;
  int cofs = b ? 2432 : 2176;
  for (int o = tid; o < CHUNKL * DSTATE / 8; o += 256) {   // 2048 vecs
    int s = o >> 4;
    int n8 = (o & 15) * 8;
    int t = b ? (L_SEQ - 1 - (c * CHUNKL + s)) : (c * CHUNKL + s);
    *(bf16x8v*)&Bs[s][n8] = *(const bf16x8v*)&xbc[(size_t)t * CONVDIM + bofs + n8];
  }
  for (int o = tid; o < 32 * DSTATE / 8; o += 256) {       // 512 vecs
    int l = o >> 4;
    int n8 = (o & 15) * 8;
    int t = b ? (L_SEQ - 1 - (c * CHUNKL + l0 + l)) : (c * CHUNKL + l0 + l);
    *(bf16x8v*)&Cs[l][n8] = *(const bf16x8v*)&xbc[(size_t)t * CONVDIM + cofs + n8];
  }
  __syncthreads();
  if (w > quarter) return;   // s-tiles 2w,2w+1 start at s=32w > l0+31: masked at use
  f32x4v acc[2][2];
#pragma unroll
  for (int i = 0; i < 2; i++)
#pragma unroll
    for (int j = 0; j < 2; j++) acc[i][j] = (f32x4v){0.f, 0.f, 0.f, 0.f};
#pragma unroll
  for (int k0 = 0; k0 < 128; k0 += 32) {
    bf16x8v a0 = *(const bf16x8v*)&Cs[(lane & 15)][(lane >> 4) * 8 + k0];
    bf16x8v a1 = *(const bf16x8v*)&Cs[16 + (lane & 15)][(lane >> 4) * 8 + k0];
#pragma unroll
    for (int j = 0; j < 2; j++) {
      bf16x8v bv = *(const bf16x8v*)&Bs[(2 * w + j) * 16 + (lane & 15)][(lane >> 4) * 8 + k0];
      acc[0][j] = __builtin_amdgcn_mfma_f32_16x16x32_bf16(a0, bv, acc[0][j], 0, 0, 0);
      acc[1][j] = __builtin_amdgcn_mfma_f32_16x16x32_bf16(a1, bv, acc[1][j], 0, 0, 0);
    }
  }
  int quad = lane >> 4, cn = lane & 15;
  bf16* Gb = G + (size_t)bc * CHUNKL * CHUNKL;
#pragma unroll
  for (int i = 0; i < 2; i++)
#pragma unroll
    for (int j = 0; j < 2; j++)
#pragma unroll
      for (int r = 0; r < 4; r++) {
        int l = l0 + i * 16 + quad * 4 + r;
        int s = (2 * w + j) * 16 + cn;
        Gb[l * CHUNKL + s] = f2b(acc[i][j][r]);
      }
}

// ---------------- per-(b,c,h): chunk states only (MFMA, bf16 out) ----------------
// R11: wave-parallel shfl_up scan; csum by lane 63.
__global__ __launch_bounds__(256) void chunk_kernel(
    const bf16* __restrict__ xbc, const float* __restrict__ dt2,
    const float* __restrict__ A_log,
    bf16* __restrict__ states, float* __restrict__ csum) {
  int gid = blockIdx.x;           // (b*32+c)*32 + h
  int h = gid % NHEADS;
  int bc = gid / NHEADS;
  int c = bc % NCHUNK, b = bc / NCHUNK;
  int tid = threadIdx.x;
  int lane = tid & 63;
  int w = tid >> 6;
  __shared__ bf16 BdT[128][136];  // [n][l] = B[l][n]*decay[l]  34 KB
  __shared__ bf16 xdtT[64][136];  // [p][s] = x[s,p]*dt[s]      17 KB
  __shared__ float acs[CHUNKL];
  __shared__ float dtl[CHUNKL];
  __shared__ float decays[CHUNKL];
  if (tid < CHUNKL)
    dtl[tid] = dt2[((size_t)b * L_SEQ + c * CHUNKL + tid) * NHEADS + h];
  __syncthreads();
  if (tid < 64) {
    float Ah = -__expf(A_log[h]);
    float v0 = Ah * dtl[2 * tid];
    float v1 = Ah * dtl[2 * tid + 1];
    float s = v0 + v1;
#pragma unroll
    for (int off = 1; off < 64; off <<= 1) {
      float t = __shfl_up(s, off);
      if (tid >= off) s += t;
    }
    acs[2 * tid]     = s - v1;
    acs[2 * tid + 1] = s;
    if (tid == 63) csum[gid] = __expf(s);   // pre-exponentiated total for scan
  }
  __syncthreads();
  if (tid < CHUNKL) decays[tid] = __expf(acs[CHUNKL - 1] - acs[tid]);
  // xdtT[p][s] staging: lane->s (t-strided 16B loads), conflict-free scatter
  for (int o = tid; o < CHUNKL * HEADDIM / 8; o += 256) {   // 1024 vecs
    int s = o & 127;
    int p8 = (o >> 7) * 8;
    int t = b ? (L_SEQ - 1 - (c * CHUNKL + s)) : (c * CHUNKL + s);
    bf16x8v xv = *(const bf16x8v*)&xbc[(size_t)t * CONVDIM + h * HEADDIM + p8];
    float d = dtl[s];
#pragma unroll
    for (int j = 0; j < 8; j++) xdtT[p8 + j][s] = f2b(sh2f(xv[j]) * d);
  }
  __syncthreads();   // decays ready
  // BdT[n][l] staging: lane->l, conflict-free scatter
  for (int o = tid; o < CHUNKL * CHUNKL / 8; o += 256) {    // 2048 vecs
    int l = o & 127;
    int n8 = (o >> 7) * 8;
    int t = b ? (L_SEQ - 1 - (c * CHUNKL + l)) : (c * CHUNKL + l);
    bf16x8v bv = *(const bf16x8v*)&xbc[(size_t)t * CONVDIM + (b ? 2304 : 2048) + n8];
    float d = decays[l];
#pragma unroll
    for (int j = 0; j < 8; j++) BdT[n8 + j][l] = f2b(sh2f(bv[j]) * d);
  }
  __syncthreads();
  // states[p][n] = sum_l xdtT[p][l]*BdT[n][l]; wave w -> p rows [16w,16w+16)
  f32x4v accS[8];
#pragma unroll
  for (int j = 0; j < 8; j++) accS[j] = (f32x4v){0.f, 0.f, 0.f, 0.f};
#pragma unroll
  for (int k0 = 0; k0 < 128; k0 += 32) {
    bf16x8v av = *(const bf16x8v*)&xdtT[w * 16 + (lane & 15)][(lane >> 4) * 8 + k0];
#pragma unroll
    for (int j = 0; j < 8; j++) {
      bf16x8v bv = *(const bf16x8v*)&BdT[j * 16 + (lane & 15)][(lane >> 4) * 8 + k0];
      accS[j] = __builtin_amdgcn_mfma_f32_16x16x32_bf16(av, bv, accS[j], 0, 0, 0);
    }
  }
  int quad = lane >> 4, cn = lane & 15;
  bf16* st = states + (size_t)gid * (HEADDIM * DSTATE);
#pragma unroll
  for (int j = 0; j < 8; j++)
#pragma unroll
    for (int r = 0; r < 4; r++) {
      int p = w * 16 + quad * 4 + r;
      int n = j * 16 + cn;
      st[p * DSTATE + n] = f2b(accS[j][r]);
    }
}

// ---------------- inter-chunk scan: register-batched (independent loads first) --------
__global__ __launch_bounds__(256) void scan_kernel(
    bf16* __restrict__ states, const float* __restrict__ csum) {
  int idx = blockIdx.x * 256 + threadIdx.x;  // 2*NHEADS*HEADDIM*DSTATE
  int n = idx % DSTATE;
  int p = (idx / DSTATE) % HEADDIM;
  int h = (idx / (DSTATE * HEADDIM)) % NHEADS;
  int b = idx / (DSTATE * HEADDIM * NHEADS);
  size_t base = ((size_t)(b * NCHUNK) * NHEADS + h) * (HEADDIM * DSTATE) + p * DSTATE + n;
  const size_t cstride = (size_t)NHEADS * HEADDIM * DSTATE;
  float tmp[NCHUNK], cv[NCHUNK];
#pragma unroll
  for (int c = 0; c < NCHUNK; c++) tmp[c] = b2f(states[base + c * cstride]);
#pragma unroll
  for (int c = 0; c < NCHUNK; c++) cv[c] = csum[(b * NCHUNK + c) * NHEADS + h];
  float S = 0.f;
#pragma unroll
  for (int c = 0; c < NCHUNK; c++) {
    states[base + c * cstride] = f2b(S);
    S = cv[c] * S + tmp[c];
  }
}

// ---------------- fused Y = Y_diag + Y_off + D*x (MFMA, single bf16 write) ----------------
// R12: 512 threads (8 waves) on the SAME single block per (b,c,h) -- the corrected
// R7 lesson: more waves with ZERO extra traffic. LDS unchanged (53.8 KB -> still
// 2 blocks/CU) but 16 waves/CU (4/SIMD, 2x R11); per-thread staging iterations
// halve; each wave owns ONE 16-row group (total MFMA identical; tri-skip via
// k0 > 16w+15 keeps the same 80-MFMA Y_diag). Keeps T14 preloads + setprio.
__global__ __launch_bounds__(512, 4) void yoff_kernel(
    const bf16* __restrict__ xbc, const float* __restrict__ dt2,
    const float* __restrict__ A_log, const bf16* __restrict__ G,
    const bf16* __restrict__ states, const float* __restrict__ Dp,
    bf16* __restrict__ Y) {
  int gid = blockIdx.x;
  int h = gid % NHEADS;
  int bc = gid / NHEADS;
  int c = bc % NCHUNK, b = bc / NCHUNK;
  int tid = threadIdx.x;
  int lane = tid & 63;
  int w = tid >> 6;               // 0..7 -> l rows [16w, 16w+16)
  __shared__ bf16 WB[128][136];   // 34 KB (W, then Ce)
  __shared__ bf16 SX[64][136];    // 17 KB (xdtT, then St)
  __shared__ float acs[CHUNKL];
  __shared__ float dtl[CHUNKL];
  __shared__ float eAl[CHUNKL];
  if (tid < CHUNKL)
    dtl[tid] = dt2[((size_t)b * L_SEQ + c * CHUNKL + tid) * NHEADS + h];
  __syncthreads();
  // wave-parallel inclusive scan of Ah*dtl (128 elems, 2/lane, wave 0 only)
  if (tid < 64) {
    float Ah = -__expf(A_log[h]);
    float v0 = Ah * dtl[2 * tid];
    float v1 = Ah * dtl[2 * tid + 1];
    float s = v0 + v1;
#pragma unroll
    for (int off = 1; off < 64; off <<= 1) {
      float t = __shfl_up(s, off);
      if (tid >= off) s += t;
    }
    acs[2 * tid]     = s - v1;
    acs[2 * tid + 1] = s;
  }
  __syncthreads();
  if (tid < CHUNKL) eAl[tid] = __expf(acs[tid]);   // <= 1
  // T14: issue Ce + St + epilogue-x global loads NOW; consumed after GEMM1/2.
  bf16x8v ce_r[4], st_r[2];
  float xe[4][4];
  {
    int cofs = b ? 2432 : 2176;
#pragma unroll
    for (int it = 0; it < 4; it++) {
      int o = tid + it * 512;
      int l = o >> 4;
      int n8 = (o & 15) * 8;
      int t = b ? (L_SEQ - 1 - (c * CHUNKL + l)) : (c * CHUNKL + l);
      ce_r[it] = *(const bf16x8v*)&xbc[(size_t)t * CONVDIM + cofs + n8];
    }
    const bf16* stp = states + (size_t)gid * (HEADDIM * DSTATE);
#pragma unroll
    for (int it = 0; it < 2; it++) {
      int o = tid + it * 512;
      st_r[it] = *(const bf16x8v*)&stp[o * 8];
    }
    int quad0 = lane >> 4, cn0 = lane & 15;
#pragma unroll
    for (int j = 0; j < 4; j++)
#pragma unroll
      for (int r = 0; r < 4; r++) {
        int l = w * 16 + quad0 * 4 + r;
        int p = j * 16 + cn0;
        int t = b ? (L_SEQ - 1 - (c * CHUNKL + l)) : (c * CHUNKL + l);
        xe[j][r] = b2f(xbc[(size_t)t * CONVDIM + h * HEADDIM + p]);
      }
  }
  // SX <- xdtT[p][s]: lane->s, conflict-free scatter (2 iters @ 512 thr)
  for (int o = tid; o < CHUNKL * HEADDIM / 8; o += 512) {   // 1024 vecs
    int s = o & 127;
    int p8 = (o >> 7) * 8;
    int t = b ? (L_SEQ - 1 - (c * CHUNKL + s)) : (c * CHUNKL + s);
    bf16x8v xv = *(const bf16x8v*)&xbc[(size_t)t * CONVDIM + h * HEADDIM + p8];
    float d = dtl[s];
#pragma unroll
    for (int j = 0; j < 8; j++) SX[p8 + j][s] = f2b(sh2f(xv[j]) * d);
  }
  // WB <- W[l][s] = G*exp(acs[l]-acs[s]) (s<=l): b128 writes; upper-tri vecs
  // (s8 > l) skip the G load and expf entirely. (4 iters @ 512 thr)
  {
    const bf16* Gb = G + (size_t)bc * CHUNKL * CHUNKL;
    for (int o = tid; o < CHUNKL * CHUNKL / 8; o += 512) {  // 2048 vecs
      int l = o >> 4;
      int s8 = (o & 15) * 8;
      bf16x8v wv;
      if (s8 > l) {
#pragma unroll
        for (int j = 0; j < 8; j++) wv[j] = 0;
      } else {
        bf16x8v g = *(const bf16x8v*)&Gb[l * CHUNKL + s8];
        float al = acs[l];
#pragma unroll
        for (int j = 0; j < 8; j++) {
          int s = s8 + j;
          float e = (s <= l) ? sh2f(g[j]) * __expf(al - acs[s]) : 0.f;
          wv[j] = f2bs(e);
        }
      }
      *(bf16x8v*)&WB[l][s8] = wv;
    }
  }
  __syncthreads();
  f32x4v accY[4];
#pragma unroll
  for (int j = 0; j < 4; j++) accY[j] = (f32x4v){0.f, 0.f, 0.f, 0.f};
  // Y_diag: A=W rows [16w,16w+16), B=xdtT p-tiles, k=s.
  // Wave-uniform skip: k0 > 16w+15 => A block all-zero (strict upper triangle).
  __builtin_amdgcn_s_setprio(1);
#pragma unroll
  for (int k0 = 0; k0 < 128; k0 += 32) {
    if (k0 > w * 16 + 15) break;
    bf16x8v a0 = *(const bf16x8v*)&WB[w * 16 + (lane & 15)][(lane >> 4) * 8 + k0];
#pragma unroll
    for (int j = 0; j < 4; j++) {
      bf16x8v bv = *(const bf16x8v*)&SX[j * 16 + (lane & 15)][(lane >> 4) * 8 + k0];
      accY[j] = __builtin_amdgcn_mfma_f32_16x16x32_bf16(a0, bv, accY[j], 0, 0, 0);
    }
  }
  __builtin_amdgcn_s_setprio(0);
  __syncthreads();   // all phase-1 LDS reads done
  // restage from REGISTERS (global latency already hidden under GEMM1):
  // WB <- Ce*eAl, SX <- St
  {
#pragma unroll
    for (int it = 0; it < 4; it++) {
      int o = tid + it * 512;
      int l = o >> 4;
      int n8 = (o & 15) * 8;
      float e = eAl[l];
      bf16x8v ov;
#pragma unroll
      for (int j = 0; j < 8; j++) ov[j] = f2bs(sh2f(ce_r[it][j]) * e);
      *(bf16x8v*)&WB[l][n8] = ov;
    }
#pragma unroll
    for (int it = 0; it < 2; it++) {
      int o = tid + it * 512;
      int p = o >> 4;
      int n8 = (o & 15) * 8;
      *(bf16x8v*)&SX[p][n8] = st_r[it];
    }
  }
  __syncthreads();
  // Y_off: A=Ce rows [16w,16w+16), B=St p-tiles, k=n; accumulate into same accY
  __builtin_amdgcn_s_setprio(1);
#pragma unroll
  for (int k0 = 0; k0 < 128; k0 += 32) {
    bf16x8v a0 = *(const bf16x8v*)&WB[w * 16 + (lane & 15)][(lane >> 4) * 8 + k0];
#pragma unroll
    for (int j = 0; j < 4; j++) {
      bf16x8v bv = *(const bf16x8v*)&SX[j * 16 + (lane & 15)][(lane >> 4) * 8 + k0];
      accY[j] = __builtin_amdgcn_mfma_f32_16x16x32_bf16(a0, bv, accY[j], 0, 0, 0);
    }
  }
  __builtin_amdgcn_s_setprio(0);
  int quad = lane >> 4, cn = lane & 15;
  float Dh = Dp[h];
#pragma unroll
  for (int j = 0; j < 4; j++)
#pragma unroll
    for (int r = 0; r < 4; r++) {
      int l = w * 16 + quad * 4 + r;
      int p = j * 16 + cn;
      size_t yi = ((size_t)b * L_SEQ + c * CHUNKL + l) * DINNER + h * HEADDIM + p;
      Y[yi] = f2b(accY[j][r] + xe[j][r] * Dh);
    }
}

// ---------------- combine: shift, flip, +x*fd, gate, RMSNorm (vectorized) ----------------
__global__ __launch_bounds__(256) void combine_kernel(
    const bf16* __restrict__ Y, const bf16* __restrict__ xbc,
    const bf16* __restrict__ zx, const float* __restrict__ fd,
    const float* __restrict__ norm_w, bf16* __restrict__ yn) {
  int t = blockIdx.x;
  int tid = threadIdx.x;
  int j8 = tid * 8;
  float yf[8], yb[8];
#pragma unroll
  for (int j = 0; j < 8; j++) { yf[j] = 0.f; yb[j] = 0.f; }
  if (t >= 1) {
    bf16x8v v = *(const bf16x8v*)&Y[(size_t)(t - 1) * DINNER + j8];
#pragma unroll
    for (int j = 0; j < 8; j++) yf[j] = sh2f(v[j]);
  }
  if (t <= L_SEQ - 2) {
    bf16x8v v = *(const bf16x8v*)&Y[((size_t)L_SEQ + (L_SEQ - 2 - t)) * DINNER + j8];
#pragma unroll
    for (int j = 0; j < 8; j++) yb[j] = sh2f(v[j]);
  }
  bf16x8v xogv = *(const bf16x8v*)&xbc[(size_t)t * CONVDIM + j8];
  bf16x8v zv = *(const bf16x8v*)&zx[(size_t)t * DPROJ + j8];
  float fdv = fd[t * NHEADS + (j8 >> 6)];
  float yg[8];
  float ss = 0.f;
#pragma unroll
  for (int j = 0; j < 8; j++) {
    float y = yf[j] + yb[j] + sh2f(xogv[j]) * fdv;
    float z = sh2f(zv[j]);
    float g = y * (z / (1.f + __expf(-z)));
    yg[j] = g;
    ss += g * g;
  }
#pragma unroll
  for (int off = 32; off > 0; off >>= 1) ss += __shfl_down(ss, off);
  __shared__ float red[4];
  if ((tid & 63) == 0) red[tid >> 6] = ss;
  __syncthreads();
  float tot = red[0] + red[1] + red[2] + red[3];
  float scale = rsqrtf(tot / (float)DINNER + 1e-5f);
  float4 nw0 = *(const float4*)&norm_w[j8];
  float4 nw1 = *(const float4*)&norm_w[j8 + 4];
  bf16x8v ov;
  ov[0] = f2bs(yg[0] * scale * nw0.x);
  ov[1] = f2bs(yg[1] * scale * nw0.y);
  ov[2] = f2bs(yg[2] * scale * nw0.z);
  ov[3] = f2bs(yg[3] * scale * nw0.w);
  ov[4] = f2bs(yg[4] * scale * nw1.x);
  ov[5] = f2bs(yg[5] * scale * nw1.y);
  ov[6] = f2bs(yg[6] * scale * nw1.z);
  ov[7] = f2bs(yg[7] * scale * nw1.w);
  *(bf16x8v*)&yn[(size_t)t * DINNER + j8] = ov;
}

// ---------------- launch ----------------
extern "C" void kernel_launch(void* const* d_in, const int* in_sizes, int n_in,
                              void* d_out, int out_size, void* d_ws, size_t ws_size,
                              hipStream_t stream) {
  const float* u         = (const float*)d_in[0];
  const float* in_proj_w = (const float*)d_in[1];
  const float* conv_w    = (const float*)d_in[2];
  const float* conv_b    = (const float*)d_in[3];
  const float* dt_bias   = (const float*)d_in[4];
  const float* A_log     = (const float*)d_in[5];
  const float* Dp        = (const float*)d_in[6];
  const float* fc_D_w    = (const float*)d_in[7];
  const float* norm_w    = (const float*)d_in[8];
  const float* out_proj_w= (const float*)d_in[9];
  float* out = (float*)d_out;

  char* base = (char*)d_ws;
  bf16*  zx  = (bf16*)base;  base += (size_t)L_SEQ * DPROJ * 2;                    // 38.3 MB
  bf16*  xbc = (bf16*)base;  base += (size_t)L_SEQ * CONVDIM * 2;                  // 21.0 MB
  float* dt2 = (float*)base; base += (size_t)2 * L_SEQ * NHEADS * 4;               //  1.0 MB
  bf16*  G   = (bf16*)base;  base += (size_t)2 * NCHUNK * CHUNKL * CHUNKL * 4;     //  4.2 MB region
  bf16*  Yb  = (bf16*)base;  base += (size_t)2 * L_SEQ * DINNER * 4;               // 67.1 MB region
  bf16*  stb = (bf16*)base;  base += (size_t)2 * NCHUNK * NHEADS * HEADDIM * DSTATE * 4; // 67.1 MB region
  float* cs  = (float*)base; base += (size_t)2 * NCHUNK * NHEADS * 4;              //  8 KB
  // aliases into dead regions:
  bf16*  u_bf   = (bf16*)Yb;                          // 8.4 MB   (Yb live only after yoff)
  bf16*  w1p_bf = (bf16*)((char*)Yb + 9437184);       // 9.7 MB   (in_proj_w padded to 4736 rows)
  bf16*  w2_bf  = (bf16*)G;                           // 4.2 MB   (G dead after yoff)
  bf16*  yn     = (bf16*)stb;                         // 16.8 MB  (stb dead after yoff)
  float* fd     = (float*)((char*)stb + 33554432);    //  0.5 MB  (32 MB offset)
  bf16*  wf_bf  = (bf16*)((char*)stb + 35651584);     //  128 KB  (34 MB offset)
  float* fdp    = (float*)((char*)stb + 37748736);    //  8 MB    (36 MB offset)
  float* p1     = (float*)Yb;                         // 16.8 MB  (Yb dead after combine)

  // 0. fused casts for MFMA gemm1 (w1 zero-padded to NPAD1 rows)
  cast2_kernel<<<(L_SEQ * DMODEL + NPAD1 * DMODEL) / 256, 256, 0, stream>>>(
      u, in_proj_w, u_bf, w1p_bf);
  // 1a. in_proj main: cols [0,4096) (8-phase 256^2, 256 blocks = exactly 1 round)
  gemm1_8ph<<<(L_SEQ / 256) * G1_GN, 512, 0, stream>>>(u_bf, w1p_bf, zx);
  // 1b. in_proj remainder: cols [4096,4672) (128^2 gemm, 160 blocks)
  gemm_mfma<bf16><<<(L_SEQ / 128) * ((NPAD1 - NSPLIT) / 128), 256, 0, stream>>>(
      u_bf, DMODEL, w1p_bf + (size_t)NSPLIT * DMODEL, DMODEL,
      zx + NSPLIT, DPROJ, DPROJ - NSPLIT, DMODEL,
      L_SEQ / 128, (NPAD1 - NSPLIT) / 128, 0);
  // 2. conv + silu + dt (fused)
  conv_dt_kernel<<<CONV_BLOCKS + (2 * L_SEQ * NHEADS) / 256, 256, 0, stream>>>(
      zx, conv_w, conv_b, xbc, dt_bias, dt2);
  // 3a. G = C B^T per (b,c), quarter-split (MFMA, bf16)
  gmat_kernel<<<2 * NCHUNK * 4, 256, 0, stream>>>(xbc, G);
  // 3b. chunk states (MFMA, bf16; wave-parallel scan)
  chunk_kernel<<<2 * NCHUNK * NHEADS, 256, 0, stream>>>(
      xbc, dt2, A_log, stb, cs);
  // 3c. inter-chunk scan (register-batched)
  scan_kernel<<<(2 * NHEADS * HEADDIM * DSTATE) / 256, 256, 0, stream>>>(stb, cs);
  // 3d. fused Y = Y_diag + Y_off + D*x (MFMA; 512 threads = 16 waves/CU)
  yoff_kernel<<<2 * NCHUNK * NHEADS, 512, 0, stream>>>(
      xbc, dt2, A_log, G, stb, Dp, Yb);
  // 4a. casts into dead regions: out_proj_w -> w2_bf (G), fc_D_w -> wf_bf (stb)
  cast_kernel<<<(DMODEL * DINNER + 255) / 256, 256, 0, stream>>>(
      out_proj_w, w2_bf, DMODEL * DINNER, DMODEL * DINNER);
  cast_kernel<<<(NHEADS * DINNER + 255) / 256, 256, 0, stream>>>(
      fc_D_w, wf_bf, NHEADS * DINNER, NHEADS * DINNER);
  // 4b. fd = x_og @ fc_D_w^T + D  (MFMA split-K=16: 512 blocks, then reduce)
  fc_mfma<<<(L_SEQ / 128) * FC_KS, 256, 0, stream>>>(xbc, wf_bf, fdp);
  fc_reduce<<<(L_SEQ * NHEADS) / 256, 256, 0, stream>>>(fdp, Dp, fd);
  // 5. combine + gate + RMSNorm
  combine_kernel<<<L_SEQ, 256, 0, stream>>>(Yb, xbc, zx, fd, norm_w, yn);
  // 6. out_proj split-K=2 (512 blocks = 2/CU) + add pass
  outproj_ks<<<512, 256, 0, stream>>>(yn, w2_bf, out, p1);
  add_kernel<<<(L_SEQ * DMODEL) / 1024, 256, 0, stream>>>(out, p1);
}

// Round 13
// 345.902 us; speedup vs baseline: 1.1713x; 1.0166x over previous
//
#include <hip/hip_runtime.h>
#include <hip/hip_bf16.h>
#include <math.h>

// ---------------- problem constants ----------------
#define L_SEQ   4096
#define DMODEL  1024
#define DINNER  2048
#define NHEADS  32
#define HEADDIM 64
#define DSTATE  128
#define NCHUNK  32
#define CHUNKL  128
#define CONVDIM 2560
#define DPROJ   4672   // 2*DINNER + 2*(2*DSTATE) + 2*NHEADS
#define NPAD1   4736   // DPROJ padded to multiple of 128 (for remainder gemm)
#define NSPLIT  4096   // cols [0,NSPLIT) via 8-phase 256^2 (256 blocks = 1 round);
                       // cols [NSPLIT,DPROJ) via 128^2 gemm (160 blocks)

typedef __hip_bfloat16 bf16;
__device__ __forceinline__ float b2f(bf16 x) { return __bfloat162float(x); }
__device__ __forceinline__ bf16 f2b(float x) { return __float2bfloat16(x); }
__device__ __forceinline__ float sh2f(short s) {
  return __uint_as_float(((unsigned int)(unsigned short)s) << 16);
}
__device__ __forceinline__ short f2bs(float x) {
  bf16 t = __float2bfloat16(x);
  return *reinterpret_cast<short*>(&t);
}

typedef __attribute__((ext_vector_type(8))) short bf16x8v;
typedef __attribute__((ext_vector_type(4))) float f32x4v;

// zxbcdt column layout: [0,2048) = z ; [2048,4608) = xBC ; [4608,4672) = dt raw
// xBC_conv channel layout: [0,2048) = x ; fw B = [2048,2176) C = [2176,2304)
//                          bw B = [2304,2432) C = [2432,2560)  (bw streams time-flipped)

// ---------------- fused casts: u -> bf16 and in_proj_w -> bf16 (zero-padded) ----------------
__global__ __launch_bounds__(256) void cast2_kernel(
    const float* __restrict__ u, const float* __restrict__ w1,
    bf16* __restrict__ u_bf, bf16* __restrict__ w1_bf) {
  const int NU = (L_SEQ * DMODEL) / 256;   // 16384 blocks
  int bid = blockIdx.x;
  if (bid < NU) {
    int i = bid * 256 + threadIdx.x;
    u_bf[i] = f2b(u[i]);
  } else {
    int i = (bid - NU) * 256 + threadIdx.x;
    w1_bf[i] = (i < DPROJ * DMODEL) ? f2b(w1[i]) : f2b(0.f);
  }
}

// ---------------- f32 -> bf16 cast ----------------
__global__ __launch_bounds__(256) void cast_kernel(
    const float* __restrict__ src, bf16* __restrict__ dst, int n_src, int n_tot) {
  int i = blockIdx.x * 256 + threadIdx.x;
  if (i < n_tot) dst[i] = (i < n_src) ? f2b(src[i]) : f2b(0.f);
}

// ================= in_proj main: 8-phase 256x256 GEMM (R1-verified body) =================
#define G1_K  1024
#define G1_GN 16            // N tiles of 256 covering [0,4096)
#define G1_NT (G1_K / 64)   // 16 K-tiles

__global__ __launch_bounds__(512, 2) void gemm1_8ph(
    const bf16* __restrict__ A, const bf16* __restrict__ B, bf16* __restrict__ C) {
  __shared__ bf16 Al[2][2][8192];   // [slot][half][subtiled 128x64]  64 KB
  __shared__ bf16 Bl[2][2][8192];   // 64 KB
  const int tid = threadIdx.x;
  const int lane = tid & 63;
  const int w = tid >> 6;        // 0..7
  const int wm = w >> 2;         // 0..1 -> C rows [wm*128, +128)
  const int wn = w & 3;          // 0..3 -> C cols [wn*64, +64)
  const int bm = (blockIdx.x / G1_GN) * 256;
  const int bn = (blockIdx.x % G1_GN) * 256;
  const int scol = ((lane & 3) ^ (((lane >> 5) & 1) << 1)) * 8;
  const int cin = ((lane >> 4) * 8) ^ (((lane >> 3) & 1) << 4);
  const int r16 = lane & 15;
  const bf16* Ag = A + (size_t)bm * G1_K;
  const bf16* Bg = B + (size_t)bn * G1_K;

  auto stage = [&](int mat, int tt, int hf) {
    const bf16* g = (mat ? Bg : Ag)
        + (size_t)(hf * 128 + (w >> 1) * 16 + (lane >> 2)) * G1_K
        + tt * 64 + (w & 1) * 32 + scol;
    bf16* d0 = mat ? &Bl[tt & 1][hf][0] : &Al[tt & 1][hf][0];
    __builtin_amdgcn_global_load_lds(
        (const __attribute__((address_space(1))) void*)g,
        (__attribute__((address_space(3))) void*)(d0 + w * 512), 16, 0, 0);
    __builtin_amdgcn_global_load_lds(
        (const __attribute__((address_space(1))) void*)(g + (size_t)64 * G1_K),
        (__attribute__((address_space(3))) void*)(d0 + (8 + w) * 512), 16, 0, 0);
  };

  f32x4v acc[8][4];
#pragma unroll
  for (int i = 0; i < 8; i++)
#pragma unroll
    for (int j = 0; j < 4; j++) acc[i][j] = (f32x4v){0.f, 0.f, 0.f, 0.f};

  stage(0, 0, 0); stage(0, 0, 1); stage(1, 0, 0); stage(1, 0, 1);
  stage(0, 1, 0); stage(0, 1, 1); stage(1, 1, 0);
  asm volatile("s_waitcnt vmcnt(6)" ::: "memory");
  __builtin_amdgcn_s_barrier();
  __builtin_amdgcn_sched_barrier(0);

#pragma unroll 2
  for (int t = 0; t < G1_NT; ++t) {
    const int slot = t & 1;
    const bf16* Ah = &Al[slot][wm][0];
    const bf16* Bh = &Bl[slot][wn >> 1][0];
    const int brb = (wn & 1) * 4;
    bf16x8v a[4][2], b[4][2];
    // ---- phase 0
#pragma unroll
    for (int i = 0; i < 4; i++) {
      a[i][0] = *(const bf16x8v*)&Ah[(i * 2 + 0) * 512 + r16 * 32 + cin];
      a[i][1] = *(const bf16x8v*)&Ah[(i * 2 + 1) * 512 + r16 * 32 + cin];
    }
#pragma unroll
    for (int j = 0; j < 2; j++) {
      b[j][0] = *(const bf16x8v*)&Bh[((brb + j) * 2 + 0) * 512 + r16 * 32 + cin];
      b[j][1] = *(const bf16x8v*)&Bh[((brb + j) * 2 + 1) * 512 + r16 * 32 + cin];
    }
    if (t + 1 < G1_NT) stage(1, t + 1, 1);
    __builtin_amdgcn_s_barrier();
    asm volatile("s_waitcnt lgkmcnt(0)" ::: "memory");
    __builtin_amdgcn_s_setprio(1);
#pragma unroll
    for (int i = 0; i < 4; i++)
#pragma unroll
      for (int j = 0; j < 2; j++) {
        acc[i][j] = __builtin_amdgcn_mfma_f32_16x16x32_bf16(a[i][0], b[j][0], acc[i][j], 0, 0, 0);
        acc[i][j] = __builtin_amdgcn_mfma_f32_16x16x32_bf16(a[i][1], b[j][1], acc[i][j], 0, 0, 0);
      }
    __builtin_amdgcn_s_setprio(0);
    __builtin_amdgcn_s_barrier();
    // ---- phase 1
#pragma unroll
    for (int j = 2; j < 4; j++) {
      b[j][0] = *(const bf16x8v*)&Bh[((brb + j) * 2 + 0) * 512 + r16 * 32 + cin];
      b[j][1] = *(const bf16x8v*)&Bh[((brb + j) * 2 + 1) * 512 + r16 * 32 + cin];
    }
    __builtin_amdgcn_s_barrier();
    asm volatile("s_waitcnt lgkmcnt(0)" ::: "memory");
    __builtin_amdgcn_s_setprio(1);
#pragma unroll
    for (int i = 0; i < 4; i++)
#pragma unroll
      for (int j = 2; j < 4; j++) {
        acc[i][j] = __builtin_amdgcn_mfma_f32_16x16x32_bf16(a[i][0], b[j][0], acc[i][j], 0, 0, 0);
        acc[i][j] = __builtin_amdgcn_mfma_f32_16x16x32_bf16(a[i][1], b[j][1], acc[i][j], 0, 0, 0);
      }
    __builtin_amdgcn_s_setprio(0);
    __builtin_amdgcn_s_barrier();
    // ---- phase 2
#pragma unroll
    for (int i = 0; i < 4; i++) {
      a[i][0] = *(const bf16x8v*)&Ah[((4 + i) * 2 + 0) * 512 + r16 * 32 + cin];
      a[i][1] = *(const bf16x8v*)&Ah[((4 + i) * 2 + 1) * 512 + r16 * 32 + cin];
    }
    if (t + 2 < G1_NT) stage(1, t + 2, 0);
    __builtin_amdgcn_s_barrier();
    asm volatile("s_waitcnt lgkmcnt(0)" ::: "memory");
    __builtin_amdgcn_s_setprio(1);
#pragma unroll
    for (int i = 0; i < 4; i++)
#pragma unroll
      for (int j = 2; j < 4; j++) {
        acc[4 + i][j] = __builtin_amdgcn_mfma_f32_16x16x32_bf16(a[i][0], b[j][0], acc[4 + i][j], 0, 0, 0);
        acc[4 + i][j] = __builtin_amdgcn_mfma_f32_16x16x32_bf16(a[i][1], b[j][1], acc[4 + i][j], 0, 0, 0);
      }
    __builtin_amdgcn_s_setprio(0);
    __builtin_amdgcn_s_barrier();
    // ---- phase 3
    if (t + 2 < G1_NT) { stage(0, t + 2, 0); stage(0, t + 2, 1); }
    __builtin_amdgcn_s_barrier();
    __builtin_amdgcn_s_setprio(1);
#pragma unroll
    for (int i = 0; i < 4; i++)
#pragma unroll
      for (int j = 0; j < 2; j++) {
        acc[4 + i][j] = __builtin_amdgcn_mfma_f32_16x16x32_bf16(a[i][0], b[j][0], acc[4 + i][j], 0, 0, 0);
        acc[4 + i][j] = __builtin_amdgcn_mfma_f32_16x16x32_bf16(a[i][1], b[j][1], acc[4 + i][j], 0, 0, 0);
      }
    __builtin_amdgcn_s_setprio(0);
    if (t < G1_NT - 2)       asm volatile("s_waitcnt vmcnt(6)" ::: "memory");
    else if (t == G1_NT - 2) asm volatile("s_waitcnt vmcnt(0)" ::: "memory");
    __builtin_amdgcn_s_barrier();
    __builtin_amdgcn_sched_barrier(0);
  }

  const int quad = lane >> 4;
  const int cn = lane & 15;
#pragma unroll
  for (int i = 0; i < 8; i++)
#pragma unroll
    for (int j = 0; j < 4; j++) {
      int col = bn + wn * 64 + j * 16 + cn;
      if (col < DPROJ) {
#pragma unroll
        for (int r = 0; r < 4; r++) {
          int row = bm + wm * 128 + i * 16 + quad * 4 + r;
          C[(size_t)row * DPROJ + col] = f2b(acc[i][j][r]);
        }
      }
    }
}

// ---------------- MFMA GEMM: C[m,n] = sum_k A[m,k]*B[n,k], bf16 in, f32 acc ----------------
// (used for the in_proj N-remainder)
template <typename TC>
__global__ __launch_bounds__(256) void gemm_mfma(
    const bf16* __restrict__ A, int lda,
    const bf16* __restrict__ B, int ldb,
    TC* __restrict__ C, int ldc,
    int N, int K, int gridM, int gridN, int swz) {
  __shared__ short As[128][32];
  __shared__ short Bs[128][32];
  int tid = threadIdx.x;
  int lane = tid & 63;
  int w = tid >> 6;            // wave 0..3
  int wr = w >> 1, wc = w & 1; // 2x2 wave grid
  int bid = blockIdx.x;
  int bm, bn;
  if (swz) {
    int mst = gridM >> 3;
    int xk = bid & 7, q = bid >> 3;
    bm = (xk + 8 * (q % mst)) * 128;
    bn = (q / mst) * 128;
  } else {
    bm = (bid / gridN) * 128;
    bn = (bid % gridN) * 128;
  }
  f32x4v acc[4][4];
#pragma unroll
  for (int i = 0; i < 4; i++)
#pragma unroll
    for (int j = 0; j < 4; j++) acc[i][j] = (f32x4v){0.f, 0.f, 0.f, 0.f};

  const bf16* Ab = A + (size_t)(bm + w * 32 + (lane >> 2)) * lda + (lane & 3) * 8;
  const bf16* Bb = B + (size_t)(bn + w * 32 + (lane >> 2)) * ldb + (lane & 3) * 8;

  for (int k0 = 0; k0 < K; k0 += 32) {
    __builtin_amdgcn_global_load_lds(
        (const __attribute__((address_space(1))) void*)(Ab + k0),
        (__attribute__((address_space(3))) void*)&As[w * 32][0], 16, 0, 0);
    __builtin_amdgcn_global_load_lds(
        (const __attribute__((address_space(1))) void*)(Ab + (size_t)16 * lda + k0),
        (__attribute__((address_space(3))) void*)&As[w * 32 + 16][0], 16, 0, 0);
    __builtin_amdgcn_global_load_lds(
        (const __attribute__((address_space(1))) void*)(Bb + k0),
        (__attribute__((address_space(3))) void*)&Bs[w * 32][0], 16, 0, 0);
    __builtin_amdgcn_global_load_lds(
        (const __attribute__((address_space(1))) void*)(Bb + (size_t)16 * ldb + k0),
        (__attribute__((address_space(3))) void*)&Bs[w * 32 + 16][0], 16, 0, 0);
    __syncthreads();
    bf16x8v af[4], bv[4];
#pragma unroll
    for (int i = 0; i < 4; i++)
      af[i] = *(const bf16x8v*)&As[wr * 64 + i * 16 + (lane & 15)][(lane >> 4) * 8];
#pragma unroll
    for (int j = 0; j < 4; j++)
      bv[j] = *(const bf16x8v*)&Bs[wc * 64 + j * 16 + (lane & 15)][(lane >> 4) * 8];
#pragma unroll
    for (int i = 0; i < 4; i++)
#pragma unroll
      for (int j = 0; j < 4; j++)
        acc[i][j] = __builtin_amdgcn_mfma_f32_16x16x32_bf16(af[i], bv[j], acc[i][j], 0, 0, 0);
    __syncthreads();
  }
  int quad = lane >> 4;
  int cn = lane & 15;
#pragma unroll
  for (int i = 0; i < 4; i++) {
#pragma unroll
    for (int j = 0; j < 4; j++) {
      int col = bn + wc * 64 + j * 16 + cn;
      if (col < N) {
#pragma unroll
        for (int r = 0; r < 4; r++) {
          int row = bm + wr * 64 + i * 16 + quad * 4 + r;
          float v = acc[i][j][r];
          if constexpr (sizeof(TC) == 2) C[(size_t)row * ldc + col] = f2b(v);
          else                           C[(size_t)row * ldc + col] = v;
        }
      }
    }
  }
}

// ---------------- out_proj split-K=2: 512 blocks (2/CU, 2 waves/SIMD) ----------------
__global__ __launch_bounds__(256) void outproj_ks(
    const bf16* __restrict__ A, const bf16* __restrict__ B,
    float* __restrict__ C0, float* __restrict__ C1) {
  __shared__ short As[128][32];
  __shared__ short Bs[128][32];
  int tid = threadIdx.x;
  int lane = tid & 63;
  int w = tid >> 6;
  int wr = w >> 1, wc = w & 1;
  int bid = blockIdx.x;
  int ks = bid >> 8;            // 0/1 K-half
  int q = bid & 255;
  int xk = q & 7, qq = q >> 3;
  int bm = (xk + 8 * (qq & 3)) * 128;   // 32 m-tiles
  int bn = (qq >> 2) * 128;             // 8 n-tiles
  float* C = ks ? C1 : C0;
  f32x4v acc[4][4];
#pragma unroll
  for (int i = 0; i < 4; i++)
#pragma unroll
    for (int j = 0; j < 4; j++) acc[i][j] = (f32x4v){0.f, 0.f, 0.f, 0.f};

  const bf16* Ab = A + (size_t)(bm + w * 32 + (lane >> 2)) * DINNER + ks * 1024 + (lane & 3) * 8;
  const bf16* Bb = B + (size_t)(bn + w * 32 + (lane >> 2)) * DINNER + ks * 1024 + (lane & 3) * 8;

  for (int k0 = 0; k0 < 1024; k0 += 32) {
    __builtin_amdgcn_global_load_lds(
        (const __attribute__((address_space(1))) void*)(Ab + k0),
        (__attribute__((address_space(3))) void*)&As[w * 32][0], 16, 0, 0);
    __builtin_amdgcn_global_load_lds(
        (const __attribute__((address_space(1))) void*)(Ab + (size_t)16 * DINNER + k0),
        (__attribute__((address_space(3))) void*)&As[w * 32 + 16][0], 16, 0, 0);
    __builtin_amdgcn_global_load_lds(
        (const __attribute__((address_space(1))) void*)(Bb + k0),
        (__attribute__((address_space(3))) void*)&Bs[w * 32][0], 16, 0, 0);
    __builtin_amdgcn_global_load_lds(
        (const __attribute__((address_space(1))) void*)(Bb + (size_t)16 * DINNER + k0),
        (__attribute__((address_space(3))) void*)&Bs[w * 32 + 16][0], 16, 0, 0);
    __syncthreads();
    bf16x8v af[4], bv[4];
#pragma unroll
    for (int i = 0; i < 4; i++)
      af[i] = *(const bf16x8v*)&As[wr * 64 + i * 16 + (lane & 15)][(lane >> 4) * 8];
#pragma unroll
    for (int j = 0; j < 4; j++)
      bv[j] = *(const bf16x8v*)&Bs[wc * 64 + j * 16 + (lane & 15)][(lane >> 4) * 8];
#pragma unroll
    for (int i = 0; i < 4; i++)
#pragma unroll
      for (int j = 0; j < 4; j++)
        acc[i][j] = __builtin_amdgcn_mfma_f32_16x16x32_bf16(af[i], bv[j], acc[i][j], 0, 0, 0);
    __syncthreads();
  }
  int quad = lane >> 4;
  int cn = lane & 15;
#pragma unroll
  for (int i = 0; i < 4; i++)
#pragma unroll
    for (int j = 0; j < 4; j++) {
      int col = bn + wc * 64 + j * 16 + cn;
#pragma unroll
      for (int r = 0; r < 4; r++) {
        int row = bm + wr * 64 + i * 16 + quad * 4 + r;
        C[(size_t)row * DMODEL + col] = acc[i][j][r];
      }
    }
}

// ---------------- out += P1 (vectorized) ----------------
__global__ __launch_bounds__(256) void add_kernel(
    float* __restrict__ out, const float* __restrict__ P) {
  int i = (blockIdx.x * 256 + threadIdx.x) * 4;
  float4 a = *(const float4*)&out[i];
  float4 b = *(const float4*)&P[i];
  a.x += b.x; a.y += b.y; a.z += b.z; a.w += b.w;
  *(float4*)&out[i] = a;
}

// ---------------- fc via MFMA split-K=16 ----------------
#define FC_KS 16
__global__ __launch_bounds__(256) void fc_mfma(
    const bf16* __restrict__ xbc, const bf16* __restrict__ Wb,
    float* __restrict__ fdp) {
  __shared__ short As[128][32];
  __shared__ short Bs[32][32];
  int tid = threadIdx.x;
  int lane = tid & 63;
  int w = tid >> 6;
  int bid = blockIdx.x;
  int ks = bid & (FC_KS - 1);
  int bm = (bid / FC_KS) * 128;
  f32x4v acc[2][2];
#pragma unroll
  for (int i = 0; i < 2; i++)
#pragma unroll
    for (int j = 0; j < 2; j++) acc[i][j] = (f32x4v){0.f, 0.f, 0.f, 0.f};

  const bf16* Ab = xbc + (size_t)(bm + w * 32 + (lane >> 2)) * CONVDIM + ks * 128 + (lane & 3) * 8;
  const bf16* Bb = Wb + (size_t)(lane >> 2) * DINNER + ks * 128 + (lane & 3) * 8;

  for (int k0 = 0; k0 < 128; k0 += 32) {
    __builtin_amdgcn_global_load_lds(
        (const __attribute__((address_space(1))) void*)(Ab + k0),
        (__attribute__((address_space(3))) void*)&As[w * 32][0], 16, 0, 0);
    __builtin_amdgcn_global_load_lds(
        (const __attribute__((address_space(1))) void*)(Ab + (size_t)16 * CONVDIM + k0),
        (__attribute__((address_space(3))) void*)&As[w * 32 + 16][0], 16, 0, 0);
    if (w == 0) {
      __builtin_amdgcn_global_load_lds(
          (const __attribute__((address_space(1))) void*)(Bb + k0),
          (__attribute__((address_space(3))) void*)&Bs[0][0], 16, 0, 0);
      __builtin_amdgcn_global_load_lds(
          (const __attribute__((address_space(1))) void*)(Bb + (size_t)16 * DINNER + k0),
          (__attribute__((address_space(3))) void*)&Bs[16][0], 16, 0, 0);
    }
    __syncthreads();
    bf16x8v af[2], bv[2];
#pragma unroll
    for (int i = 0; i < 2; i++)
      af[i] = *(const bf16x8v*)&As[w * 32 + i * 16 + (lane & 15)][(lane >> 4) * 8];
#pragma unroll
    for (int j = 0; j < 2; j++)
      bv[j] = *(const bf16x8v*)&Bs[j * 16 + (lane & 15)][(lane >> 4) * 8];
#pragma unroll
    for (int i = 0; i < 2; i++)
#pragma unroll
      for (int j = 0; j < 2; j++)
        acc[i][j] = __builtin_amdgcn_mfma_f32_16x16x32_bf16(af[i], bv[j], acc[i][j], 0, 0, 0);
    __syncthreads();
  }
  int quad = lane >> 4;
  int cn = lane & 15;
  float* outp = fdp + (size_t)ks * (L_SEQ * NHEADS);
#pragma unroll
  for (int i = 0; i < 2; i++)
#pragma unroll
    for (int j = 0; j < 2; j++)
#pragma unroll
      for (int r = 0; r < 4; r++) {
        int row = bm + w * 32 + i * 16 + quad * 4 + r;
        int col = j * 16 + cn;
        outp[(size_t)row * NHEADS + col] = acc[i][j][r];
      }
}

__global__ __launch_bounds__(256) void fc_reduce(
    const float* __restrict__ fdp, const float* __restrict__ Dp,
    float* __restrict__ fd) {
  int i = blockIdx.x * 256 + threadIdx.x;   // L_SEQ*NHEADS
  float s = Dp[i & (NHEADS - 1)];
#pragma unroll
  for (int ks = 0; ks < FC_KS; ks++) s += fdp[(size_t)ks * (L_SEQ * NHEADS) + i];
  fd[i] = s;
}

// ---------------- conv (4 t/thread) + SiLU, with dt softplus folded in ----------------
#define CONV_BLOCKS ((L_SEQ / 4) * CONVDIM / 256)   // 10240
__global__ __launch_bounds__(256) void conv_dt_kernel(
    const bf16* __restrict__ zx, const float* __restrict__ conv_w,
    const float* __restrict__ conv_b, bf16* __restrict__ xbc,
    const float* __restrict__ dt_bias, float* __restrict__ dt2) {
  int bid = blockIdx.x;
  if (bid < CONV_BLOCKS) {
    int idx = bid * 256 + threadIdx.x;
    int ch = idx % CONVDIM;
    int t0 = (idx / CONVDIM) * 4;
    const bf16* col = zx + DINNER + ch;
    float w0 = conv_w[ch * 4 + 0], w1 = conv_w[ch * 4 + 1];
    float w2 = conv_w[ch * 4 + 2], w3 = conv_w[ch * 4 + 3];
    float bsv = conv_b[ch];
    float x[7];
#pragma unroll
    for (int i = 0; i < 7; i++) {
      int t = t0 - 3 + i;
      x[i] = (t >= 0) ? b2f(col[(size_t)t * DPROJ]) : 0.f;
    }
#pragma unroll
    for (int j = 0; j < 4; j++) {
      float acc = bsv + w0 * x[j] + w1 * x[j + 1] + w2 * x[j + 2] + w3 * x[j + 3];
      xbc[(size_t)(t0 + j) * CONVDIM + ch] = f2b(acc / (1.f + __expf(-acc)));
    }
  } else {
    int idx = (bid - CONV_BLOCKS) * 256 + threadIdx.x;   // 2*L_SEQ*NHEADS
    int h = idx % NHEADS;
    int t = (idx / NHEADS) % L_SEQ;
    int b = idx / (NHEADS * L_SEQ);
    float v;
    if (b == 0) v = b2f(zx[(size_t)t * DPROJ + 4608 + h]);
    else        v = b2f(zx[(size_t)(L_SEQ - 1 - t) * DPROJ + 4608 + NHEADS + h]);
    v += dt_bias[h];
    dt2[idx] = (v > 20.f) ? v : log1pf(expf(v));
  }
}

// ---------------- G[b,c,l,s] = sum_n C[l,n]*B[s,n]  (MFMA, quarter-split) ----------------
__global__ __launch_bounds__(256) void gmat_kernel(
    const bf16* __restrict__ xbc, bf16* __restrict__ G) {
  __shared__ bf16 Cs[32][136];   // C[l0+l][n]  8.5 KB
  __shared__ bf16 Bs[128][136];  // B[s][n]     34 KB
  int blk = blockIdx.x;          // (b*32+c)*4 + quarter
  int quarter = blk & 3;
  int bc = blk >> 2;
  int b = bc / NCHUNK, c = bc % NCHUNK;
  int l0 = quarter * 32;
  int tid = threadIdx.x;
  int lane = tid & 63;
  int w = tid >> 6;
  int bofs = b ? 2304 : 2048;
  int cofs = b ? 2432 : 2176;
  for (int o = tid; o < CHUNKL * DSTATE / 8; o += 256) {   // 2048 vecs
    int s = o >> 4;
    int n8 = (o & 15) * 8;
    int t = b ? (L_SEQ - 1 - (c * CHUNKL + s)) : (c * CHUNKL + s);
    *(bf16x8v*)&Bs[s][n8] = *(const bf16x8v*)&xbc[(size_t)t * CONVDIM + bofs + n8];
  }
  for (int o = tid; o < 32 * DSTATE / 8; o += 256) {       // 512 vecs
    int l = o >> 4;
    int n8 = (o & 15) * 8;
    int t = b ? (L_SEQ - 1 - (c * CHUNKL + l0 + l)) : (c * CHUNKL + l0 + l);
    *(bf16x8v*)&Cs[l][n8] = *(const bf16x8v*)&xbc[(size_t)t * CONVDIM + cofs + n8];
  }
  __syncthreads();
  if (w > quarter) return;   // s-tiles 2w,2w+1 start at s=32w > l0+31: masked at use
  f32x4v acc[2][2];
#pragma unroll
  for (int i = 0; i < 2; i++)
#pragma unroll
    for (int j = 0; j < 2; j++) acc[i][j] = (f32x4v){0.f, 0.f, 0.f, 0.f};
#pragma unroll
  for (int k0 = 0; k0 < 128; k0 += 32) {
    bf16x8v a0 = *(const bf16x8v*)&Cs[(lane & 15)][(lane >> 4) * 8 + k0];
    bf16x8v a1 = *(const bf16x8v*)&Cs[16 + (lane & 15)][(lane >> 4) * 8 + k0];
#pragma unroll
    for (int j = 0; j < 2; j++) {
      bf16x8v bv = *(const bf16x8v*)&Bs[(2 * w + j) * 16 + (lane & 15)][(lane >> 4) * 8 + k0];
      acc[0][j] = __builtin_amdgcn_mfma_f32_16x16x32_bf16(a0, bv, acc[0][j], 0, 0, 0);
      acc[1][j] = __builtin_amdgcn_mfma_f32_16x16x32_bf16(a1, bv, acc[1][j], 0, 0, 0);
    }
  }
  int quad = lane >> 4, cn = lane & 15;
  bf16* Gb = G + (size_t)bc * CHUNKL * CHUNKL;
#pragma unroll
  for (int i = 0; i < 2; i++)
#pragma unroll
    for (int j = 0; j < 2; j++)
#pragma unroll
      for (int r = 0; r < 4; r++) {
        int l = l0 + i * 16 + quad * 4 + r;
        int s = (2 * w + j) * 16 + cn;
        Gb[l * CHUNKL + s] = f2b(acc[i][j][r]);
      }
}

// ---------------- per-(b,c,h): chunk states only (MFMA, bf16 out) ----------------
// R13: widened to 512 threads (8 waves) on the SAME single block -- the R12
// pattern: 2x waves/CU with ZERO extra traffic. Wave w -> p-tile (w&3),
// n-half (w>>2); 16 MFMA/wave (was 32); staging strides 256 -> 512.
__global__ __launch_bounds__(512, 4) void chunk_kernel(
    const bf16* __restrict__ xbc, const float* __restrict__ dt2,
    const float* __restrict__ A_log,
    bf16* __restrict__ states, float* __restrict__ csum) {
  int gid = blockIdx.x;           // (b*32+c)*32 + h
  int h = gid % NHEADS;
  int bc = gid / NHEADS;
  int c = bc % NCHUNK, b = bc / NCHUNK;
  int tid = threadIdx.x;
  int lane = tid & 63;
  int w = tid >> 6;               // 0..7
  int wp = w & 3;                 // p-tile [16wp, 16wp+16)
  int wn2 = w >> 2;               // n-half 0/1
  __shared__ bf16 BdT[128][136];  // [n][l] = B[l][n]*decay[l]  34 KB
  __shared__ bf16 xdtT[64][136];  // [p][s] = x[s,p]*dt[s]      17 KB
  __shared__ float acs[CHUNKL];
  __shared__ float dtl[CHUNKL];
  __shared__ float decays[CHUNKL];
  if (tid < CHUNKL)
    dtl[tid] = dt2[((size_t)b * L_SEQ + c * CHUNKL + tid) * NHEADS + h];
  __syncthreads();
  if (tid < 64) {
    float Ah = -__expf(A_log[h]);
    float v0 = Ah * dtl[2 * tid];
    float v1 = Ah * dtl[2 * tid + 1];
    float s = v0 + v1;
#pragma unroll
    for (int off = 1; off < 64; off <<= 1) {
      float t = __shfl_up(s, off);
      if (tid >= off) s += t;
    }
    acs[2 * tid]     = s - v1;
    acs[2 * tid + 1] = s;
    if (tid == 63) csum[gid] = __expf(s);   // pre-exponentiated total for scan
  }
  __syncthreads();
  if (tid < CHUNKL) decays[tid] = __expf(acs[CHUNKL - 1] - acs[tid]);
  // xdtT[p][s] staging: lane->s (t-strided 16B loads), conflict-free scatter
  for (int o = tid; o < CHUNKL * HEADDIM / 8; o += 512) {   // 1024 vecs, 2 iters
    int s = o & 127;
    int p8 = (o >> 7) * 8;
    int t = b ? (L_SEQ - 1 - (c * CHUNKL + s)) : (c * CHUNKL + s);
    bf16x8v xv = *(const bf16x8v*)&xbc[(size_t)t * CONVDIM + h * HEADDIM + p8];
    float d = dtl[s];
#pragma unroll
    for (int j = 0; j < 8; j++) xdtT[p8 + j][s] = f2b(sh2f(xv[j]) * d);
  }
  __syncthreads();   // decays ready
  // BdT[n][l] staging: lane->l, conflict-free scatter
  for (int o = tid; o < CHUNKL * CHUNKL / 8; o += 512) {    // 2048 vecs, 4 iters
    int l = o & 127;
    int n8 = (o >> 7) * 8;
    int t = b ? (L_SEQ - 1 - (c * CHUNKL + l)) : (c * CHUNKL + l);
    bf16x8v bv = *(const bf16x8v*)&xbc[(size_t)t * CONVDIM + (b ? 2304 : 2048) + n8];
    float d = decays[l];
#pragma unroll
    for (int j = 0; j < 8; j++) BdT[n8 + j][l] = f2b(sh2f(bv[j]) * d);
  }
  __syncthreads();
  // states[p][n] = sum_l xdtT[p][l]*BdT[n][l]; wave -> p rows [16wp,+16),
  // n cols [64*wn2, +64)
  f32x4v accS[4];
#pragma unroll
  for (int j = 0; j < 4; j++) accS[j] = (f32x4v){0.f, 0.f, 0.f, 0.f};
  __builtin_amdgcn_s_setprio(1);
#pragma unroll
  for (int k0 = 0; k0 < 128; k0 += 32) {
    bf16x8v av = *(const bf16x8v*)&xdtT[wp * 16 + (lane & 15)][(lane >> 4) * 8 + k0];
#pragma unroll
    for (int j = 0; j < 4; j++) {
      bf16x8v bv = *(const bf16x8v*)&BdT[(wn2 * 4 + j) * 16 + (lane & 15)][(lane >> 4) * 8 + k0];
      accS[j] = __builtin_amdgcn_mfma_f32_16x16x32_bf16(av, bv, accS[j], 0, 0, 0);
    }
  }
  __builtin_amdgcn_s_setprio(0);
  int quad = lane >> 4, cn = lane & 15;
  bf16* st = states + (size_t)gid * (HEADDIM * DSTATE);
#pragma unroll
  for (int j = 0; j < 4; j++)
#pragma unroll
    for (int r = 0; r < 4; r++) {
      int p = wp * 16 + quad * 4 + r;
      int n = (wn2 * 4 + j) * 16 + cn;
      st[p * DSTATE + n] = f2b(accS[j][r]);
    }
}

// ---------------- inter-chunk scan: register-batched (independent loads first) --------
__global__ __launch_bounds__(256) void scan_kernel(
    bf16* __restrict__ states, const float* __restrict__ csum) {
  int idx = blockIdx.x * 256 + threadIdx.x;  // 2*NHEADS*HEADDIM*DSTATE
  int n = idx % DSTATE;
  int p = (idx / DSTATE) % HEADDIM;
  int h = (idx / (DSTATE * HEADDIM)) % NHEADS;
  int b = idx / (DSTATE * HEADDIM * NHEADS);
  size_t base = ((size_t)(b * NCHUNK) * NHEADS + h) * (HEADDIM * DSTATE) + p * DSTATE + n;
  const size_t cstride = (size_t)NHEADS * HEADDIM * DSTATE;
  float tmp[NCHUNK], cv[NCHUNK];
#pragma unroll
  for (int c = 0; c < NCHUNK; c++) tmp[c] = b2f(states[base + c * cstride]);
#pragma unroll
  for (int c = 0; c < NCHUNK; c++) cv[c] = csum[(b * NCHUNK + c) * NHEADS + h];
  float S = 0.f;
#pragma unroll
  for (int c = 0; c < NCHUNK; c++) {
    states[base + c * cstride] = f2b(S);
    S = cv[c] * S + tmp[c];
  }
}

// ---------------- fused Y = Y_diag + Y_off + D*x (MFMA, single bf16 write) ----------------
// R12: 512 threads (8 waves) on the SAME single block per (b,c,h); T14 preloads
// + setprio; wave w owns l rows [16w, 16w+16).
__global__ __launch_bounds__(512, 4) void yoff_kernel(
    const bf16* __restrict__ xbc, const float* __restrict__ dt2,
    const float* __restrict__ A_log, const bf16* __restrict__ G,
    const bf16* __restrict__ states, const float* __restrict__ Dp,
    bf16* __restrict__ Y) {
  int gid = blockIdx.x;
  int h = gid % NHEADS;
  int bc = gid / NHEADS;
  int c = bc % NCHUNK, b = bc / NCHUNK;
  int tid = threadIdx.x;
  int lane = tid & 63;
  int w = tid >> 6;               // 0..7 -> l rows [16w, 16w+16)
  __shared__ bf16 WB[128][136];   // 34 KB (W, then Ce)
  __shared__ bf16 SX[64][136];    // 17 KB (xdtT, then St)
  __shared__ float acs[CHUNKL];
  __shared__ float dtl[CHUNKL];
  __shared__ float eAl[CHUNKL];
  if (tid < CHUNKL)
    dtl[tid] = dt2[((size_t)b * L_SEQ + c * CHUNKL + tid) * NHEADS + h];
  __syncthreads();
  // wave-parallel inclusive scan of Ah*dtl (128 elems, 2/lane, wave 0 only)
  if (tid < 64) {
    float Ah = -__expf(A_log[h]);
    float v0 = Ah * dtl[2 * tid];
    float v1 = Ah * dtl[2 * tid + 1];
    float s = v0 + v1;
#pragma unroll
    for (int off = 1; off < 64; off <<= 1) {
      float t = __shfl_up(s, off);
      if (tid >= off) s += t;
    }
    acs[2 * tid]     = s - v1;
    acs[2 * tid + 1] = s;
  }
  __syncthreads();
  if (tid < CHUNKL) eAl[tid] = __expf(acs[tid]);   // <= 1
  // T14: issue Ce + St + epilogue-x global loads NOW; consumed after GEMM1/2.
  bf16x8v ce_r[4], st_r[2];
  float xe[4][4];
  {
    int cofs = b ? 2432 : 2176;
#pragma unroll
    for (int it = 0; it < 4; it++) {
      int o = tid + it * 512;
      int l = o >> 4;
      int n8 = (o & 15) * 8;
      int t = b ? (L_SEQ - 1 - (c * CHUNKL + l)) : (c * CHUNKL + l);
      ce_r[it] = *(const bf16x8v*)&xbc[(size_t)t * CONVDIM + cofs + n8];
    }
    const bf16* stp = states + (size_t)gid * (HEADDIM * DSTATE);
#pragma unroll
    for (int it = 0; it < 2; it++) {
      int o = tid + it * 512;
      st_r[it] = *(const bf16x8v*)&stp[o * 8];
    }
    int quad0 = lane >> 4, cn0 = lane & 15;
#pragma unroll
    for (int j = 0; j < 4; j++)
#pragma unroll
      for (int r = 0; r < 4; r++) {
        int l = w * 16 + quad0 * 4 + r;
        int p = j * 16 + cn0;
        int t = b ? (L_SEQ - 1 - (c * CHUNKL + l)) : (c * CHUNKL + l);
        xe[j][r] = b2f(xbc[(size_t)t * CONVDIM + h * HEADDIM + p]);
      }
  }
  // SX <- xdtT[p][s]: lane->s, conflict-free scatter (2 iters @ 512 thr)
  for (int o = tid; o < CHUNKL * HEADDIM / 8; o += 512) {   // 1024 vecs
    int s = o & 127;
    int p8 = (o >> 7) * 8;
    int t = b ? (L_SEQ - 1 - (c * CHUNKL + s)) : (c * CHUNKL + s);
    bf16x8v xv = *(const bf16x8v*)&xbc[(size_t)t * CONVDIM + h * HEADDIM + p8];
    float d = dtl[s];
#pragma unroll
    for (int j = 0; j < 8; j++) SX[p8 + j][s] = f2b(sh2f(xv[j]) * d);
  }
  // WB <- W[l][s] = G*exp(acs[l]-acs[s]) (s<=l): b128 writes; upper-tri vecs
  // (s8 > l) skip the G load and expf entirely. (4 iters @ 512 thr)
  {
    const bf16* Gb = G + (size_t)bc * CHUNKL * CHUNKL;
    for (int o = tid; o < CHUNKL * CHUNKL / 8; o += 512) {  // 2048 vecs
      int l = o >> 4;
      int s8 = (o & 15) * 8;
      bf16x8v wv;
      if (s8 > l) {
#pragma unroll
        for (int j = 0; j < 8; j++) wv[j] = 0;
      } else {
        bf16x8v g = *(const bf16x8v*)&Gb[l * CHUNKL + s8];
        float al = acs[l];
#pragma unroll
        for (int j = 0; j < 8; j++) {
          int s = s8 + j;
          float e = (s <= l) ? sh2f(g[j]) * __expf(al - acs[s]) : 0.f;
          wv[j] = f2bs(e);
        }
      }
      *(bf16x8v*)&WB[l][s8] = wv;
    }
  }
  __syncthreads();
  f32x4v accY[4];
#pragma unroll
  for (int j = 0; j < 4; j++) accY[j] = (f32x4v){0.f, 0.f, 0.f, 0.f};
  // Y_diag: A=W rows [16w,16w+16), B=xdtT p-tiles, k=s.
  // Wave-uniform skip: k0 > 16w+15 => A block all-zero (strict upper triangle).
  __builtin_amdgcn_s_setprio(1);
#pragma unroll
  for (int k0 = 0; k0 < 128; k0 += 32) {
    if (k0 > w * 16 + 15) break;
    bf16x8v a0 = *(const bf16x8v*)&WB[w * 16 + (lane & 15)][(lane >> 4) * 8 + k0];
#pragma unroll
    for (int j = 0; j < 4; j++) {
      bf16x8v bv = *(const bf16x8v*)&SX[j * 16 + (lane & 15)][(lane >> 4) * 8 + k0];
      accY[j] = __builtin_amdgcn_mfma_f32_16x16x32_bf16(a0, bv, accY[j], 0, 0, 0);
    }
  }
  __builtin_amdgcn_s_setprio(0);
  __syncthreads();   // all phase-1 LDS reads done
  // restage from REGISTERS (global latency already hidden under GEMM1):
  // WB <- Ce*eAl, SX <- St
  {
#pragma unroll
    for (int it = 0; it < 4; it++) {
      int o = tid + it * 512;
      int l = o >> 4;
      int n8 = (o & 15) * 8;
      float e = eAl[l];
      bf16x8v ov;
#pragma unroll
      for (int j = 0; j < 8; j++) ov[j] = f2bs(sh2f(ce_r[it][j]) * e);
      *(bf16x8v*)&WB[l][n8] = ov;
    }
#pragma unroll
    for (int it = 0; it < 2; it++) {
      int o = tid + it * 512;
      int p = o >> 4;
      int n8 = (o & 15) * 8;
      *(bf16x8v*)&SX[p][n8] = st_r[it];
    }
  }
  __syncthreads();
  // Y_off: A=Ce rows [16w,16w+16), B=St p-tiles, k=n; accumulate into same accY
  __builtin_amdgcn_s_setprio(1);
#pragma unroll
  for (int k0 = 0; k0 < 128; k0 += 32) {
    bf16x8v a0 = *(const bf16x8v*)&WB[w * 16 + (lane & 15)][(lane >> 4) * 8 + k0];
#pragma unroll
    for (int j = 0; j < 4; j++) {
      bf16x8v bv = *(const bf16x8v*)&SX[j * 16 + (lane & 15)][(lane >> 4) * 8 + k0];
      accY[j] = __builtin_amdgcn_mfma_f32_16x16x32_bf16(a0, bv, accY[j], 0, 0, 0);
    }
  }
  __builtin_amdgcn_s_setprio(0);
  int quad = lane >> 4, cn = lane & 15;
  float Dh = Dp[h];
#pragma unroll
  for (int j = 0; j < 4; j++)
#pragma unroll
    for (int r = 0; r < 4; r++) {
      int l = w * 16 + quad * 4 + r;
      int p = j * 16 + cn;
      size_t yi = ((size_t)b * L_SEQ + c * CHUNKL + l) * DINNER + h * HEADDIM + p;
      Y[yi] = f2b(accY[j][r] + xe[j][r] * Dh);
    }
}

// ---------------- combine: shift, flip, +x*fd, gate, RMSNorm (vectorized) ----------------
__global__ __launch_bounds__(256) void combine_kernel(
    const bf16* __restrict__ Y, const bf16* __restrict__ xbc,
    const bf16* __restrict__ zx, const float* __restrict__ fd,
    const float* __restrict__ norm_w, bf16* __restrict__ yn) {
  int t = blockIdx.x;
  int tid = threadIdx.x;
  int j8 = tid * 8;
  float yf[8], yb[8];
#pragma unroll
  for (int j = 0; j < 8; j++) { yf[j] = 0.f; yb[j] = 0.f; }
  if (t >= 1) {
    bf16x8v v = *(const bf16x8v*)&Y[(size_t)(t - 1) * DINNER + j8];
#pragma unroll
    for (int j = 0; j < 8; j++) yf[j] = sh2f(v[j]);
  }
  if (t <= L_SEQ - 2) {
    bf16x8v v = *(const bf16x8v*)&Y[((size_t)L_SEQ + (L_SEQ - 2 - t)) * DINNER + j8];
#pragma unroll
    for (int j = 0; j < 8; j++) yb[j] = sh2f(v[j]);
  }
  bf16x8v xogv = *(const bf16x8v*)&xbc[(size_t)t * CONVDIM + j8];
  bf16x8v zv = *(const bf16x8v*)&zx[(size_t)t * DPROJ + j8];
  float fdv = fd[t * NHEADS + (j8 >> 6)];
  float yg[8];
  float ss = 0.f;
#pragma unroll
  for (int j = 0; j < 8; j++) {
    float y = yf[j] + yb[j] + sh2f(xogv[j]) * fdv;
    float z = sh2f(zv[j]);
    float g = y * (z / (1.f + __expf(-z)));
    yg[j] = g;
    ss += g * g;
  }
#pragma unroll
  for (int off = 32; off > 0; off >>= 1) ss += __shfl_down(ss, off);
  __shared__ float red[4];
  if ((tid & 63) == 0) red[tid >> 6] = ss;
  __syncthreads();
  float tot = red[0] + red[1] + red[2] + red[3];
  float scale = rsqrtf(tot / (float)DINNER + 1e-5f);
  float4 nw0 = *(const float4*)&norm_w[j8];
  float4 nw1 = *(const float4*)&norm_w[j8 + 4];
  bf16x8v ov;
  ov[0] = f2bs(yg[0] * scale * nw0.x);
  ov[1] = f2bs(yg[1] * scale * nw0.y);
  ov[2] = f2bs(yg[2] * scale * nw0.z);
  ov[3] = f2bs(yg[3] * scale * nw0.w);
  ov[4] = f2bs(yg[4] * scale * nw1.x);
  ov[5] = f2bs(yg[5] * scale * nw1.y);
  ov[6] = f2bs(yg[6] * scale * nw1.z);
  ov[7] = f2bs(yg[7] * scale * nw1.w);
  *(bf16x8v*)&yn[(size_t)t * DINNER + j8] = ov;
}

// ---------------- launch ----------------
extern "C" void kernel_launch(void* const* d_in, const int* in_sizes, int n_in,
                              void* d_out, int out_size, void* d_ws, size_t ws_size,
                              hipStream_t stream) {
  const float* u         = (const float*)d_in[0];
  const float* in_proj_w = (const float*)d_in[1];
  const float* conv_w    = (const float*)d_in[2];
  const float* conv_b    = (const float*)d_in[3];
  const float* dt_bias   = (const float*)d_in[4];
  const float* A_log     = (const float*)d_in[5];
  const float* Dp        = (const float*)d_in[6];
  const float* fc_D_w    = (const float*)d_in[7];
  const float* norm_w    = (const float*)d_in[8];
  const float* out_proj_w= (const float*)d_in[9];
  float* out = (float*)d_out;

  char* base = (char*)d_ws;
  bf16*  zx  = (bf16*)base;  base += (size_t)L_SEQ * DPROJ * 2;                    // 38.3 MB
  bf16*  xbc = (bf16*)base;  base += (size_t)L_SEQ * CONVDIM * 2;                  // 21.0 MB
  float* dt2 = (float*)base; base += (size_t)2 * L_SEQ * NHEADS * 4;               //  1.0 MB
  bf16*  G   = (bf16*)base;  base += (size_t)2 * NCHUNK * CHUNKL * CHUNKL * 4;     //  4.2 MB region
  bf16*  Yb  = (bf16*)base;  base += (size_t)2 * L_SEQ * DINNER * 4;               // 67.1 MB region
  bf16*  stb = (bf16*)base;  base += (size_t)2 * NCHUNK * NHEADS * HEADDIM * DSTATE * 4; // 67.1 MB region
  float* cs  = (float*)base; base += (size_t)2 * NCHUNK * NHEADS * 4;              //  8 KB
  // aliases into dead regions:
  bf16*  u_bf   = (bf16*)Yb;                          // 8.4 MB   (Yb live only after yoff)
  bf16*  w1p_bf = (bf16*)((char*)Yb + 9437184);       // 9.7 MB   (in_proj_w padded to 4736 rows)
  bf16*  w2_bf  = (bf16*)G;                           // 4.2 MB   (G dead after yoff)
  bf16*  yn     = (bf16*)stb;                         // 16.8 MB  (stb dead after yoff)
  float* fd     = (float*)((char*)stb + 33554432);    //  0.5 MB  (32 MB offset)
  bf16*  wf_bf  = (bf16*)((char*)stb + 35651584);     //  128 KB  (34 MB offset)
  float* fdp    = (float*)((char*)stb + 37748736);    //  8 MB    (36 MB offset)
  float* p1     = (float*)Yb;                         // 16.8 MB  (Yb dead after combine)

  // 0. fused casts for MFMA gemm1 (w1 zero-padded to NPAD1 rows)
  cast2_kernel<<<(L_SEQ * DMODEL + NPAD1 * DMODEL) / 256, 256, 0, stream>>>(
      u, in_proj_w, u_bf, w1p_bf);
  // 1a. in_proj main: cols [0,4096) (8-phase 256^2, 256 blocks = exactly 1 round)
  gemm1_8ph<<<(L_SEQ / 256) * G1_GN, 512, 0, stream>>>(u_bf, w1p_bf, zx);
  // 1b. in_proj remainder: cols [4096,4672) (128^2 gemm, 160 blocks)
  gemm_mfma<bf16><<<(L_SEQ / 128) * ((NPAD1 - NSPLIT) / 128), 256, 0, stream>>>(
      u_bf, DMODEL, w1p_bf + (size_t)NSPLIT * DMODEL, DMODEL,
      zx + NSPLIT, DPROJ, DPROJ - NSPLIT, DMODEL,
      L_SEQ / 128, (NPAD1 - NSPLIT) / 128, 0);
  // 2. conv + silu + dt (fused)
  conv_dt_kernel<<<CONV_BLOCKS + (2 * L_SEQ * NHEADS) / 256, 256, 0, stream>>>(
      zx, conv_w, conv_b, xbc, dt_bias, dt2);
  // 3a. G = C B^T per (b,c), quarter-split (MFMA, bf16)
  gmat_kernel<<<2 * NCHUNK * 4, 256, 0, stream>>>(xbc, G);
  // 3b. chunk states (MFMA, bf16; 512 threads = 16 waves/CU)
  chunk_kernel<<<2 * NCHUNK * NHEADS, 512, 0, stream>>>(
      xbc, dt2, A_log, stb, cs);
  // 3c. inter-chunk scan (register-batched)
  scan_kernel<<<(2 * NHEADS * HEADDIM * DSTATE) / 256, 256, 0, stream>>>(stb, cs);
  // 3d. fused Y = Y_diag + Y_off + D*x (MFMA; 512 threads = 16 waves/CU)
  yoff_kernel<<<2 * NCHUNK * NHEADS, 512, 0, stream>>>(
      xbc, dt2, A_log, G, stb, Dp, Yb);
  // 4a. casts into dead regions: out_proj_w -> w2_bf (G), fc_D_w -> wf_bf (stb)
  cast_kernel<<<(DMODEL * DINNER + 255) / 256, 256, 0, stream>>>(
      out_proj_w, w2_bf, DMODEL * DINNER, DMODEL * DINNER);
  cast_kernel<<<(NHEADS * DINNER + 255) / 256, 256, 0, stream>>>(
      fc_D_w, wf_bf, NHEADS * DINNER, NHEADS * DINNER);
  // 4b. fd = x_og @ fc_D_w^T + D  (MFMA split-K=16: 512 blocks, then reduce)
  fc_mfma<<<(L_SEQ / 128) * FC_KS, 256, 0, stream>>>(xbc, wf_bf, fdp);
  fc_reduce<<<(L_SEQ * NHEADS) / 256, 256, 0, stream>>>(fdp, Dp, fd);
  // 5. combine + gate + RMSNorm
  combine_kernel<<<L_SEQ, 256, 0, stream>>>(Yb, xbc, zx, fd, norm_w, yn);
  // 6. out_proj split-K=2 (512 blocks = 2/CU) + add pass
  outproj_ks<<<512, 256, 0, stream>>>(yn, w2_bf, out, p1);
  add_kernel<<<(L_SEQ * DMODEL) / 1024, 256, 0, stream>>>(out, p1);
}